// Round 1
// baseline (3076.571 us; speedup 1.0000x reference)
//
#include <hip/hip_runtime.h>
#include <cmath>

// ---------------------------------------------------------------------------
// Hyperbolic MS-CNN (Poincare ball, c=1) — fp32 correctness-first baseline.
//
// Structure per conv layer i:
//   A : v = logmap0(x_prev)                (per-pixel over channels)
//   B : y = PoincareFC(expmap0(scale*patch(v)), z_i, b_i)   (fused conv)
//   C1: t = f * relu(y)  (tangent of hrelu; expmap0/logmap0 roundtrip with
//                          hmaxpool's logmap0 cancels exactly)
//   C2a: m = maxpool2x2(t)  (channelwise max in tangent space)
//   C2b: x_i = expmap0(m)
//   avg: flat segment = spatial mean of x_i  (== adaptive_avg + mean)
// Then: pfc(flat, zf1,bf1) -> hrelu rows -> pfc(., zf2,bf2) -> out (16,1000)
// ---------------------------------------------------------------------------

#define EPSF 1e-15f
#define ATANH_CAP 0.9999999f  // 1 - 1e-7

// ---------------- z column norms: zn[o] = sqrt(max(sum_k z[k,o]^2, eps)) ----
__global__ __launch_bounds__(256) void znorm_kernel(
    const float* __restrict__ z, float* __restrict__ zn, int K, int Nout) {
  int o = blockIdx.x * blockDim.x + threadIdx.x;
  if (o >= Nout) return;
  float s = 0.f;
  for (int k = 0; k < K; ++k) { float v = z[(size_t)k * Nout + o]; s += v * v; }
  zn[o] = sqrtf(fmaxf(s, EPSF));
}

// ---------------- logmap0 (MODE=0) / expmap0 (MODE=1) over channel axis ----
template <int MODE>
__global__ __launch_bounds__(256) void map0_kernel(
    const float* __restrict__ in, float* __restrict__ out,
    int C, int HW, int total) {
  int i = blockIdx.x * blockDim.x + threadIdx.x;
  if (i >= total) return;
  int b = i / HW, s = i - b * HW;
  const float* p = in + (size_t)b * C * HW + s;
  float ss = 0.f;
  for (int c = 0; c < C; ++c) { float v = p[(size_t)c * HW]; ss += v * v; }
  float n = sqrtf(fmaxf(ss, EPSF));
  float f;
  if (MODE == 0) f = atanhf(fminf(n, ATANH_CAP)) / n;
  else           f = tanhf(n) / n;
  float* q = out + (size_t)b * C * HW + s;
  for (int c = 0; c < C; ++c) q[(size_t)c * HW] = f * p[(size_t)c * HW];
}

// ---------------- tangent of hrelu, in place: y <- atanh(|y|)/|y| * relu(y) -
__global__ __launch_bounds__(256) void relutan_kernel(
    float* __restrict__ y, int C, int HW, int total) {
  int i = blockIdx.x * blockDim.x + threadIdx.x;
  if (i >= total) return;
  int b = i / HW, s = i - b * HW;
  float* p = y + (size_t)b * C * HW + s;
  float ss = 0.f;
  for (int c = 0; c < C; ++c) { float v = p[(size_t)c * HW]; ss += v * v; }
  float n = sqrtf(fmaxf(ss, EPSF));
  float f = atanhf(fminf(n, ATANH_CAP)) / n;
  for (int c = 0; c < C; ++c) {
    float v = p[(size_t)c * HW];
    p[(size_t)c * HW] = f * fmaxf(v, 0.f);
  }
}

// ---------------- 2x2 stride-2 channelwise max ------------------------------
__global__ __launch_bounds__(256) void maxpool_kernel(
    const float* __restrict__ t, float* __restrict__ m,
    int C, int H, int W, int total) {
  int i = blockIdx.x * blockDim.x + threadIdx.x;
  if (i >= total) return;
  int HO = H >> 1, WO = W >> 1;
  int wo = i % WO; int rest = i / WO;
  int ho = rest % HO; rest /= HO;
  int c = rest % C;  int b = rest / C;
  const float* p = t + (((size_t)(b * C + c) * H + 2 * ho) * W + 2 * wo);
  float v = fmaxf(fmaxf(p[0], p[1]), fmaxf(p[W], p[W + 1]));
  m[i] = v;
}

// ---------------- spatial mean into flat segment ----------------------------
__global__ __launch_bounds__(256) void avgpool_kernel(
    const float* __restrict__ x, float* __restrict__ flat,
    int C, int HW, int flatC, int coff) {
  int c = blockIdx.x, b = blockIdx.y, tid = threadIdx.x;
  const float* p = x + ((size_t)b * C + c) * HW;
  float s = 0.f;
  for (int i = tid; i < HW; i += blockDim.x) s += p[i];
  __shared__ float red[256];
  red[tid] = s; __syncthreads();
  for (int st = 128; st > 0; st >>= 1) {
    if (tid < st) red[tid] += red[tid + st];
    __syncthreads();
  }
  if (tid == 0) flat[(size_t)b * flatC + coff + c] = red[0] / (float)HW;
}

// ---------------- fused hyperbolic conv (patch->expmap0->PoincareFC) --------
template <int CIN, int K, int PAD, int COUT, int H, int W, int TH, int TW>
__global__ __launch_bounds__(256) void hconv_kernel(
    const float* __restrict__ vin, const float* __restrict__ z,
    const float* __restrict__ r, const float* __restrict__ zn,
    float* __restrict__ out, float scale) {
  constexpr int BLOCK = 256;
  constexpr int SY = TH + K - 1, SX = TW + K - 1;
  constexpr int NP = TH * TW;        // positions per block
  constexpr int OS = BLOCK / NP;     // Cout split groups
  constexpr int CPT = COUT / OS;     // channels per thread
  constexpr int KK = K * K;
  constexpr int CKK = CIN * KK;

  __shared__ float sm[CIN * SY * SX];
  __shared__ float redbuf[BLOCK];
  __shared__ float gbuf[NP];
  __shared__ float cbuf[NP];
  __shared__ float chb[COUT], shb[COUT], znb[COUT];

  const int tid = threadIdx.x;
  int bid = blockIdx.x;
  constexpr int TX = W / TW, TY = H / TH;
  const int tx = bid % TX; bid /= TX;
  const int ty = bid % TY; const int b = bid / TY;
  const int oy0 = ty * TH, ox0 = tx * TW;

  if (tid < COUT) {
    float rv = r[tid];
    chb[tid] = coshf(2.f * rv);
    shb[tid] = sinhf(2.f * rv);
    znb[tid] = zn[tid];
  }
  const float* vb = vin + (size_t)b * CIN * H * W;
  for (int idx = tid; idx < CIN * SY * SX; idx += BLOCK) {
    int sx = idx % SX; int t = idx / SX; int sy = t % SY; int c = t / SY;
    int gy = oy0 + sy - PAD, gx = ox0 + sx - PAD;
    float val = 0.f;
    if (gy >= 0 && gy < H && gx >= 0 && gx < W)
      val = vb[((size_t)c * H + gy) * W + gx];
    sm[idx] = val;
  }
  __syncthreads();

  const int p = tid & (NP - 1);
  int osg = tid / NP;
  if (NP == 64) osg = __builtin_amdgcn_readfirstlane(osg);  // wave-uniform
  const int py = p / TW, px = p % TW;

  // per-position squared patch norm (partials across OS groups)
  {
    float partial = 0.f;
    for (int ck = osg; ck < CKK; ck += OS) {
      int c = ck / KK; int rem = ck - c * KK;
      int iy = rem / K; int ix = rem - iy * K;
      float v = sm[(c * SY + py + iy) * SX + (px + ix)];
      partial += v * v;
    }
    redbuf[tid] = partial;
  }
  __syncthreads();
  if (tid < NP) {
    float s = 0.f;
    for (int k2 = 0; k2 < OS; ++k2) s += redbuf[tid + k2 * NP];
    float n = sqrtf(fmaxf(scale * scale * s, EPSF));
    float th = tanhf(n);
    gbuf[tid] = th * scale / n;  // maps raw-patch dot -> expmap'd dot
    cbuf[tid] = th * th;         // cx2 = |u|^2
  }
  __syncthreads();

  // dot products: acc[j] = sum_ck patch[ck] * z[ck, obase+j]
  float acc[CPT];
#pragma unroll
  for (int j = 0; j < CPT; ++j) acc[j] = 0.f;
  const int obase = osg * CPT;
  {
    int ck = 0;
    for (int c = 0; c < CIN; ++c) {
      for (int iy = 0; iy < K; ++iy) {
        const float* srow = sm + (c * SY + py + iy) * SX + px;
#pragma unroll
        for (int ix = 0; ix < K; ++ix) {
          const float pv = srow[ix];
          const float* zr = z + (size_t)ck * COUT + obase;
#pragma unroll
          for (int j = 0; j < CPT; ++j)
            acc[j] = fmaf(pv, zr[j], acc[j]);
          ++ck;
        }
      }
    }
  }

  // epilogue: MLR -> sinh -> ball projection
  const float g = gbuf[p];
  const float cx2 = cbuf[p];
  const float onemc = fmaxf(1.f - cx2, EPSF);
  float ls = 0.f;
#pragma unroll
  for (int j = 0; j < CPT; ++j) {
    int o = obase + j;
    float znv = znb[o];
    float num = 2.f * (g * acc[j] / znv) * chb[o] - (1.f + cx2) * shb[o];
    float mlr = 2.f * znv * asinhf(num / onemc);
    float yv = sinhf(mlr);
    acc[j] = yv;
    ls += yv * yv;
  }
  redbuf[tid] = ls;
  __syncthreads();
  if (tid < NP) {
    float s = 0.f;
    for (int k2 = 0; k2 < OS; ++k2) s += redbuf[tid + k2 * NP];
    gbuf[tid] = s;  // reuse (g already consumed by all threads)
  }
  __syncthreads();
  const float denom = 1.f + sqrtf(1.f + gbuf[p]);
  const int oy = oy0 + py, ox = ox0 + px;
#pragma unroll
  for (int j = 0; j < CPT; ++j)
    out[(((size_t)b * COUT + obase + j) * H + oy) * W + ox] = acc[j] / denom;
}

// ---------------- Poincare FC over rows -------------------------------------
template <int NIN, int NOUT, int BLOCK>
__global__ __launch_bounds__(256) void pfc_kernel(
    const float* __restrict__ x, const float* __restrict__ z,
    const float* __restrict__ r, const float* __restrict__ zn,
    float* __restrict__ out) {
  const int b = blockIdx.x, tid = threadIdx.x;
  __shared__ float xs[NIN];
  __shared__ float red[BLOCK];
  for (int i = tid; i < NIN; i += BLOCK) xs[i] = x[(size_t)b * NIN + i];
  __syncthreads();
  float s = 0.f;
  for (int i = tid; i < NIN; i += BLOCK) { float v = xs[i]; s += v * v; }
  red[tid] = s; __syncthreads();
  for (int st = BLOCK / 2; st > 0; st >>= 1) {
    if (tid < st) red[tid] += red[tid + st];
    __syncthreads();
  }
  const float cx2 = red[0];
  __syncthreads();
  constexpr int CPT = (NOUT + BLOCK - 1) / BLOCK;
  const float onemc = fmaxf(1.f - cx2, EPSF);
  float yv[CPT];
  float ls = 0.f;
#pragma unroll
  for (int j = 0; j < CPT; ++j) {
    int o = tid + j * BLOCK;
    float y = 0.f;
    if (o < NOUT) {
      float d = 0.f;
      for (int k = 0; k < NIN; ++k) d = fmaf(xs[k], z[(size_t)k * NOUT + o], d);
      float znv = zn[o];
      float rv = r[o];
      float num = 2.f * (d / znv) * coshf(2.f * rv) - (1.f + cx2) * sinhf(2.f * rv);
      float mlr = 2.f * znv * asinhf(num / onemc);
      y = sinhf(mlr);
    }
    yv[j] = y; ls += y * y;
  }
  red[tid] = ls; __syncthreads();
  for (int st = BLOCK / 2; st > 0; st >>= 1) {
    if (tid < st) red[tid] += red[tid + st];
    __syncthreads();
  }
  const float denom = 1.f + sqrtf(1.f + red[0]);
#pragma unroll
  for (int j = 0; j < CPT; ++j) {
    int o = tid + j * BLOCK;
    if (o < NOUT) out[(size_t)b * NOUT + o] = yv[j] / denom;
  }
}

// ---------------- hrelu over rows (axis=-1) ---------------------------------
template <int N, int BLOCK>
__global__ __launch_bounds__(256) void hrelu_rows_kernel(
    const float* __restrict__ in, float* __restrict__ out) {
  const int b = blockIdx.x, tid = threadIdx.x;
  __shared__ float red[BLOCK];
  constexpr int CPT = N / BLOCK;
  float v[CPT];
  float s = 0.f;
#pragma unroll
  for (int j = 0; j < CPT; ++j) {
    v[j] = in[(size_t)b * N + tid + j * BLOCK];
    s += v[j] * v[j];
  }
  red[tid] = s; __syncthreads();
  for (int st = BLOCK / 2; st > 0; st >>= 1) {
    if (tid < st) red[tid] += red[tid + st];
    __syncthreads();
  }
  float n = sqrtf(fmaxf(red[0], EPSF));
  float f = atanhf(fminf(n, ATANH_CAP)) / n;
  __syncthreads();
  float s2 = 0.f;
#pragma unroll
  for (int j = 0; j < CPT; ++j) { v[j] = f * fmaxf(v[j], 0.f); s2 += v[j] * v[j]; }
  red[tid] = s2; __syncthreads();
  for (int st = BLOCK / 2; st > 0; st >>= 1) {
    if (tid < st) red[tid] += red[tid + st];
    __syncthreads();
  }
  float nt = sqrtf(fmaxf(red[0], EPSF));
  float gg = tanhf(nt) / nt;
#pragma unroll
  for (int j = 0; j < CPT; ++j)
    out[(size_t)b * N + tid + j * BLOCK] = gg * v[j];
}

// ---------------------------------------------------------------------------
static inline double beta_fn(double a, double b) {
  return std::exp(std::lgamma(a) + std::lgamma(b) - std::lgamma(a + b));
}

extern "C" void kernel_launch(void* const* d_in, const int* in_sizes, int n_in,
                              void* d_out, int out_size, void* d_ws, size_t ws_size,
                              hipStream_t stream) {
  const float* x   = (const float*)d_in[0];
  const float* z1  = (const float*)d_in[1];
  const float* b1  = (const float*)d_in[2];
  const float* z2  = (const float*)d_in[3];
  const float* b2  = (const float*)d_in[4];
  const float* z3  = (const float*)d_in[5];
  const float* b3  = (const float*)d_in[6];
  const float* z4  = (const float*)d_in[7];
  const float* b4  = (const float*)d_in[8];
  const float* zf1 = (const float*)d_in[9];
  const float* bf1 = (const float*)d_in[10];
  const float* zf2 = (const float*)d_in[11];
  const float* bf2 = (const float*)d_in[12];
  float* outp = (float*)d_out;

  float* ws   = (float*)d_ws;
  float* zn   = ws;                  // 2048
  float* flat = ws + 2048;           // 16*352
  float* h1r  = ws + 7680;           // 16*512
  float* h1   = ws + 15872;          // 16*512
  float* xbuf = ws + 24576;          // 2,097,152 (max x_i)
  float* vm   = xbuf + 2097152;      // 2,097,152 (tangent in / pooled tangent)
  float* ybuf = vm + 2097152;        // 8,388,608 (conv out / relu tangent)
  // total: 12,607,488 floats = 50.4 MB <= ws_size (assumed)

  const float s1 = (float)(beta_fn(27.0 / 2.0, 0.5) / beta_fn(3.0 / 2.0, 0.5));
  const float s2 = (float)(beta_fn(800.0 / 2.0, 0.5) / beta_fn(32.0 / 2.0, 0.5));
  const float s3 = (float)(beta_fn(3136.0 / 2.0, 0.5) / beta_fn(64.0 / 2.0, 0.5));
  const float s4 = (float)(beta_fn(1152.0 / 2.0, 0.5) / beta_fn(128.0 / 2.0, 0.5));

  auto g1 = [](int n) { return dim3((n + 255) / 256); };

  // z column norms
  znorm_kernel<<<g1(32),   256, 0, stream>>>(z1, zn + 0, 27, 32);
  znorm_kernel<<<g1(64),   256, 0, stream>>>(z2, zn + 32, 800, 64);
  znorm_kernel<<<g1(128),  256, 0, stream>>>(z3, zn + 96, 3136, 128);
  znorm_kernel<<<g1(128),  256, 0, stream>>>(z4, zn + 224, 1152, 128);
  znorm_kernel<<<g1(512),  256, 0, stream>>>(zf1, zn + 352, 352, 512);
  znorm_kernel<<<g1(1000), 256, 0, stream>>>(zf2, zn + 864, 512, 1000);

  // ---- layer 1: (16,3,128,128) -> (16,32,64,64)
  map0_kernel<0><<<g1(262144), 256, 0, stream>>>(x, vm, 3, 128 * 128, 262144);
  hconv_kernel<3, 3, 1, 32, 128, 128, 8, 8><<<4096, 256, 0, stream>>>(vm, z1, b1, zn + 0, ybuf, s1);
  relutan_kernel<<<g1(262144), 256, 0, stream>>>(ybuf, 32, 128 * 128, 262144);
  maxpool_kernel<<<g1(2097152), 256, 0, stream>>>(ybuf, vm, 32, 128, 128, 2097152);
  map0_kernel<1><<<g1(65536), 256, 0, stream>>>(vm, xbuf, 32, 64 * 64, 65536);
  avgpool_kernel<<<dim3(32, 16), 256, 0, stream>>>(xbuf, flat, 32, 4096, 352, 0);

  // ---- layer 2: -> (16,64,32,32)
  map0_kernel<0><<<g1(65536), 256, 0, stream>>>(xbuf, vm, 32, 64 * 64, 65536);
  hconv_kernel<32, 5, 2, 64, 64, 64, 8, 8><<<1024, 256, 0, stream>>>(vm, z2, b2, zn + 32, ybuf, s2);
  relutan_kernel<<<g1(65536), 256, 0, stream>>>(ybuf, 64, 64 * 64, 65536);
  maxpool_kernel<<<g1(1048576), 256, 0, stream>>>(ybuf, vm, 64, 64, 64, 1048576);
  map0_kernel<1><<<g1(16384), 256, 0, stream>>>(vm, xbuf, 64, 32 * 32, 16384);
  avgpool_kernel<<<dim3(64, 16), 256, 0, stream>>>(xbuf, flat, 64, 1024, 352, 32);

  // ---- layer 3: -> (16,128,16,16)
  map0_kernel<0><<<g1(16384), 256, 0, stream>>>(xbuf, vm, 64, 32 * 32, 16384);
  hconv_kernel<64, 7, 3, 128, 32, 32, 8, 8><<<256, 256, 0, stream>>>(vm, z3, b3, zn + 96, ybuf, s3);
  relutan_kernel<<<g1(16384), 256, 0, stream>>>(ybuf, 128, 32 * 32, 16384);
  maxpool_kernel<<<g1(524288), 256, 0, stream>>>(ybuf, vm, 128, 32, 32, 524288);
  map0_kernel<1><<<g1(4096), 256, 0, stream>>>(vm, xbuf, 128, 16 * 16, 4096);
  avgpool_kernel<<<dim3(128, 16), 256, 0, stream>>>(xbuf, flat, 128, 256, 352, 96);

  // ---- layer 4: -> (16,128,8,8)
  map0_kernel<0><<<g1(4096), 256, 0, stream>>>(xbuf, vm, 128, 16 * 16, 4096);
  hconv_kernel<128, 3, 1, 128, 16, 16, 4, 8><<<128, 256, 0, stream>>>(vm, z4, b4, zn + 224, ybuf, s4);
  relutan_kernel<<<g1(4096), 256, 0, stream>>>(ybuf, 128, 16 * 16, 4096);
  maxpool_kernel<<<g1(131072), 256, 0, stream>>>(ybuf, vm, 128, 16, 16, 131072);
  map0_kernel<1><<<g1(1024), 256, 0, stream>>>(vm, xbuf, 128, 8 * 8, 1024);
  avgpool_kernel<<<dim3(128, 16), 256, 0, stream>>>(xbuf, flat, 128, 64, 352, 224);

  // ---- head: flat (16,352) -> (16,512) -> hrelu -> (16,1000)
  pfc_kernel<352, 512, 256><<<16, 256, 0, stream>>>(flat, zf1, bf1, zn + 352, h1r);
  hrelu_rows_kernel<512, 256><<<16, 256, 0, stream>>>(h1r, h1);
  pfc_kernel<512, 1000, 256><<<16, 256, 0, stream>>>(h1, zf2, bf2, zn + 864, outp);

  (void)in_sizes; (void)n_in; (void)out_size; (void)ws_size;
}

// Round 2
// 1740.735 us; speedup vs baseline: 1.7674x; 1.7674x over previous
//
#include <hip/hip_runtime.h>
#include <cmath>

// ---------------------------------------------------------------------------
// Hyperbolic MS-CNN (Poincare ball, c=1) — fp32, round 2.
//
// Key algebraic fusions (exact, not approximations):
//  * hrelu(y) = expmap0(relu(logmap0(y))) and hmaxpool = expmap0(max(logmap0(.)))
//    => the expmap0/logmap0 round trip between them cancels; we keep the
//    TANGENT t = atanh(|y|)/|y| * relu(y) (fused into the conv epilogue,
//    where sum(y^2) is already available) and maxpool in tangent space.
//  * next layer's hconv starts with logmap0(expmap0(m)) = m, so the pooled
//    tangent m feeds the next conv directly. expmap0 is only materialized
//    for the adaptive-avg feature branch.
// ---------------------------------------------------------------------------

#define EPSF 1e-15f
#define ATANH_CAP 0.9999999f  // 1 - 1e-7

// ---------------- z column norms (parallel over K and columns) --------------
__global__ __launch_bounds__(256) void znorm_kernel(
    const float* __restrict__ z, float* __restrict__ zn, int K, int Nout) {
  const int tid = threadIdx.x;
  const int col = (blockIdx.x << 4) + (tid & 15);
  const int kg = tid >> 4;  // 0..15
  float s = 0.f;
  if (col < Nout)
    for (int k = kg; k < K; k += 16) {
      float v = z[(size_t)k * Nout + col];
      s += v * v;
    }
  __shared__ float red[256];
  red[tid] = s;
  __syncthreads();
  if (tid < 16) {
    float t = 0.f;
#pragma unroll
    for (int j = 0; j < 16; ++j) t += red[tid + (j << 4)];
    if (col < Nout) zn[col] = sqrtf(fmaxf(t, EPSF));
  }
}

// ---------------- logmap0 (MODE=0) / expmap0 (MODE=1) over channel axis ----
template <int MODE>
__global__ __launch_bounds__(256) void map0_kernel(
    const float* __restrict__ in, float* __restrict__ out,
    int C, int HW, int total) {
  int i = blockIdx.x * blockDim.x + threadIdx.x;
  if (i >= total) return;
  int b = i / HW, s = i - b * HW;
  const float* p = in + (size_t)b * C * HW + s;
  float ss = 0.f;
  for (int c = 0; c < C; ++c) { float v = p[(size_t)c * HW]; ss += v * v; }
  float n = sqrtf(fmaxf(ss, EPSF));
  float f;
  if (MODE == 0) f = atanhf(fminf(n, ATANH_CAP)) / n;
  else           f = tanhf(n) / n;
  float* q = out + (size_t)b * C * HW + s;
  for (int c = 0; c < C; ++c) q[(size_t)c * HW] = f * p[(size_t)c * HW];
}

// ---------------- 2x2 stride-2 channelwise max (tangent space) --------------
__global__ __launch_bounds__(256) void maxpool_kernel(
    const float* __restrict__ t, float* __restrict__ m,
    int C, int H, int W, int total) {
  int i = blockIdx.x * blockDim.x + threadIdx.x;
  if (i >= total) return;
  int HO = H >> 1, WO = W >> 1;
  int wo = i % WO; int rest = i / WO;
  int ho = rest % HO; rest /= HO;
  int c = rest % C;  int b = rest / C;
  const float* p = t + (((size_t)(b * C + c) * H + 2 * ho) * W + 2 * wo);
  float v = fmaxf(fmaxf(p[0], p[1]), fmaxf(p[W], p[W + 1]));
  m[i] = v;
}

// ---------------- spatial mean into flat segment ----------------------------
__global__ __launch_bounds__(256) void avgpool_kernel(
    const float* __restrict__ x, float* __restrict__ flat,
    int C, int HW, int flatC, int coff) {
  int c = blockIdx.x, b = blockIdx.y, tid = threadIdx.x;
  const float* p = x + ((size_t)b * C + c) * HW;
  float s = 0.f;
  for (int i = tid; i < HW; i += blockDim.x) s += p[i];
  __shared__ float red[256];
  red[tid] = s; __syncthreads();
  for (int st = 128; st > 0; st >>= 1) {
    if (tid < st) red[tid] += red[tid + st];
    __syncthreads();
  }
  if (tid == 0) flat[(size_t)b * flatC + coff + c] = red[0] / (float)HW;
}

// ---------------- fused hconv: patch->expmap0->PoincareFC->relu-tangent -----
// Input : vin  = tangent image (B, CIN, H, W)   (logmap0 of the ball input)
// Output: out  = t = atanh(|y|)/|y| * relu(y)  (tangent, pre-maxpool)
template <int CIN, int K, int PAD, int COUT, int H, int W, int TH, int TW>
__global__ __launch_bounds__(256) void hconv_kernel(
    const float* __restrict__ vin, const float* __restrict__ z,
    const float* __restrict__ r, const float* __restrict__ zn,
    float* __restrict__ out, float scale) {
  constexpr int BLOCK = 256;
  constexpr int SY = TH + K - 1, SX = TW + K - 1;
  constexpr int NP = TH * TW;        // positions per block
  constexpr int OS = BLOCK / NP;     // Cout split groups
  constexpr int CPT = COUT / OS;     // channels per thread (multiple of 4)
  constexpr int KK = K * K;
  constexpr int CKK = CIN * KK;

  __shared__ float sm[CIN * SY * SX];
  __shared__ float redbuf[BLOCK];
  __shared__ float gbuf[NP];
  __shared__ float cbuf[NP];
  __shared__ float chb[COUT], shb[COUT], znb[COUT];

  const int tid = threadIdx.x;
  int bid = blockIdx.x;
  constexpr int TX = W / TW, TY = H / TH;
  const int tx = bid % TX; bid /= TX;
  const int ty = bid % TY; const int b = bid / TY;
  const int oy0 = ty * TH, ox0 = tx * TW;

  if (tid < COUT) {
    float rv = r[tid];
    chb[tid] = coshf(2.f * rv);
    shb[tid] = sinhf(2.f * rv);
    znb[tid] = zn[tid];
  }
  const float* vb = vin + (size_t)b * CIN * H * W;
  for (int idx = tid; idx < CIN * SY * SX; idx += BLOCK) {
    int sx = idx % SX; int t = idx / SX; int sy = t % SY; int c = t / SY;
    int gy = oy0 + sy - PAD, gx = ox0 + sx - PAD;
    float val = 0.f;
    if (gy >= 0 && gy < H && gx >= 0 && gx < W)
      val = vb[((size_t)c * H + gy) * W + gx];
    sm[idx] = val;
  }
  __syncthreads();

  const int p = tid & (NP - 1);
  int osg = tid / NP;
  if (NP == 64) osg = __builtin_amdgcn_readfirstlane(osg);  // wave-uniform
  const int py = p / TW, px = p % TW;

  // per-position squared patch norm (partials across OS groups)
  {
    float partial = 0.f;
    for (int ck = osg; ck < CKK; ck += OS) {
      int c = ck / KK; int rem = ck - c * KK;
      int iy = rem / K; int ix = rem - iy * K;
      float v = sm[(c * SY + py + iy) * SX + (px + ix)];
      partial += v * v;
    }
    redbuf[tid] = partial;
  }
  __syncthreads();
  if (tid < NP) {
    float s = 0.f;
    for (int k2 = 0; k2 < OS; ++k2) s += redbuf[tid + k2 * NP];
    float n = sqrtf(fmaxf(scale * scale * s, EPSF));
    float th = tanhf(n);
    gbuf[tid] = th * scale / n;  // maps raw-patch dot -> expmap'd dot
    cbuf[tid] = th * th;         // cx2 = |u|^2
  }
  __syncthreads();

  // dot products: acc[j] = sum_ck patch[ck] * z[ck, obase+j]
  float acc[CPT];
#pragma unroll
  for (int j = 0; j < CPT; ++j) acc[j] = 0.f;
  const int obase = osg * CPT;
  {
    int ck = 0;
    for (int c = 0; c < CIN; ++c) {
      for (int iy = 0; iy < K; ++iy) {
        const float* srow = sm + (c * SY + py + iy) * SX + px;
#pragma unroll
        for (int ix = 0; ix < K; ++ix) {
          const float pv = srow[ix];
          const float4* zr4 =
              reinterpret_cast<const float4*>(z + (size_t)ck * COUT + obase);
#pragma unroll
          for (int j4 = 0; j4 < CPT / 4; ++j4) {
            float4 zv = zr4[j4];
            acc[4 * j4 + 0] = fmaf(pv, zv.x, acc[4 * j4 + 0]);
            acc[4 * j4 + 1] = fmaf(pv, zv.y, acc[4 * j4 + 1]);
            acc[4 * j4 + 2] = fmaf(pv, zv.z, acc[4 * j4 + 2]);
            acc[4 * j4 + 3] = fmaf(pv, zv.w, acc[4 * j4 + 3]);
          }
          ++ck;
        }
      }
    }
  }

  // epilogue: MLR -> sinh -> ball projection -> relu tangent (fused hrelu)
  const float g = gbuf[p];
  const float cx2 = cbuf[p];
  const float onemc = fmaxf(1.f - cx2, EPSF);
  float ls = 0.f;
#pragma unroll
  for (int j = 0; j < CPT; ++j) {
    int o = obase + j;
    float znv = znb[o];
    float num = 2.f * (g * acc[j] / znv) * chb[o] - (1.f + cx2) * shb[o];
    float mlr = 2.f * znv * asinhf(num / onemc);
    float yv = sinhf(mlr);
    acc[j] = yv;
    ls += yv * yv;
  }
  redbuf[tid] = ls;
  __syncthreads();
  if (tid < NP) {
    float s = 0.f;
    for (int k2 = 0; k2 < OS; ++k2) s += redbuf[tid + k2 * NP];
    gbuf[tid] = s;  // reuse (g already consumed by all threads)
  }
  __syncthreads();
  const float sy2 = gbuf[p];              // sum over COUT of yraw^2
  const float inv = 1.f / (1.f + sqrtf(1.f + sy2));   // ball projection
  const float ny = sqrtf(fmaxf(sy2 * inv * inv, EPSF));  // |y| after proj
  const float fs = atanhf(fminf(ny, ATANH_CAP)) / ny * inv;  // logmap0*proj
  const int oy = oy0 + py, ox = ox0 + px;
#pragma unroll
  for (int j = 0; j < CPT; ++j)
    out[(((size_t)b * COUT + obase + j) * H + oy) * W + ox] =
        fs * fmaxf(acc[j], 0.f);
}

// ---------------- Poincare FC over rows -------------------------------------
template <int NIN, int NOUT, int BLOCK>
__global__ __launch_bounds__(256) void pfc_kernel(
    const float* __restrict__ x, const float* __restrict__ z,
    const float* __restrict__ r, const float* __restrict__ zn,
    float* __restrict__ out) {
  const int b = blockIdx.x, tid = threadIdx.x;
  __shared__ float xs[NIN];
  __shared__ float red[BLOCK];
  for (int i = tid; i < NIN; i += BLOCK) xs[i] = x[(size_t)b * NIN + i];
  __syncthreads();
  float s = 0.f;
  for (int i = tid; i < NIN; i += BLOCK) { float v = xs[i]; s += v * v; }
  red[tid] = s; __syncthreads();
  for (int st = BLOCK / 2; st > 0; st >>= 1) {
    if (tid < st) red[tid] += red[tid + st];
    __syncthreads();
  }
  const float cx2 = red[0];
  __syncthreads();
  constexpr int CPT = (NOUT + BLOCK - 1) / BLOCK;
  const float onemc = fmaxf(1.f - cx2, EPSF);
  float yv[CPT];
  float ls = 0.f;
#pragma unroll
  for (int j = 0; j < CPT; ++j) {
    int o = tid + j * BLOCK;
    float y = 0.f;
    if (o < NOUT) {
      float d = 0.f;
      for (int k = 0; k < NIN; ++k) d = fmaf(xs[k], z[(size_t)k * NOUT + o], d);
      float znv = zn[o];
      float rv = r[o];
      float num = 2.f * (d / znv) * coshf(2.f * rv) - (1.f + cx2) * sinhf(2.f * rv);
      float mlr = 2.f * znv * asinhf(num / onemc);
      y = sinhf(mlr);
    }
    yv[j] = y; ls += y * y;
  }
  red[tid] = ls; __syncthreads();
  for (int st = BLOCK / 2; st > 0; st >>= 1) {
    if (tid < st) red[tid] += red[tid + st];
    __syncthreads();
  }
  const float denom = 1.f + sqrtf(1.f + red[0]);
#pragma unroll
  for (int j = 0; j < CPT; ++j) {
    int o = tid + j * BLOCK;
    if (o < NOUT) out[(size_t)b * NOUT + o] = yv[j] / denom;
  }
}

// ---------------- hrelu over rows (axis=-1) ---------------------------------
template <int N, int BLOCK>
__global__ __launch_bounds__(256) void hrelu_rows_kernel(
    const float* __restrict__ in, float* __restrict__ out) {
  const int b = blockIdx.x, tid = threadIdx.x;
  __shared__ float red[BLOCK];
  constexpr int CPT = N / BLOCK;
  float v[CPT];
  float s = 0.f;
#pragma unroll
  for (int j = 0; j < CPT; ++j) {
    v[j] = in[(size_t)b * N + tid + j * BLOCK];
    s += v[j] * v[j];
  }
  red[tid] = s; __syncthreads();
  for (int st = BLOCK / 2; st > 0; st >>= 1) {
    if (tid < st) red[tid] += red[tid + st];
    __syncthreads();
  }
  float n = sqrtf(fmaxf(red[0], EPSF));
  float f = atanhf(fminf(n, ATANH_CAP)) / n;
  __syncthreads();
  float s2 = 0.f;
#pragma unroll
  for (int j = 0; j < CPT; ++j) { v[j] = f * fmaxf(v[j], 0.f); s2 += v[j] * v[j]; }
  red[tid] = s2; __syncthreads();
  for (int st = BLOCK / 2; st > 0; st >>= 1) {
    if (tid < st) red[tid] += red[tid + st];
    __syncthreads();
  }
  float nt = sqrtf(fmaxf(red[0], EPSF));
  float gg = tanhf(nt) / nt;
#pragma unroll
  for (int j = 0; j < CPT; ++j)
    out[(size_t)b * N + tid + j * BLOCK] = gg * v[j];
}

// ---------------------------------------------------------------------------
static inline double beta_fn(double a, double b) {
  return std::exp(std::lgamma(a) + std::lgamma(b) - std::lgamma(a + b));
}

extern "C" void kernel_launch(void* const* d_in, const int* in_sizes, int n_in,
                              void* d_out, int out_size, void* d_ws, size_t ws_size,
                              hipStream_t stream) {
  const float* x   = (const float*)d_in[0];
  const float* z1  = (const float*)d_in[1];
  const float* b1  = (const float*)d_in[2];
  const float* z2  = (const float*)d_in[3];
  const float* b2  = (const float*)d_in[4];
  const float* z3  = (const float*)d_in[5];
  const float* b3  = (const float*)d_in[6];
  const float* z4  = (const float*)d_in[7];
  const float* b4  = (const float*)d_in[8];
  const float* zf1 = (const float*)d_in[9];
  const float* bf1 = (const float*)d_in[10];
  const float* zf2 = (const float*)d_in[11];
  const float* bf2 = (const float*)d_in[12];
  float* outp = (float*)d_out;

  float* ws   = (float*)d_ws;
  float* zn   = ws;                  // 2048
  float* flat = ws + 2048;           // 16*352
  float* h1r  = ws + 7680;           // 16*512
  float* h1   = ws + 15872;          // 16*512
  float* xbuf = ws + 24576;          // 2,097,152 (expmap'd pooled, avg branch)
  float* vm   = xbuf + 2097152;      // 2,097,152 (tangent: conv input / pooled)
  float* ybuf = vm + 2097152;        // 8,388,608 (conv out tangent t)
  // total: 12,607,488 floats = 50.4 MB

  const float s1 = (float)(beta_fn(27.0 / 2.0, 0.5) / beta_fn(3.0 / 2.0, 0.5));
  const float s2 = (float)(beta_fn(800.0 / 2.0, 0.5) / beta_fn(32.0 / 2.0, 0.5));
  const float s3 = (float)(beta_fn(3136.0 / 2.0, 0.5) / beta_fn(64.0 / 2.0, 0.5));
  const float s4 = (float)(beta_fn(1152.0 / 2.0, 0.5) / beta_fn(128.0 / 2.0, 0.5));

  auto g1 = [](int n) { return dim3((n + 255) / 256); };

  // z column norms (parallel over K)
  znorm_kernel<<<2,  256, 0, stream>>>(z1, zn + 0, 27, 32);
  znorm_kernel<<<4,  256, 0, stream>>>(z2, zn + 32, 800, 64);
  znorm_kernel<<<8,  256, 0, stream>>>(z3, zn + 96, 3136, 128);
  znorm_kernel<<<8,  256, 0, stream>>>(z4, zn + 224, 1152, 128);
  znorm_kernel<<<32, 256, 0, stream>>>(zf1, zn + 352, 352, 512);
  znorm_kernel<<<63, 256, 0, stream>>>(zf2, zn + 864, 512, 1000);

  // ---- layer 1: (16,3,128,128) -> t1 (16,32,128,128) -> m1 (16,32,64,64)
  map0_kernel<0><<<g1(262144), 256, 0, stream>>>(x, vm, 3, 128 * 128, 262144);
  hconv_kernel<3, 3, 1, 32, 128, 128, 8, 8><<<4096, 256, 0, stream>>>(vm, z1, b1, zn + 0, ybuf, s1);
  maxpool_kernel<<<g1(2097152), 256, 0, stream>>>(ybuf, vm, 32, 128, 128, 2097152);
  map0_kernel<1><<<g1(65536), 256, 0, stream>>>(vm, xbuf, 32, 64 * 64, 65536);
  avgpool_kernel<<<dim3(32, 16), 256, 0, stream>>>(xbuf, flat, 32, 4096, 352, 0);

  // ---- layer 2: m1 -> t2 (16,64,64,64) -> m2 (16,64,32,32)
  hconv_kernel<32, 5, 2, 64, 64, 64, 4, 8><<<2048, 256, 0, stream>>>(vm, z2, b2, zn + 32, ybuf, s2);
  maxpool_kernel<<<g1(1048576), 256, 0, stream>>>(ybuf, vm, 64, 64, 64, 1048576);
  map0_kernel<1><<<g1(16384), 256, 0, stream>>>(vm, xbuf, 64, 32 * 32, 16384);
  avgpool_kernel<<<dim3(64, 16), 256, 0, stream>>>(xbuf, flat, 64, 1024, 352, 32);

  // ---- layer 3: m2 -> t3 (16,128,32,32) -> m3 (16,128,16,16)
  hconv_kernel<64, 7, 3, 128, 32, 32, 4, 4><<<1024, 256, 0, stream>>>(vm, z3, b3, zn + 96, ybuf, s3);
  maxpool_kernel<<<g1(524288), 256, 0, stream>>>(ybuf, vm, 128, 32, 32, 524288);
  map0_kernel<1><<<g1(4096), 256, 0, stream>>>(vm, xbuf, 128, 16 * 16, 4096);
  avgpool_kernel<<<dim3(128, 16), 256, 0, stream>>>(xbuf, flat, 128, 256, 352, 96);

  // ---- layer 4: m3 -> t4 (16,128,16,16) -> m4 (16,128,8,8)
  hconv_kernel<128, 3, 1, 128, 16, 16, 2, 4><<<512, 256, 0, stream>>>(vm, z4, b4, zn + 224, ybuf, s4);
  maxpool_kernel<<<g1(131072), 256, 0, stream>>>(ybuf, vm, 128, 16, 16, 131072);
  map0_kernel<1><<<g1(1024), 256, 0, stream>>>(vm, xbuf, 128, 8 * 8, 1024);
  avgpool_kernel<<<dim3(128, 16), 256, 0, stream>>>(xbuf, flat, 128, 64, 352, 224);

  // ---- head: flat (16,352) -> (16,512) -> hrelu -> (16,1000)
  pfc_kernel<352, 512, 256><<<16, 256, 0, stream>>>(flat, zf1, bf1, zn + 352, h1r);
  hrelu_rows_kernel<512, 256><<<16, 256, 0, stream>>>(h1r, h1);
  pfc_kernel<512, 1000, 256><<<16, 256, 0, stream>>>(h1, zf2, bf2, zn + 864, outp);

  (void)in_sizes; (void)n_in; (void)out_size; (void)ws_size;
}

// Round 3
// 807.417 us; speedup vs baseline: 3.8104x; 2.1559x over previous
//
#include <hip/hip_runtime.h>
#include <cmath>

// ---------------------------------------------------------------------------
// Hyperbolic MS-CNN (Poincare ball, c=1) — round 3: MFMA convs.
//
// Convs are GEMMs [M=B*H*W, K=CIN*KK, N=COUT] done with mfma_f32_16x16x32_bf16
// in split precision (A,B each = bf16_hi + bf16_lo; 3 MFMAs per tile:
// hi*hi + hi*lo + lo*hi; residual ~2^-16 relative).
// K-dimension is reordered tap-major: k_new = tap*CIN_PAD + c (CIN_PAD = CIN
// padded to >=32). A 32-wide K-step then lies inside ONE tap covering 32
// consecutive channels -> A fragments come from 2 ds_read_b128 out of a
// channel-last LDS window. z is pre-permuted into exact B-fragment order.
// ---------------------------------------------------------------------------

#define EPSF 1e-15f
#define ATANH_CAP 0.9999999f  // 1 - 1e-7

typedef __attribute__((ext_vector_type(8))) short short8;
typedef __attribute__((ext_vector_type(4))) float f32x4;

__device__ inline unsigned rne16(float f) {
  unsigned u = __float_as_uint(f);
  return (u + 0x7FFFu + ((u >> 16) & 1u)) >> 16;
}

// ---------------- z column norms (parallel over K and columns) --------------
__global__ __launch_bounds__(256) void znorm_kernel(
    const float* __restrict__ z, float* __restrict__ zn, int K, int Nout) {
  const int tid = threadIdx.x;
  const int col = (blockIdx.x << 4) + (tid & 15);
  const int kg = tid >> 4;
  float s = 0.f;
  if (col < Nout)
    for (int k = kg; k < K; k += 16) {
      float v = z[(size_t)k * Nout + col];
      s += v * v;
    }
  __shared__ float red[256];
  red[tid] = s;
  __syncthreads();
  if (tid < 16) {
    float t = 0.f;
#pragma unroll
    for (int j = 0; j < 16; ++j) t += red[tid + (j << 4)];
    if (col < Nout) zn[col] = sqrtf(fmaxf(t, EPSF));
  }
}

// ---------------- z -> MFMA-fragment-ordered hi/lo bf16 ---------------------
// B-frag convention: for tile (ks, nt), lane l supplies B[k][n] with
// k = ks*32 + (l>>4)*8 + i, n = nt*16 + (l&15), i = 0..7 contiguous ushorts.
template <int CIN, int CSH, int KK, int COUT>
__global__ __launch_bounds__(256) void zfprep_kernel(
    const float* __restrict__ z, unsigned short* __restrict__ zh,
    unsigned short* __restrict__ zl) {
  constexpr int CPAD = 1 << CSH;
  constexpr int KP = KK * CPAD;
  constexpr int NT = COUT / 16;
  int t = blockIdx.x * 256 + threadIdx.x;
  if (t >= KP * COUT) return;
  int k = t / COUT, n = t - k * COUT;
  int ks = k >> 5, lg = (k >> 3) & 3, i = k & 7;
  int nt = n >> 4, lm = n & 15;
  size_t e = ((size_t)(ks * NT + nt) * 64 + lg * 16 + lm) * 8 + i;
  int tap = k >> CSH, c = k & (CPAD - 1);
  float val = (c < CIN) ? z[(size_t)(c * KK + tap) * COUT + n] : 0.f;
  unsigned hi = rne16(val);
  float hif = __uint_as_float(hi << 16);
  unsigned lo = rne16(val - hif);
  zh[e] = (unsigned short)hi;
  zl[e] = (unsigned short)lo;
}

// ---------------- logmap0 + per-pixel sum of squares ------------------------
__global__ __launch_bounds__(256) void logmap_s2_kernel(
    const float* __restrict__ in, float* __restrict__ out,
    float* __restrict__ s2, int C, int HW, int total) {
  int i = blockIdx.x * blockDim.x + threadIdx.x;
  if (i >= total) return;
  int b = i / HW, s = i - b * HW;
  const float* p = in + (size_t)b * C * HW + s;
  float ss = 0.f;
  for (int c = 0; c < C; ++c) { float v = p[(size_t)c * HW]; ss += v * v; }
  float n = sqrtf(fmaxf(ss, EPSF));
  float f = atanhf(fminf(n, ATANH_CAP)) / n;
  float* q = out + (size_t)b * C * HW + s;
  for (int c = 0; c < C; ++c) q[(size_t)c * HW] = f * p[(size_t)c * HW];
  s2[i] = f * f * ss;
}

// ---------------- expmap0 over channel axis ---------------------------------
__global__ __launch_bounds__(256) void expmap_kernel(
    const float* __restrict__ in, float* __restrict__ out,
    int C, int HW, int total) {
  int i = blockIdx.x * blockDim.x + threadIdx.x;
  if (i >= total) return;
  int b = i / HW, s = i - b * HW;
  const float* p = in + (size_t)b * C * HW + s;
  float ss = 0.f;
  for (int c = 0; c < C; ++c) { float v = p[(size_t)c * HW]; ss += v * v; }
  float n = sqrtf(fmaxf(ss, EPSF));
  float f = tanhf(n) / n;
  float* q = out + (size_t)b * C * HW + s;
  for (int c = 0; c < C; ++c) q[(size_t)c * HW] = f * p[(size_t)c * HW];
}

// ---------------- per-pixel sum of squares over channels --------------------
__global__ __launch_bounds__(256) void s2_kernel(
    const float* __restrict__ m, float* __restrict__ s2,
    int C, int HW, int total) {
  int i = blockIdx.x * blockDim.x + threadIdx.x;
  if (i >= total) return;
  int b = i / HW, s = i - b * HW;
  const float* p = m + (size_t)b * C * HW + s;
  float ss = 0.f;
  for (int c = 0; c < C; ++c) { float v = p[(size_t)c * HW]; ss += v * v; }
  s2[i] = ss;
}

// ---------------- 2x2 stride-2 channelwise max (tangent space) --------------
__global__ __launch_bounds__(256) void maxpool_kernel(
    const float* __restrict__ t, float* __restrict__ m,
    int C, int H, int W, int total) {
  int i = blockIdx.x * blockDim.x + threadIdx.x;
  if (i >= total) return;
  int HO = H >> 1, WO = W >> 1;
  int wo = i % WO; int rest = i / WO;
  int ho = rest % HO; rest /= HO;
  int c = rest % C;  int b = rest / C;
  const float* p = t + (((size_t)(b * C + c) * H + 2 * ho) * W + 2 * wo);
  m[i] = fmaxf(fmaxf(p[0], p[1]), fmaxf(p[W], p[W + 1]));
}

// ---------------- spatial mean into flat segment ----------------------------
__global__ __launch_bounds__(256) void avgpool_kernel(
    const float* __restrict__ x, float* __restrict__ flat,
    int C, int HW, int flatC, int coff) {
  int c = blockIdx.x, b = blockIdx.y, tid = threadIdx.x;
  const float* p = x + ((size_t)b * C + c) * HW;
  float s = 0.f;
  for (int i = tid; i < HW; i += blockDim.x) s += p[i];
  __shared__ float red[256];
  red[tid] = s; __syncthreads();
  for (int st = 128; st > 0; st >>= 1) {
    if (tid < st) red[tid] += red[tid + st];
    __syncthreads();
  }
  if (tid == 0) flat[(size_t)b * flatC + coff + c] = red[0] / (float)HW;
}

// ---------------- MFMA fused hconv ------------------------------------------
// vin: tangent (B,CIN,H,W); s2map: per-pixel sum_c vin^2 (B,H,W)
// out: t = atanh(|y|)/|y| * relu(y) tangent (B,COUT,H,W)
template <int CIN, int CSH, int K, int PAD, int COUT, int H, int W,
          int TH, int TW, int WAVES>
__global__ __launch_bounds__(WAVES * 64) void hconv_mfma(
    const float* __restrict__ vin, const float* __restrict__ s2map,
    const unsigned short* __restrict__ zfh,
    const unsigned short* __restrict__ zfl,
    const float* __restrict__ r, const float* __restrict__ zn,
    float* __restrict__ out, float scale) {
  constexpr int NTHR = WAVES * 64;
  constexpr int CPAD = 1 << CSH;
  constexpr int KK = K * K;
  constexpr int MT = WAVES * 16;      // rows per block (== TH*TW)
  constexpr int NT = COUT / 16;       // 16-col tiles
  constexpr int NK = KK * CPAD / 32;  // K-steps
  constexpr int SY = TH + K - 1, SX = TW + K - 1;
  constexpr int NPOS = SY * SX;
  constexpr int RW = CPAD + 4;        // padded row stride (words)
  constexpr int TRS = MT + 4;         // trans row stride (floats)
  constexpr int WINW = NPOS * RW;
  constexpr int TRW = COUT * TRS;
  constexpr int SHW = (WINW > TRW) ? WINW : TRW;

  __shared__ unsigned win[SHW];
  __shared__ float s2w[NPOS];
  __shared__ float gA[MT], cA[MT];
  __shared__ float chb[COUT], shb[COUT], znb[COUT];

  const int tid = threadIdx.x;
  int bid = blockIdx.x;
  constexpr int TXC = W / TW, TYC = H / TH;
  const int tx = bid % TXC; bid /= TXC;
  const int ty = bid % TYC; const int b = bid / TYC;
  const int y0 = ty * TH, x0 = tx * TW;

  if (tid < COUT) {
    float rv = r[tid];
    chb[tid] = coshf(2.f * rv);
    shb[tid] = sinhf(2.f * rv);
    znb[tid] = zn[tid];
  }
  // stage window (channel-last, hi/lo bf16 packed in u32) + zero padding
  const float* vb = vin + (size_t)b * CIN * H * W;
  for (int idx = tid; idx < CPAD * NPOS; idx += NTHR) {
    int c = idx / NPOS;
    int pos = idx - c * NPOS;
    int sy = pos / SX, sx = pos - sy * SX;
    float val = 0.f;
    if (c < CIN) {
      int gy = y0 + sy - PAD, gx = x0 + sx - PAD;
      if (gy >= 0 && gy < H && gx >= 0 && gx < W)
        val = vb[((size_t)c * H + gy) * W + gx];
    }
    unsigned hi = rne16(val);
    float hif = __uint_as_float(hi << 16);
    unsigned lo = rne16(val - hif);
    win[pos * RW + c] = (hi << 16) | lo;
  }
  // stage s2 window
  const float* s2b = s2map + (size_t)b * H * W;
  for (int i = tid; i < NPOS; i += NTHR) {
    int sy = i / SX, sx = i - sy * SX;
    int gy = y0 + sy - PAD, gx = x0 + sx - PAD;
    s2w[i] = (gy >= 0 && gy < H && gx >= 0 && gx < W) ? s2b[gy * W + gx] : 0.f;
  }
  __syncthreads();

  // per-row patch norms
  if (tid < MT) {
    int py = tid / TW, px = tid - (tid / TW) * TW;
    float s = 0.f;
    for (int iy = 0; iy < K; ++iy)
      for (int ix = 0; ix < K; ++ix)
        s += s2w[(py + iy) * SX + (px + ix)];
    float n = sqrtf(fmaxf(scale * scale * s, EPSF));
    float th = tanhf(n);
    gA[tid] = th * scale / n;
    cA[tid] = th * th;
  }

  const int lane = tid & 63, wv = tid >> 6;
  const int lm = lane & 15, lg = lane >> 4;
  const int m = wv * 16 + lm;
  const int py = m / TW, px = m - (m / TW) * TW;

  f32x4 acc[NT];
#pragma unroll
  for (int nt = 0; nt < NT; ++nt) acc[nt] = (f32x4){0.f, 0.f, 0.f, 0.f};

  for (int ks = 0; ks < NK; ++ks) {
    const int tap = (ks * 32) >> CSH;
    const int c0 = (ks * 32) & (CPAD - 1);
    const int iy = tap / K, ix = tap - (tap / K) * K;
    const int pos = (py + iy) * SX + (px + ix);
    const unsigned* wp = win + pos * RW + c0 + lg * 8;
    uint4 w0 = *(const uint4*)wp;
    uint4 w1 = *(const uint4*)(wp + 4);
    short8 ahi, alo;
    ahi[0] = (short)(w0.x >> 16); alo[0] = (short)(w0.x & 0xFFFF);
    ahi[1] = (short)(w0.y >> 16); alo[1] = (short)(w0.y & 0xFFFF);
    ahi[2] = (short)(w0.z >> 16); alo[2] = (short)(w0.z & 0xFFFF);
    ahi[3] = (short)(w0.w >> 16); alo[3] = (short)(w0.w & 0xFFFF);
    ahi[4] = (short)(w1.x >> 16); alo[4] = (short)(w1.x & 0xFFFF);
    ahi[5] = (short)(w1.y >> 16); alo[5] = (short)(w1.y & 0xFFFF);
    ahi[6] = (short)(w1.z >> 16); alo[6] = (short)(w1.z & 0xFFFF);
    ahi[7] = (short)(w1.w >> 16); alo[7] = (short)(w1.w & 0xFFFF);

    const unsigned short* bh = zfh + (size_t)(ks * NT) * 512 + lane * 8;
    const unsigned short* bl = zfl + (size_t)(ks * NT) * 512 + lane * 8;
    uint4 Bh[NT], Bl[NT];
#pragma unroll
    for (int nt = 0; nt < NT; ++nt) {
      Bh[nt] = *(const uint4*)(bh + nt * 512);
      Bl[nt] = *(const uint4*)(bl + nt * 512);
    }
#pragma unroll
    for (int nt = 0; nt < NT; ++nt) {
      short8 bhv = __builtin_bit_cast(short8, Bh[nt]);
      short8 blv = __builtin_bit_cast(short8, Bl[nt]);
      acc[nt] = __builtin_amdgcn_mfma_f32_16x16x32_bf16(ahi, bhv, acc[nt], 0, 0, 0);
      acc[nt] = __builtin_amdgcn_mfma_f32_16x16x32_bf16(ahi, blv, acc[nt], 0, 0, 0);
      acc[nt] = __builtin_amdgcn_mfma_f32_16x16x32_bf16(alo, bhv, acc[nt], 0, 0, 0);
    }
  }
  __syncthreads();  // all waves done with win; safe to overlay trans

  // epilogue: D row = wv*16 + lg*4 + reg, col = nt*16 + lm
  float ls[4] = {0.f, 0.f, 0.f, 0.f};
  float gR[4], cR[4];
#pragma unroll
  for (int reg = 0; reg < 4; ++reg) {
    int rr = wv * 16 + lg * 4 + reg;
    gR[reg] = gA[rr]; cR[reg] = cA[rr];
  }
#pragma unroll
  for (int nt = 0; nt < NT; ++nt) {
    int o = nt * 16 + lm;
    float znv = znb[o], ch = chb[o], sh = shb[o];
#pragma unroll
    for (int reg = 0; reg < 4; ++reg) {
      float onemc = fmaxf(1.f - cR[reg], EPSF);
      float num = 2.f * (gR[reg] * acc[nt][reg] / znv) * ch - (1.f + cR[reg]) * sh;
      float mlr = 2.f * znv * asinhf(num / onemc);
      float yv = sinhf(mlr);
      acc[nt][reg] = yv;
      ls[reg] += yv * yv;
    }
  }
#pragma unroll
  for (int mask = 1; mask < 16; mask <<= 1) {
#pragma unroll
    for (int reg = 0; reg < 4; ++reg)
      ls[reg] += __shfl_xor(ls[reg], mask);
  }
  float fs[4];
#pragma unroll
  for (int reg = 0; reg < 4; ++reg) {
    float inv = 1.f / (1.f + sqrtf(1.f + ls[reg]));
    float ny = sqrtf(fmaxf(ls[reg] * inv * inv, EPSF));
    fs[reg] = atanhf(fminf(ny, ATANH_CAP)) / ny * inv;
  }
  float* tr = (float*)win;  // [COUT][TRS]
#pragma unroll
  for (int nt = 0; nt < NT; ++nt) {
    int o = nt * 16 + lm;
#pragma unroll
    for (int reg = 0; reg < 4; ++reg) {
      int rr = wv * 16 + lg * 4 + reg;
      tr[o * TRS + rr] = fs[reg] * fmaxf(acc[nt][reg], 0.f);
    }
  }
  __syncthreads();

  // coalesced store: rows of TW floats
  for (int i = tid; i < COUT * TH; i += NTHR) {
    int co = i / TH, pyy = i - (i / TH) * TH;
    const float* src = tr + co * TRS + pyy * TW;
    float* dst = out + (((size_t)b * COUT + co) * H + y0 + pyy) * W + x0;
    *(float4*)dst = *(const float4*)src;
    *(float4*)(dst + 4) = *(const float4*)(src + 4);
  }
}

// ---------------- Poincare FC over rows -------------------------------------
template <int NIN, int NOUT, int BLOCK>
__global__ __launch_bounds__(256) void pfc_kernel(
    const float* __restrict__ x, const float* __restrict__ z,
    const float* __restrict__ r, const float* __restrict__ zn,
    float* __restrict__ out) {
  const int b = blockIdx.x, tid = threadIdx.x;
  __shared__ float xs[NIN];
  __shared__ float red[BLOCK];
  for (int i = tid; i < NIN; i += BLOCK) xs[i] = x[(size_t)b * NIN + i];
  __syncthreads();
  float s = 0.f;
  for (int i = tid; i < NIN; i += BLOCK) { float v = xs[i]; s += v * v; }
  red[tid] = s; __syncthreads();
  for (int st = BLOCK / 2; st > 0; st >>= 1) {
    if (tid < st) red[tid] += red[tid + st];
    __syncthreads();
  }
  const float cx2 = red[0];
  __syncthreads();
  constexpr int CPT = (NOUT + BLOCK - 1) / BLOCK;
  const float onemc = fmaxf(1.f - cx2, EPSF);
  float yv[CPT];
  float ls = 0.f;
#pragma unroll
  for (int j = 0; j < CPT; ++j) {
    int o = tid + j * BLOCK;
    float y = 0.f;
    if (o < NOUT) {
      float d = 0.f;
      for (int k = 0; k < NIN; ++k) d = fmaf(xs[k], z[(size_t)k * NOUT + o], d);
      float znv = zn[o];
      float rv = r[o];
      float num = 2.f * (d / znv) * coshf(2.f * rv) - (1.f + cx2) * sinhf(2.f * rv);
      float mlr = 2.f * znv * asinhf(num / onemc);
      y = sinhf(mlr);
    }
    yv[j] = y; ls += y * y;
  }
  red[tid] = ls; __syncthreads();
  for (int st = BLOCK / 2; st > 0; st >>= 1) {
    if (tid < st) red[tid] += red[tid + st];
    __syncthreads();
  }
  const float denom = 1.f + sqrtf(1.f + red[0]);
#pragma unroll
  for (int j = 0; j < CPT; ++j) {
    int o = tid + j * BLOCK;
    if (o < NOUT) out[(size_t)b * NOUT + o] = yv[j] / denom;
  }
}

// ---------------- hrelu over rows (axis=-1) ---------------------------------
template <int N, int BLOCK>
__global__ __launch_bounds__(256) void hrelu_rows_kernel(
    const float* __restrict__ in, float* __restrict__ out) {
  const int b = blockIdx.x, tid = threadIdx.x;
  __shared__ float red[BLOCK];
  constexpr int CPT = N / BLOCK;
  float v[CPT];
  float s = 0.f;
#pragma unroll
  for (int j = 0; j < CPT; ++j) {
    v[j] = in[(size_t)b * N + tid + j * BLOCK];
    s += v[j] * v[j];
  }
  red[tid] = s; __syncthreads();
  for (int st = BLOCK / 2; st > 0; st >>= 1) {
    if (tid < st) red[tid] += red[tid + st];
    __syncthreads();
  }
  float n = sqrtf(fmaxf(red[0], EPSF));
  float f = atanhf(fminf(n, ATANH_CAP)) / n;
  __syncthreads();
  float s2 = 0.f;
#pragma unroll
  for (int j = 0; j < CPT; ++j) { v[j] = f * fmaxf(v[j], 0.f); s2 += v[j] * v[j]; }
  red[tid] = s2; __syncthreads();
  for (int st = BLOCK / 2; st > 0; st >>= 1) {
    if (tid < st) red[tid] += red[tid + st];
    __syncthreads();
  }
  float nt = sqrtf(fmaxf(red[0], EPSF));
  float gg = tanhf(nt) / nt;
#pragma unroll
  for (int j = 0; j < CPT; ++j)
    out[(size_t)b * N + tid + j * BLOCK] = gg * v[j];
}

// ---------------------------------------------------------------------------
static inline double beta_fn(double a, double b) {
  return std::exp(std::lgamma(a) + std::lgamma(b) - std::lgamma(a + b));
}

extern "C" void kernel_launch(void* const* d_in, const int* in_sizes, int n_in,
                              void* d_out, int out_size, void* d_ws, size_t ws_size,
                              hipStream_t stream) {
  const float* x   = (const float*)d_in[0];
  const float* z1  = (const float*)d_in[1];
  const float* b1  = (const float*)d_in[2];
  const float* z2  = (const float*)d_in[3];
  const float* b2  = (const float*)d_in[4];
  const float* z3  = (const float*)d_in[5];
  const float* b3  = (const float*)d_in[6];
  const float* z4  = (const float*)d_in[7];
  const float* b4  = (const float*)d_in[8];
  const float* zf1 = (const float*)d_in[9];
  const float* bf1 = (const float*)d_in[10];
  const float* zf2 = (const float*)d_in[11];
  const float* bf2 = (const float*)d_in[12];
  float* outp = (float*)d_out;

  float* ws   = (float*)d_ws;
  float* zn   = ws;                       // 2048
  float* flat = ws + 2048;                // 16*352
  float* h1r  = ws + 7680;                // 16*512
  float* h1   = ws + 15872;               // 16*512
  float* xbuf = ws + 24576;               // 2,097,152
  float* vm   = xbuf + 2097152;           // 2,097,152
  float* ybuf = vm + 2097152;             // 8,388,608
  float* s2a  = ws + 12607488;            // 262,144
  unsigned short* zfu = (unsigned short*)(ws + 12869632);
  unsigned short* zf1h = zfu;             //   9,216
  unsigned short* zf1l = zfu + 9216;
  unsigned short* zf2h = zfu + 18432;     //  51,200
  unsigned short* zf2l = zfu + 69632;
  unsigned short* zf3h = zfu + 120832;    // 401,408
  unsigned short* zf3l = zfu + 522240;
  unsigned short* zf4h = zfu + 923648;    // 147,456
  unsigned short* zf4l = zfu + 1071104;   // ends 1,218,560 (total ~53.9 MB)

  const float s1 = (float)(beta_fn(27.0 / 2.0, 0.5) / beta_fn(3.0 / 2.0, 0.5));
  const float s2c = (float)(beta_fn(800.0 / 2.0, 0.5) / beta_fn(32.0 / 2.0, 0.5));
  const float s3 = (float)(beta_fn(3136.0 / 2.0, 0.5) / beta_fn(64.0 / 2.0, 0.5));
  const float s4 = (float)(beta_fn(1152.0 / 2.0, 0.5) / beta_fn(128.0 / 2.0, 0.5));

  auto g1 = [](int n) { return dim3((n + 255) / 256); };

  // prep: column norms + fragment-ordered hi/lo z
  znorm_kernel<<<2,  256, 0, stream>>>(z1, zn + 0, 27, 32);
  znorm_kernel<<<4,  256, 0, stream>>>(z2, zn + 32, 800, 64);
  znorm_kernel<<<8,  256, 0, stream>>>(z3, zn + 96, 3136, 128);
  znorm_kernel<<<8,  256, 0, stream>>>(z4, zn + 224, 1152, 128);
  znorm_kernel<<<32, 256, 0, stream>>>(zf1, zn + 352, 352, 512);
  znorm_kernel<<<63, 256, 0, stream>>>(zf2, zn + 864, 512, 1000);
  zfprep_kernel<3, 5, 9, 32><<<36, 256, 0, stream>>>(z1, zf1h, zf1l);
  zfprep_kernel<32, 5, 25, 64><<<200, 256, 0, stream>>>(z2, zf2h, zf2l);
  zfprep_kernel<64, 6, 49, 128><<<1568, 256, 0, stream>>>(z3, zf3h, zf3l);
  zfprep_kernel<128, 7, 9, 128><<<576, 256, 0, stream>>>(z4, zf4h, zf4l);

  // ---- layer 1: (16,3,128,128) -> t1 (16,32,128,128) -> m1 (16,32,64,64)
  logmap_s2_kernel<<<g1(262144), 256, 0, stream>>>(x, vm, s2a, 3, 16384, 262144);
  hconv_mfma<3, 5, 3, 1, 32, 128, 128, 8, 8, 4>
      <<<4096, 256, 0, stream>>>(vm, s2a, zf1h, zf1l, b1, zn + 0, ybuf, s1);
  maxpool_kernel<<<g1(2097152), 256, 0, stream>>>(ybuf, vm, 32, 128, 128, 2097152);
  s2_kernel<<<g1(65536), 256, 0, stream>>>(vm, s2a, 32, 4096, 65536);
  expmap_kernel<<<g1(65536), 256, 0, stream>>>(vm, xbuf, 32, 4096, 65536);
  avgpool_kernel<<<dim3(32, 16), 256, 0, stream>>>(xbuf, flat, 32, 4096, 352, 0);

  // ---- layer 2: m1 -> t2 (16,64,64,64) -> m2 (16,64,32,32)
  hconv_mfma<32, 5, 5, 2, 64, 64, 64, 8, 8, 4>
      <<<1024, 256, 0, stream>>>(vm, s2a, zf2h, zf2l, b2, zn + 32, ybuf, s2c);
  maxpool_kernel<<<g1(1048576), 256, 0, stream>>>(ybuf, vm, 64, 64, 64, 1048576);
  s2_kernel<<<g1(16384), 256, 0, stream>>>(vm, s2a, 64, 1024, 16384);
  expmap_kernel<<<g1(16384), 256, 0, stream>>>(vm, xbuf, 64, 1024, 16384);
  avgpool_kernel<<<dim3(64, 16), 256, 0, stream>>>(xbuf, flat, 64, 1024, 352, 32);

  // ---- layer 3: m2 -> t3 (16,128,32,32) -> m3 (16,128,16,16)
  hconv_mfma<64, 6, 7, 3, 128, 32, 32, 4, 8, 2>
      <<<512, 128, 0, stream>>>(vm, s2a, zf3h, zf3l, b3, zn + 96, ybuf, s3);
  maxpool_kernel<<<g1(524288), 256, 0, stream>>>(ybuf, vm, 128, 32, 32, 524288);
  s2_kernel<<<g1(4096), 256, 0, stream>>>(vm, s2a, 128, 256, 4096);
  expmap_kernel<<<g1(4096), 256, 0, stream>>>(vm, xbuf, 128, 256, 4096);
  avgpool_kernel<<<dim3(128, 16), 256, 0, stream>>>(xbuf, flat, 128, 256, 352, 96);

  // ---- layer 4: m3 -> t4 (16,128,16,16) -> m4 (16,128,8,8)
  hconv_mfma<128, 7, 3, 1, 128, 16, 16, 4, 8, 2>
      <<<128, 128, 0, stream>>>(vm, s2a, zf4h, zf4l, b4, zn + 224, ybuf, s4);
  maxpool_kernel<<<g1(131072), 256, 0, stream>>>(ybuf, vm, 128, 16, 16, 131072);
  expmap_kernel<<<g1(1024), 256, 0, stream>>>(vm, xbuf, 128, 64, 1024);
  avgpool_kernel<<<dim3(128, 16), 256, 0, stream>>>(xbuf, flat, 128, 64, 352, 224);

  // ---- head: flat (16,352) -> (16,512) -> hrelu -> (16,1000)
  pfc_kernel<352, 512, 256><<<16, 256, 0, stream>>>(flat, zf1, bf1, zn + 352, h1r);
  hrelu_rows_kernel<512, 256><<<16, 256, 0, stream>>>(h1r, h1);
  pfc_kernel<512, 1000, 256><<<16, 256, 0, stream>>>(h1, zf2, bf2, zn + 864, outp);

  (void)in_sizes; (void)n_in; (void)out_size; (void)ws_size;
}

// Round 4
// 593.967 us; speedup vs baseline: 5.1797x; 1.3594x over previous
//
#include <hip/hip_runtime.h>
#include <cmath>

// ---------------------------------------------------------------------------
// Hyperbolic MS-CNN (Poincare ball, c=1) — round 4.
// MFMA convs with N-split waves (occupancy), hi/lo bf16 LDS planes (no VALU
// unpack), fused expmap+avgpool feature branch.
// ---------------------------------------------------------------------------

#define EPSF 1e-15f
#define ATANH_CAP 0.9999999f  // 1 - 1e-7

typedef __attribute__((ext_vector_type(8))) short short8;
typedef __attribute__((ext_vector_type(4))) float f32x4;

__device__ inline unsigned rne16(float f) {
  unsigned u = __float_as_uint(f);
  return (u + 0x7FFFu + ((u >> 16) & 1u)) >> 16;
}

// ---------------- z column norms (parallel over K and columns) --------------
__global__ __launch_bounds__(256) void znorm_kernel(
    const float* __restrict__ z, float* __restrict__ zn, int K, int Nout) {
  const int tid = threadIdx.x;
  const int col = (blockIdx.x << 4) + (tid & 15);
  const int kg = tid >> 4;
  float s = 0.f;
  if (col < Nout)
    for (int k = kg; k < K; k += 16) {
      float v = z[(size_t)k * Nout + col];
      s += v * v;
    }
  __shared__ float red[256];
  red[tid] = s;
  __syncthreads();
  if (tid < 16) {
    float t = 0.f;
#pragma unroll
    for (int j = 0; j < 16; ++j) t += red[tid + (j << 4)];
    if (col < Nout) zn[col] = sqrtf(fmaxf(t, EPSF));
  }
}

// ---------------- z -> MFMA-fragment-ordered hi/lo bf16 ---------------------
// tile (ks, nt): lane l supplies B[k][n], k = ks*32+(l>>4)*8+i, n = nt*16+(l&15)
template <int CIN, int CSH, int KK, int COUT>
__global__ __launch_bounds__(256) void zfprep_kernel(
    const float* __restrict__ z, unsigned short* __restrict__ zh,
    unsigned short* __restrict__ zl) {
  constexpr int CPAD = 1 << CSH;
  constexpr int KP = KK * CPAD;
  constexpr int NT = COUT / 16;
  int t = blockIdx.x * 256 + threadIdx.x;
  if (t >= KP * COUT) return;
  int k = t / COUT, n = t - k * COUT;
  int ks = k >> 5, lg = (k >> 3) & 3, i = k & 7;
  int nt = n >> 4, lm = n & 15;
  size_t e = ((size_t)(ks * NT + nt) * 64 + lg * 16 + lm) * 8 + i;
  int tap = k >> CSH, c = k & (CPAD - 1);
  float val = (c < CIN) ? z[(size_t)(c * KK + tap) * COUT + n] : 0.f;
  unsigned hi = rne16(val);
  float hif = __uint_as_float(hi << 16);
  unsigned lo = rne16(val - hif);
  zh[e] = (unsigned short)hi;
  zl[e] = (unsigned short)lo;
}

// ---------------- logmap0 + per-pixel sum of squares ------------------------
__global__ __launch_bounds__(256) void logmap_s2_kernel(
    const float* __restrict__ in, float* __restrict__ out,
    float* __restrict__ s2, int C, int HW, int total) {
  int i = blockIdx.x * blockDim.x + threadIdx.x;
  if (i >= total) return;
  int b = i / HW, s = i - b * HW;
  const float* p = in + (size_t)b * C * HW + s;
  float ss = 0.f;
  for (int c = 0; c < C; ++c) { float v = p[(size_t)c * HW]; ss += v * v; }
  float n = sqrtf(fmaxf(ss, EPSF));
  float f = atanhf(fminf(n, ATANH_CAP)) / n;
  float* q = out + (size_t)b * C * HW + s;
  for (int c = 0; c < C; ++c) q[(size_t)c * HW] = f * p[(size_t)c * HW];
  s2[i] = f * f * ss;
}

// ---------------- fmap: per-pixel s2 (for next conv) + expmap weight --------
__global__ __launch_bounds__(256) void fmap_kernel(
    const float* __restrict__ vm, float* __restrict__ s2out,
    float* __restrict__ fout, int C, int HW, int total) {
  int i = blockIdx.x * blockDim.x + threadIdx.x;
  if (i >= total) return;
  int b = i / HW, s = i - b * HW;
  const float* p = vm + (size_t)b * C * HW + s;
  float ss = 0.f;
  for (int c = 0; c < C; ++c) { float v = p[(size_t)c * HW]; ss += v * v; }
  float n = sqrtf(fmaxf(ss, EPSF));
  s2out[i] = ss;
  fout[i] = tanhf(n) / n;
}

// ---------------- 2x2 stride-2 channelwise max (tangent space) --------------
__global__ __launch_bounds__(256) void maxpool_kernel(
    const float* __restrict__ t, float* __restrict__ m,
    int C, int H, int W, int total) {
  int i = blockIdx.x * blockDim.x + threadIdx.x;
  if (i >= total) return;
  int HO = H >> 1, WO = W >> 1;
  int wo = i % WO; int rest = i / WO;
  int ho = rest % HO; rest /= HO;
  int c = rest % C;  int b = rest / C;
  const float* p = t + (((size_t)(b * C + c) * H + 2 * ho) * W + 2 * wo);
  m[i] = fmaxf(fmaxf(p[0], p[1]), fmaxf(p[W], p[W + 1]));
}

// ---------------- weighted spatial mean: flat = (1/HW) sum f[i]*vm[c][i] ----
__global__ __launch_bounds__(256) void wavgpool_kernel(
    const float* __restrict__ vm, const float* __restrict__ f,
    float* __restrict__ flat, int C, int HW, int flatC, int coff) {
  int c = blockIdx.x, b = blockIdx.y, tid = threadIdx.x;
  const float* p = vm + ((size_t)b * C + c) * HW;
  const float* q = f + (size_t)b * HW;
  float s = 0.f;
  for (int i = tid; i < HW; i += blockDim.x) s += p[i] * q[i];
  __shared__ float red[256];
  red[tid] = s; __syncthreads();
  for (int st = 128; st > 0; st >>= 1) {
    if (tid < st) red[tid] += red[tid + st];
    __syncthreads();
  }
  if (tid == 0) flat[(size_t)b * flatC + coff + c] = red[0] / (float)HW;
}

// ---------------- MFMA fused hconv ------------------------------------------
// vin: tangent (B,CIN,H,W); s2map: per-pixel sum_c vin^2 (B,H,W)
// out: t = atanh(|y|)/|y| * relu(y) tangent (B,COUT,H,W)
// Waves: WM in M (16 rows each) x WN in N (NT/WN 16-col tiles each).
template <int CIN, int CSH, int K, int PAD, int COUT, int H, int W,
          int TH, int TW, int WM, int WN>
__global__ __launch_bounds__(WM * WN * 64) void hconv_mfma(
    const float* __restrict__ vin, const float* __restrict__ s2map,
    const unsigned short* __restrict__ zfh,
    const unsigned short* __restrict__ zfl,
    const float* __restrict__ r, const float* __restrict__ zn,
    float* __restrict__ out, float scale) {
  constexpr int NTHR = WM * WN * 64;
  constexpr int CPAD = 1 << CSH;
  constexpr int KK = K * K;
  constexpr int MT = WM * 16;
  static_assert(MT == TH * TW, "tile rows mismatch");
  constexpr int NT = COUT / 16;
  constexpr int NTW = NT / WN;
  static_assert(NTW * WN == NT, "");
  constexpr int NK = KK * CPAD / 32;
  constexpr int SY = TH + K - 1, SX = TW + K - 1;
  constexpr int NPOS = SY * SX;
  constexpr int RWU = CPAD + 8;            // ushort row stride (16B aligned)
  constexpr int TRS = MT + 4;
  constexpr int WINU = NPOS * RWU;
  static_assert(COUT * TRS <= WINU, "trans overlay too big");

  __shared__ __align__(16) unsigned short winbuf[2 * WINU];
  __shared__ float s2w[NPOS];
  __shared__ float gA[MT], cA[MT];
  __shared__ float chb[COUT], shb[COUT], znb[COUT];
  __shared__ float redw[(WN > 1) ? WN * MT : 1];
  unsigned short* winh = winbuf;
  unsigned short* winl = winbuf + WINU;

  const int tid = threadIdx.x;
  int bid = blockIdx.x;
  constexpr int TXC = W / TW, TYC = H / TH;
  const int tx = bid % TXC; bid /= TXC;
  const int ty = bid % TYC; const int b = bid / TYC;
  const int y0 = ty * TH, x0 = tx * TW;

  if (tid < COUT) {
    float rv = r[tid];
    chb[tid] = coshf(2.f * rv);
    shb[tid] = sinhf(2.f * rv);
    znb[tid] = zn[tid];
  }
  // stage window as hi/lo bf16 planes (+ zero padding)
  const float* vb = vin + (size_t)b * CIN * H * W;
  for (int idx = tid; idx < CPAD * NPOS; idx += NTHR) {
    int c = idx / NPOS;
    int pos = idx - c * NPOS;
    int sy = pos / SX, sx = pos - sy * SX;
    float val = 0.f;
    if (c < CIN) {
      int gy = y0 + sy - PAD, gx = x0 + sx - PAD;
      if (gy >= 0 && gy < H && gx >= 0 && gx < W)
        val = vb[((size_t)c * H + gy) * W + gx];
    }
    unsigned hi = rne16(val);
    float hif = __uint_as_float(hi << 16);
    unsigned lo = rne16(val - hif);
    winh[pos * RWU + c] = (unsigned short)hi;
    winl[pos * RWU + c] = (unsigned short)lo;
  }
  const float* s2b = s2map + (size_t)b * H * W;
  for (int i = tid; i < NPOS; i += NTHR) {
    int sy = i / SX, sx = i - sy * SX;
    int gy = y0 + sy - PAD, gx = x0 + sx - PAD;
    s2w[i] = (gy >= 0 && gy < H && gx >= 0 && gx < W) ? s2b[gy * W + gx] : 0.f;
  }
  __syncthreads();

  if (tid < MT) {
    int py = tid / TW, px = tid - (tid / TW) * TW;
    float s = 0.f;
    for (int iy = 0; iy < K; ++iy)
      for (int ix = 0; ix < K; ++ix)
        s += s2w[(py + iy) * SX + (px + ix)];
    float n = sqrtf(fmaxf(scale * scale * s, EPSF));
    float th = tanhf(n);
    gA[tid] = th * scale / n;
    cA[tid] = th * th;
  }
  __syncthreads();

  const int w = __builtin_amdgcn_readfirstlane(tid >> 6);
  const int wm = w % WM, wn = w / WM;
  const int lane = tid & 63, lm = lane & 15, lg = lane >> 4;
  const int m = wm * 16 + lm;
  const int py = m / TW, px = m - (m / TW) * TW;
  const int nt0 = wn * NTW;

  f32x4 acc[NTW];
#pragma unroll
  for (int j = 0; j < NTW; ++j) acc[j] = (f32x4){0.f, 0.f, 0.f, 0.f};

  for (int ks = 0; ks < NK; ++ks) {
    const int tap = (ks * 32) >> CSH;
    const int c0 = (ks * 32) & (CPAD - 1);
    const int iy = tap / K, ix = tap - (tap / K) * K;
    const int lofs = ((py + iy) * SX + (px + ix)) * RWU + c0 + lg * 8;
    const unsigned short* bp = zfh + (size_t)(ks * NT + nt0) * 512 + lane * 8;
    const unsigned short* bq = zfl + (size_t)(ks * NT + nt0) * 512 + lane * 8;
    uint4 Bh[NTW], Bl[NTW];
#pragma unroll
    for (int j = 0; j < NTW; ++j) {
      Bh[j] = *(const uint4*)(bp + j * 512);
      Bl[j] = *(const uint4*)(bq + j * 512);
    }
    short8 ahi = *(const short8*)(winh + lofs);
    short8 alo = *(const short8*)(winl + lofs);
#pragma unroll
    for (int j = 0; j < NTW; ++j) {
      short8 bhv = __builtin_bit_cast(short8, Bh[j]);
      short8 blv = __builtin_bit_cast(short8, Bl[j]);
      acc[j] = __builtin_amdgcn_mfma_f32_16x16x32_bf16(ahi, bhv, acc[j], 0, 0, 0);
      acc[j] = __builtin_amdgcn_mfma_f32_16x16x32_bf16(ahi, blv, acc[j], 0, 0, 0);
      acc[j] = __builtin_amdgcn_mfma_f32_16x16x32_bf16(alo, bhv, acc[j], 0, 0, 0);
    }
  }

  // epilogue: D row = wm*16 + lg*4 + reg, col = (nt0+j)*16 + lm
  float ls[4] = {0.f, 0.f, 0.f, 0.f};
  float gR[4], cR[4];
#pragma unroll
  for (int reg = 0; reg < 4; ++reg) {
    int rr = wm * 16 + lg * 4 + reg;
    gR[reg] = gA[rr]; cR[reg] = cA[rr];
  }
#pragma unroll
  for (int j = 0; j < NTW; ++j) {
    int o = (nt0 + j) * 16 + lm;
    float znv = znb[o], ch = chb[o], sh = shb[o];
#pragma unroll
    for (int reg = 0; reg < 4; ++reg) {
      float onemc = fmaxf(1.f - cR[reg], EPSF);
      float num = 2.f * (gR[reg] * acc[j][reg] / znv) * ch - (1.f + cR[reg]) * sh;
      float mlr = 2.f * znv * asinhf(num / onemc);
      float yv = sinhf(mlr);
      acc[j][reg] = yv;
      ls[reg] += yv * yv;
    }
  }
#pragma unroll
  for (int mask = 1; mask < 16; mask <<= 1)
#pragma unroll
    for (int reg = 0; reg < 4; ++reg)
      ls[reg] += __shfl_xor(ls[reg], mask);

  if constexpr (WN > 1) {
    if (lm == 0) {
#pragma unroll
      for (int reg = 0; reg < 4; ++reg)
        redw[wn * MT + wm * 16 + lg * 4 + reg] = ls[reg];
    }
  }
  __syncthreads();  // redw visible; all waves done reading win planes
  if constexpr (WN > 1) {
#pragma unroll
    for (int reg = 0; reg < 4; ++reg) {
      float s = 0.f;
#pragma unroll
      for (int k2 = 0; k2 < WN; ++k2)
        s += redw[k2 * MT + wm * 16 + lg * 4 + reg];
      ls[reg] = s;
    }
  }
  float fs[4];
#pragma unroll
  for (int reg = 0; reg < 4; ++reg) {
    float inv = 1.f / (1.f + sqrtf(1.f + ls[reg]));
    float ny = sqrtf(fmaxf(ls[reg] * inv * inv, EPSF));
    fs[reg] = atanhf(fminf(ny, ATANH_CAP)) / ny * inv;
  }
  float* tr = (float*)winbuf;  // [COUT][TRS] overlay
#pragma unroll
  for (int j = 0; j < NTW; ++j) {
    int o = (nt0 + j) * 16 + lm;
#pragma unroll
    for (int reg = 0; reg < 4; ++reg) {
      int rr = wm * 16 + lg * 4 + reg;
      tr[o * TRS + rr] = fs[reg] * fmaxf(acc[j][reg], 0.f);
    }
  }
  __syncthreads();

  for (int i = tid; i < COUT * TH; i += NTHR) {
    int co = i / TH, pyy = i - (i / TH) * TH;
    const float* src = tr + co * TRS + pyy * TW;
    float* dst = out + (((size_t)b * COUT + co) * H + y0 + pyy) * W + x0;
    *(float4*)dst = *(const float4*)src;
    *(float4*)(dst + 4) = *(const float4*)(src + 4);
  }
}

// ---------------- Poincare FC over rows -------------------------------------
template <int NIN, int NOUT, int BLOCK>
__global__ __launch_bounds__(256) void pfc_kernel(
    const float* __restrict__ x, const float* __restrict__ z,
    const float* __restrict__ r, const float* __restrict__ zn,
    float* __restrict__ out) {
  const int b = blockIdx.x, tid = threadIdx.x;
  __shared__ float xs[NIN];
  __shared__ float red[BLOCK];
  for (int i = tid; i < NIN; i += BLOCK) xs[i] = x[(size_t)b * NIN + i];
  __syncthreads();
  float s = 0.f;
  for (int i = tid; i < NIN; i += BLOCK) { float v = xs[i]; s += v * v; }
  red[tid] = s; __syncthreads();
  for (int st = BLOCK / 2; st > 0; st >>= 1) {
    if (tid < st) red[tid] += red[tid + st];
    __syncthreads();
  }
  const float cx2 = red[0];
  __syncthreads();
  constexpr int CPT = (NOUT + BLOCK - 1) / BLOCK;
  const float onemc = fmaxf(1.f - cx2, EPSF);
  float yv[CPT];
  float ls = 0.f;
#pragma unroll
  for (int j = 0; j < CPT; ++j) {
    int o = tid + j * BLOCK;
    float y = 0.f;
    if (o < NOUT) {
      float d = 0.f;
      for (int k = 0; k < NIN; ++k) d = fmaf(xs[k], z[(size_t)k * NOUT + o], d);
      float znv = zn[o];
      float rv = r[o];
      float num = 2.f * (d / znv) * coshf(2.f * rv) - (1.f + cx2) * sinhf(2.f * rv);
      float mlr = 2.f * znv * asinhf(num / onemc);
      y = sinhf(mlr);
    }
    yv[j] = y; ls += y * y;
  }
  red[tid] = ls; __syncthreads();
  for (int st = BLOCK / 2; st > 0; st >>= 1) {
    if (tid < st) red[tid] += red[tid + st];
    __syncthreads();
  }
  const float denom = 1.f + sqrtf(1.f + red[0]);
#pragma unroll
  for (int j = 0; j < CPT; ++j) {
    int o = tid + j * BLOCK;
    if (o < NOUT) out[(size_t)b * NOUT + o] = yv[j] / denom;
  }
}

// ---------------- hrelu over rows (axis=-1) ---------------------------------
template <int N, int BLOCK>
__global__ __launch_bounds__(256) void hrelu_rows_kernel(
    const float* __restrict__ in, float* __restrict__ out) {
  const int b = blockIdx.x, tid = threadIdx.x;
  __shared__ float red[BLOCK];
  constexpr int CPT = N / BLOCK;
  float v[CPT];
  float s = 0.f;
#pragma unroll
  for (int j = 0; j < CPT; ++j) {
    v[j] = in[(size_t)b * N + tid + j * BLOCK];
    s += v[j] * v[j];
  }
  red[tid] = s; __syncthreads();
  for (int st = BLOCK / 2; st > 0; st >>= 1) {
    if (tid < st) red[tid] += red[tid + st];
    __syncthreads();
  }
  float n = sqrtf(fmaxf(red[0], EPSF));
  float f = atanhf(fminf(n, ATANH_CAP)) / n;
  __syncthreads();
  float s2 = 0.f;
#pragma unroll
  for (int j = 0; j < CPT; ++j) { v[j] = f * fmaxf(v[j], 0.f); s2 += v[j] * v[j]; }
  red[tid] = s2; __syncthreads();
  for (int st = BLOCK / 2; st > 0; st >>= 1) {
    if (tid < st) red[tid] += red[tid + st];
    __syncthreads();
  }
  float nt = sqrtf(fmaxf(red[0], EPSF));
  float gg = tanhf(nt) / nt;
#pragma unroll
  for (int j = 0; j < CPT; ++j)
    out[(size_t)b * N + tid + j * BLOCK] = gg * v[j];
}

// ---------------------------------------------------------------------------
static inline double beta_fn(double a, double b) {
  return std::exp(std::lgamma(a) + std::lgamma(b) - std::lgamma(a + b));
}

extern "C" void kernel_launch(void* const* d_in, const int* in_sizes, int n_in,
                              void* d_out, int out_size, void* d_ws, size_t ws_size,
                              hipStream_t stream) {
  const float* x   = (const float*)d_in[0];
  const float* z1  = (const float*)d_in[1];
  const float* b1  = (const float*)d_in[2];
  const float* z2  = (const float*)d_in[3];
  const float* b2  = (const float*)d_in[4];
  const float* z3  = (const float*)d_in[5];
  const float* b3  = (const float*)d_in[6];
  const float* z4  = (const float*)d_in[7];
  const float* b4  = (const float*)d_in[8];
  const float* zf1 = (const float*)d_in[9];
  const float* bf1 = (const float*)d_in[10];
  const float* zf2 = (const float*)d_in[11];
  const float* bf2 = (const float*)d_in[12];
  float* outp = (float*)d_out;

  float* ws    = (float*)d_ws;
  float* zn    = ws;                        // 2048
  float* flat  = ws + 2048;                 // 5632
  float* h1r   = ws + 7680;                 // 8192
  float* h1    = ws + 15872;                // 8704
  float* vm    = ws + 24576;                // 2,097,152
  float* ybuf  = vm + 2097152;              // 8,388,608
  float* s2a   = ybuf + 8388608;            // 262,144
  float* fmapb = s2a + 262144;              // 65,536
  unsigned short* zfu = (unsigned short*)(fmapb + 65536);
  unsigned short* zf1h = zfu;               //   9,216
  unsigned short* zf1l = zfu + 9216;
  unsigned short* zf2h = zfu + 18432;       //  51,200
  unsigned short* zf2l = zfu + 69632;
  unsigned short* zf3h = zfu + 120832;      // 401,408
  unsigned short* zf3l = zfu + 522240;
  unsigned short* zf4h = zfu + 923648;      // 147,456
  unsigned short* zf4l = zfu + 1071104;     // ends 1,218,560 ushorts (~48 MB)

  const float s1  = (float)(beta_fn(27.0 / 2.0, 0.5) / beta_fn(3.0 / 2.0, 0.5));
  const float s2c = (float)(beta_fn(800.0 / 2.0, 0.5) / beta_fn(32.0 / 2.0, 0.5));
  const float s3  = (float)(beta_fn(3136.0 / 2.0, 0.5) / beta_fn(64.0 / 2.0, 0.5));
  const float s4  = (float)(beta_fn(1152.0 / 2.0, 0.5) / beta_fn(128.0 / 2.0, 0.5));

  auto g1 = [](int n) { return dim3((n + 255) / 256); };

  // prep: column norms + fragment-ordered hi/lo z
  znorm_kernel<<<2,  256, 0, stream>>>(z1, zn + 0, 27, 32);
  znorm_kernel<<<4,  256, 0, stream>>>(z2, zn + 32, 800, 64);
  znorm_kernel<<<8,  256, 0, stream>>>(z3, zn + 96, 3136, 128);
  znorm_kernel<<<8,  256, 0, stream>>>(z4, zn + 224, 1152, 128);
  znorm_kernel<<<32, 256, 0, stream>>>(zf1, zn + 352, 352, 512);
  znorm_kernel<<<63, 256, 0, stream>>>(zf2, zn + 864, 512, 1000);
  zfprep_kernel<3, 5, 9, 32><<<36, 256, 0, stream>>>(z1, zf1h, zf1l);
  zfprep_kernel<32, 5, 25, 64><<<200, 256, 0, stream>>>(z2, zf2h, zf2l);
  zfprep_kernel<64, 6, 49, 128><<<1568, 256, 0, stream>>>(z3, zf3h, zf3l);
  zfprep_kernel<128, 7, 9, 128><<<576, 256, 0, stream>>>(z4, zf4h, zf4l);

  // ---- layer 1: (16,3,128,128) -> t1 (16,32,128,128) -> m1 (16,32,64,64)
  logmap_s2_kernel<<<g1(262144), 256, 0, stream>>>(x, vm, s2a, 3, 16384, 262144);
  hconv_mfma<3, 5, 3, 1, 32, 128, 128, 8, 8, 4, 1>
      <<<4096, 256, 0, stream>>>(vm, s2a, zf1h, zf1l, b1, zn + 0, ybuf, s1);
  maxpool_kernel<<<g1(2097152), 256, 0, stream>>>(ybuf, vm, 32, 128, 128, 2097152);
  fmap_kernel<<<g1(65536), 256, 0, stream>>>(vm, s2a, fmapb, 32, 4096, 65536);
  wavgpool_kernel<<<dim3(32, 16), 256, 0, stream>>>(vm, fmapb, flat, 32, 4096, 352, 0);

  // ---- layer 2: m1 -> t2 (16,64,64,64) -> m2 (16,64,32,32)
  hconv_mfma<32, 5, 5, 2, 64, 64, 64, 8, 8, 4, 2>
      <<<1024, 512, 0, stream>>>(vm, s2a, zf2h, zf2l, b2, zn + 32, ybuf, s2c);
  maxpool_kernel<<<g1(1048576), 256, 0, stream>>>(ybuf, vm, 64, 64, 64, 1048576);
  fmap_kernel<<<g1(16384), 256, 0, stream>>>(vm, s2a, fmapb, 64, 1024, 16384);
  wavgpool_kernel<<<dim3(64, 16), 256, 0, stream>>>(vm, fmapb, flat, 64, 1024, 352, 32);

  // ---- layer 3: m2 -> t3 (16,128,32,32) -> m3 (16,128,16,16)
  hconv_mfma<64, 6, 7, 3, 128, 32, 32, 4, 8, 2, 4>
      <<<512, 512, 0, stream>>>(vm, s2a, zf3h, zf3l, b3, zn + 96, ybuf, s3);
  maxpool_kernel<<<g1(524288), 256, 0, stream>>>(ybuf, vm, 128, 32, 32, 524288);
  fmap_kernel<<<g1(4096), 256, 0, stream>>>(vm, s2a, fmapb, 128, 256, 4096);
  wavgpool_kernel<<<dim3(128, 16), 256, 0, stream>>>(vm, fmapb, flat, 128, 256, 352, 96);

  // ---- layer 4: m3 -> t4 (16,128,16,16) -> m4 (16,128,8,8)
  hconv_mfma<128, 7, 3, 1, 128, 16, 16, 2, 8, 1, 8>
      <<<256, 512, 0, stream>>>(vm, s2a, zf4h, zf4l, b4, zn + 224, ybuf, s4);
  maxpool_kernel<<<g1(131072), 256, 0, stream>>>(ybuf, vm, 128, 16, 16, 131072);
  fmap_kernel<<<g1(1024), 256, 0, stream>>>(vm, s2a, fmapb, 128, 64, 1024);
  wavgpool_kernel<<<dim3(128, 16), 256, 0, stream>>>(vm, fmapb, flat, 128, 64, 352, 224);

  // ---- head: flat (16,352) -> (16,512) -> hrelu -> (16,1000)
  pfc_kernel<352, 512, 256><<<16, 256, 0, stream>>>(flat, zf1, bf1, zn + 352, h1r);
  hrelu_rows_kernel<512, 256><<<16, 256, 0, stream>>>(h1r, h1);
  pfc_kernel<512, 1000, 256><<<16, 256, 0, stream>>>(h1, zf2, bf2, zn + 864, outp);

  (void)in_sizes; (void)n_in; (void)out_size; (void)ws_size;
}

// Round 5
// 366.520 us; speedup vs baseline: 8.3940x; 1.6206x over previous
//
#include <hip/hip_runtime.h>
#include <cmath>

// ---------------------------------------------------------------------------
// Hyperbolic MS-CNN (Poincare ball, c=1) — round 5.
//  * MFMA convs (split bf16 hi/lo, 3 MFMAs) with fused epilogue:
//    MLR -> sinh -> projection -> relu-tangent -> 2x2 maxpool -> s2/f maps.
//  * Fast transcendentals via v_exp/v_log/v_rcp (exact forms, ~1e-6 rel err).
//  * Layer 1 uses CPAD=8 (taps padded to 12) instead of padding channels to 32.
// ---------------------------------------------------------------------------

#define EPSF 1e-15f
#define ATANH_CAP 0.9999999f  // 1 - 1e-7

typedef __attribute__((ext_vector_type(8))) short short8;
typedef __attribute__((ext_vector_type(4))) float f32x4;

__device__ inline unsigned rne16(float f) {
  unsigned u = __float_as_uint(f);
  return (u + 0x7FFFu + ((u >> 16) & 1u)) >> 16;
}
__device__ inline float fexp2(float x) { return __builtin_amdgcn_exp2f(x); }
__device__ inline float flog2(float x) { return __builtin_amdgcn_logf(x); }
__device__ inline float frcp(float x) { return __builtin_amdgcn_rcpf(x); }

// atanh(min(n,cap))/n ; exact small-n series below 0.004
__device__ inline float atanh_over(float n) {
  float nc = fminf(n, ATANH_CAP);
  float f = 0.34657359f * flog2((1.f + nc) * frcp(1.f - nc)) * frcp(n);
  float s = 1.f + 0.33333333f * n * n;
  return (n < 0.004f) ? s : f;
}
// tanh(n)/n
__device__ inline float tanh_over(float n) {
  float p2 = fexp2(2.885390082f * n);  // e^{2n}
  float f = (1.f - 2.f * frcp(p2 + 1.f)) * frcp(n);
  float s = 1.f - 0.33333333f * n * n;
  return (n < 0.004f) ? s : f;
}
// sinh(twozn * asinh(q)) = sign(q) * (t^twozn - t^-twozn)/2, t=|q|+sqrt(q^2+1)
__device__ inline float sinh_zasinh(float q, float twozn) {
  float aq = fabsf(q);
  float t = aq + sqrtf(fmaf(aq, aq, 1.f));
  float p = fexp2(twozn * flog2(t));
  float y = 0.5f * (p - frcp(p));
  return copysignf(y, q);
}

// ---------------- z column norms (parallel over K and columns) --------------
__global__ __launch_bounds__(256) void znorm_kernel(
    const float* __restrict__ z, float* __restrict__ zn, int K, int Nout) {
  const int tid = threadIdx.x;
  const int col = (blockIdx.x << 4) + (tid & 15);
  const int kg = tid >> 4;
  float s = 0.f;
  if (col < Nout)
    for (int k = kg; k < K; k += 16) {
      float v = z[(size_t)k * Nout + col];
      s += v * v;
    }
  __shared__ float red[256];
  red[tid] = s;
  __syncthreads();
  if (tid < 16) {
    float t = 0.f;
#pragma unroll
    for (int j = 0; j < 16; ++j) t += red[tid + (j << 4)];
    if (col < Nout) zn[col] = sqrtf(fmaxf(t, EPSF));
  }
}

// ---------------- z -> MFMA-fragment-ordered hi/lo bf16 ---------------------
// tile (ks, nt): lane l supplies B[k][n], k = ks*32+(l>>4)*8+i, n = nt*16+(l&15)
template <int CIN, int CSH, int TAPS, int KK, int COUT>
__global__ __launch_bounds__(256) void zfprep_kernel(
    const float* __restrict__ z, unsigned short* __restrict__ zh,
    unsigned short* __restrict__ zl) {
  constexpr int CPAD = 1 << CSH;
  constexpr int KP = TAPS * CPAD;
  constexpr int NT = COUT / 16;
  int t = blockIdx.x * 256 + threadIdx.x;
  if (t >= KP * COUT) return;
  int k = t / COUT, n = t - k * COUT;
  int ks = k >> 5, lg = (k >> 3) & 3, i = k & 7;
  int nt = n >> 4, lm = n & 15;
  size_t e = ((size_t)(ks * NT + nt) * 64 + lg * 16 + lm) * 8 + i;
  int tap = k >> CSH, c = k & (CPAD - 1);
  float val = (c < CIN && tap < KK) ? z[(size_t)(c * KK + tap) * COUT + n] : 0.f;
  unsigned hi = rne16(val);
  float hif = __uint_as_float(hi << 16);
  unsigned lo = rne16(val - hif);
  zh[e] = (unsigned short)hi;
  zl[e] = (unsigned short)lo;
}

// ---------------- logmap0 + per-pixel sum of squares ------------------------
__global__ __launch_bounds__(256) void logmap_s2_kernel(
    const float* __restrict__ in, float* __restrict__ out,
    float* __restrict__ s2, int C, int HW, int total) {
  int i = blockIdx.x * blockDim.x + threadIdx.x;
  if (i >= total) return;
  int b = i / HW, s = i - b * HW;
  const float* p = in + (size_t)b * C * HW + s;
  float ss = 0.f;
  for (int c = 0; c < C; ++c) { float v = p[(size_t)c * HW]; ss += v * v; }
  float n = sqrtf(fmaxf(ss, EPSF));
  float f = atanh_over(n);
  float* q = out + (size_t)b * C * HW + s;
  for (int c = 0; c < C; ++c) q[(size_t)c * HW] = f * p[(size_t)c * HW];
  s2[i] = f * f * ss;
}

// ---------------- weighted spatial mean: flat = (1/HW) sum f[i]*vm[c][i] ----
__global__ __launch_bounds__(256) void wavgpool_kernel(
    const float* __restrict__ vm, const float* __restrict__ f,
    float* __restrict__ flat, int C, int HW, int flatC, int coff) {
  int c = blockIdx.x, b = blockIdx.y, tid = threadIdx.x;
  const float* p = vm + ((size_t)b * C + c) * HW;
  const float* q = f + (size_t)b * HW;
  float s = 0.f;
  for (int i = tid; i < HW; i += blockDim.x) s += p[i] * q[i];
  __shared__ float red[256];
  red[tid] = s; __syncthreads();
  for (int st = 128; st > 0; st >>= 1) {
    if (tid < st) red[tid] += red[tid + st];
    __syncthreads();
  }
  if (tid == 0) flat[(size_t)b * flatC + coff + c] = red[0] / (float)HW;
}

// ---------------- MFMA fused hconv + hrelu-tangent + maxpool + maps ---------
// vin: tangent (B,CIN,H,W); s2map: per-pixel sum_c vin^2 (B,H,W)
// mout: pooled tangent (B,COUT,H/2,W/2); s2out/fout: (B,H/2,W/2)
template <int CIN, int CSH, int TAPS, int K, int PAD, int COUT, int H, int W,
          int TH, int TW, int WM, int WN>
__global__ __launch_bounds__(WM * WN * 64) void hconv_mfma(
    const float* __restrict__ vin, const float* __restrict__ s2map,
    const unsigned short* __restrict__ zfh,
    const unsigned short* __restrict__ zfl,
    const float* __restrict__ r, const float* __restrict__ zn,
    float* __restrict__ mout, float* __restrict__ s2out,
    float* __restrict__ fout, float scale) {
  constexpr int NTHR = WM * WN * 64;
  constexpr int CPAD = 1 << CSH;
  constexpr int KK = K * K;
  constexpr int MT = WM * 16;
  static_assert(MT == TH * TW, "tile rows mismatch");
  constexpr int NT = COUT / 16;
  constexpr int NTW = NT / WN;
  static_assert(NTW * WN == NT, "");
  constexpr int NK = TAPS * CPAD / 32;
  static_assert(NK * 32 == TAPS * CPAD, "K-step misalign");
  constexpr int SY = TH + K - 1, SX = TW + K - 1;
  constexpr int NPOS = SY * SX;
  constexpr int RWU = (CPAD >= 32) ? (CPAD + 8) : 16;  // 16B-aligned rows
  constexpr int TRS = MT + 4;
  constexpr int WINU = NPOS * RWU;
  constexpr int TRU = 2 * COUT * TRS;
  constexpr int SHU = (2 * WINU > TRU) ? 2 * WINU : TRU;
  constexpr int HO = H / 2, WO = W / 2;
  constexpr int PH = TH / 2, PW = TW / 2, NPP = PH * PW;
  constexpr int CG0 = NTHR / NPP;
  constexpr int CG = (CG0 < COUT) ? CG0 : COUT;
  constexpr int CPG = COUT / CG;
  static_assert(CPG * CG == COUT, "pool split");

  __shared__ __align__(16) unsigned short winbuf[SHU];
  __shared__ float s2w[NPOS];
  __shared__ float gA[MT], cA[MT];
  __shared__ float c1b[COUT], shb[COUT], z2b[COUT];
  __shared__ float redw[(WN > 1) ? WN * MT : 1];
  __shared__ float pacc[NTHR];
  unsigned short* winh = winbuf;
  unsigned short* winl = winbuf + WINU;

  const int tid = threadIdx.x;
  int bid = blockIdx.x;
  constexpr int TXC = W / TW, TYC = H / TH;
  const int tx = bid % TXC; bid /= TXC;
  const int ty = bid % TYC; const int b = bid / TYC;
  const int y0 = ty * TH, x0 = tx * TW;

  if (tid < COUT) {
    float rv = r[tid];
    float znv = zn[tid];
    float ch = coshf(2.f * rv), sh = sinhf(2.f * rv);
    c1b[tid] = 2.f * ch / znv;
    shb[tid] = sh;
    z2b[tid] = 2.f * znv;
  }
  // stage window as hi/lo bf16 planes (+ zero padding)
  const float* vb = vin + (size_t)b * CIN * H * W;
  for (int idx = tid; idx < CPAD * NPOS; idx += NTHR) {
    int c = idx / NPOS;
    int pos = idx - c * NPOS;
    int sy = pos / SX, sx = pos - sy * SX;
    float val = 0.f;
    if (c < CIN) {
      int gy = y0 + sy - PAD, gx = x0 + sx - PAD;
      if (gy >= 0 && gy < H && gx >= 0 && gx < W)
        val = vb[((size_t)c * H + gy) * W + gx];
    }
    unsigned hi = rne16(val);
    float hif = __uint_as_float(hi << 16);
    unsigned lo = rne16(val - hif);
    winh[pos * RWU + c] = (unsigned short)hi;
    winl[pos * RWU + c] = (unsigned short)lo;
  }
  const float* s2b = s2map + (size_t)b * H * W;
  for (int i = tid; i < NPOS; i += NTHR) {
    int sy = i / SX, sx = i - sy * SX;
    int gy = y0 + sy - PAD, gx = x0 + sx - PAD;
    s2w[i] = (gy >= 0 && gy < H && gx >= 0 && gx < W) ? s2b[gy * W + gx] : 0.f;
  }
  __syncthreads();

  if (tid < MT) {
    int py = tid / TW, px = tid - (tid / TW) * TW;
    float s = 0.f;
    for (int iy = 0; iy < K; ++iy)
      for (int ix = 0; ix < K; ++ix)
        s += s2w[(py + iy) * SX + (px + ix)];
    float n = sqrtf(fmaxf(scale * scale * s, EPSF));
    float th = n * tanh_over(n);           // tanh(n)
    gA[tid] = th * scale * frcp(n);        // maps raw dot -> expmap'd dot
    cA[tid] = th * th;                     // cx2
  }
  __syncthreads();

  const int w = __builtin_amdgcn_readfirstlane(tid >> 6);
  const int wm = w % WM, wn = w / WM;
  const int lane = tid & 63, lm = lane & 15, lg = lane >> 4;
  const int m = wm * 16 + lm;
  const int py = m / TW, px = m - (m / TW) * TW;
  const int nt0 = wn * NTW;

  f32x4 acc[NTW];
#pragma unroll
  for (int j = 0; j < NTW; ++j) acc[j] = (f32x4){0.f, 0.f, 0.f, 0.f};

  for (int ks = 0; ks < NK; ++ks) {
    const int kbase = ks * 32 + lg * 8;
    const int tap = kbase >> CSH;
    const int c0 = kbase & (CPAD - 1);
    const unsigned short* bp = zfh + (size_t)(ks * NT + nt0) * 512 + lane * 8;
    const unsigned short* bq = zfl + (size_t)(ks * NT + nt0) * 512 + lane * 8;
    uint4 Bh[NTW], Bl[NTW];
#pragma unroll
    for (int j = 0; j < NTW; ++j) {
      Bh[j] = *(const uint4*)(bp + j * 512);
      Bl[j] = *(const uint4*)(bq + j * 512);
    }
    short8 ahi = {}, alo = {};
    bool valid = true;
    if constexpr (TAPS != KK) valid = (tap < KK);
    if (valid) {
      const int iy = tap / K, ix = tap - (tap / K) * K;
      const int lofs = ((py + iy) * SX + (px + ix)) * RWU + c0;
      ahi = *(const short8*)(winh + lofs);
      alo = *(const short8*)(winl + lofs);
    }
#pragma unroll
    for (int j = 0; j < NTW; ++j) {
      short8 bhv = __builtin_bit_cast(short8, Bh[j]);
      short8 blv = __builtin_bit_cast(short8, Bl[j]);
      acc[j] = __builtin_amdgcn_mfma_f32_16x16x32_bf16(ahi, bhv, acc[j], 0, 0, 0);
      acc[j] = __builtin_amdgcn_mfma_f32_16x16x32_bf16(ahi, blv, acc[j], 0, 0, 0);
      acc[j] = __builtin_amdgcn_mfma_f32_16x16x32_bf16(alo, bhv, acc[j], 0, 0, 0);
    }
  }

  // epilogue: D row = wm*16 + lg*4 + reg, col = (nt0+j)*16 + lm
  float ls[4] = {0.f, 0.f, 0.f, 0.f};
  float gR[4], rcpom[4], onePc[4];
#pragma unroll
  for (int reg = 0; reg < 4; ++reg) {
    int rr = wm * 16 + lg * 4 + reg;
    float cx2 = cA[rr];
    gR[reg] = gA[rr];
    rcpom[reg] = frcp(fmaxf(1.f - cx2, EPSF));
    onePc[reg] = 1.f + cx2;
  }
#pragma unroll
  for (int j = 0; j < NTW; ++j) {
    int o = (nt0 + j) * 16 + lm;
    float c1 = c1b[o], sh = shb[o], z2 = z2b[o];
#pragma unroll
    for (int reg = 0; reg < 4; ++reg) {
      float num = c1 * (gR[reg] * acc[j][reg]) - onePc[reg] * sh;
      float yv = sinh_zasinh(num * rcpom[reg], z2);
      acc[j][reg] = yv;
      ls[reg] += yv * yv;
    }
  }
#pragma unroll
  for (int mask = 1; mask < 16; mask <<= 1)
#pragma unroll
    for (int reg = 0; reg < 4; ++reg)
      ls[reg] += __shfl_xor(ls[reg], mask);

  if constexpr (WN > 1) {
    if (lm == 0) {
#pragma unroll
      for (int reg = 0; reg < 4; ++reg)
        redw[wn * MT + wm * 16 + lg * 4 + reg] = ls[reg];
    }
  }
  __syncthreads();  // redw visible; all waves done reading win planes
  if constexpr (WN > 1) {
#pragma unroll
    for (int reg = 0; reg < 4; ++reg) {
      float s = 0.f;
#pragma unroll
      for (int k2 = 0; k2 < WN; ++k2)
        s += redw[k2 * MT + wm * 16 + lg * 4 + reg];
      ls[reg] = s;
    }
  }
  float fs[4];
#pragma unroll
  for (int reg = 0; reg < 4; ++reg) {
    float inv = frcp(1.f + sqrtf(1.f + ls[reg]));   // ball projection
    float ny = sqrtf(fmaxf(ls[reg] * inv * inv, EPSF));
    fs[reg] = atanh_over(ny) * inv;                 // logmap0 * proj
  }
  float* tr = (float*)winbuf;  // [COUT][TRS] overlay
#pragma unroll
  for (int j = 0; j < NTW; ++j) {
    int o = (nt0 + j) * 16 + lm;
#pragma unroll
    for (int reg = 0; reg < 4; ++reg) {
      int rr = wm * 16 + lg * 4 + reg;
      tr[o * TRS + rr] = fs[reg] * fmaxf(acc[j][reg], 0.f);
    }
  }
  __syncthreads();

  // fused 2x2 maxpool (tangent space) + per-pooled-pixel s2/f maps
  const int y0p = y0 >> 1, x0p = x0 >> 1;
  if (tid < NPP * CG) {
    int cg = tid / NPP, p = tid - cg * NPP;
    int ppy = p / PW, ppx = p - ppy * PW;
    const float* base = tr + (ppy * 2) * TW + ppx * 2;
    float ss = 0.f;
#pragma unroll
    for (int j = 0; j < CPG; ++j) {
      int c = cg * CPG + j;
      const float* rp = base + c * TRS;
      float mv = fmaxf(fmaxf(rp[0], rp[1]), fmaxf(rp[TW], rp[TW + 1]));
      mout[((size_t)(b * COUT + c) * HO + y0p + ppy) * WO + x0p + ppx] = mv;
      ss += mv * mv;
    }
    pacc[cg * NPP + p] = ss;
  }
  __syncthreads();
  if (tid < NPP) {
    float ss = 0.f;
    for (int k2 = 0; k2 < CG; ++k2) ss += pacc[k2 * NPP + tid];
    int ppy = tid / PW, ppx = tid - (tid / PW) * PW;
    size_t pix = ((size_t)b * HO + y0p + ppy) * WO + x0p + ppx;
    s2out[pix] = ss;
    float n = sqrtf(fmaxf(ss, EPSF));
    fout[pix] = tanh_over(n);
  }
}

// ---------------- Poincare FC over rows (head; libm precision) --------------
template <int NIN, int NOUT, int BLOCK>
__global__ __launch_bounds__(256) void pfc_kernel(
    const float* __restrict__ x, const float* __restrict__ z,
    const float* __restrict__ r, const float* __restrict__ zn,
    float* __restrict__ out) {
  const int b = blockIdx.x, tid = threadIdx.x;
  __shared__ float xs[NIN];
  __shared__ float red[BLOCK];
  for (int i = tid; i < NIN; i += BLOCK) xs[i] = x[(size_t)b * NIN + i];
  __syncthreads();
  float s = 0.f;
  for (int i = tid; i < NIN; i += BLOCK) { float v = xs[i]; s += v * v; }
  red[tid] = s; __syncthreads();
  for (int st = BLOCK / 2; st > 0; st >>= 1) {
    if (tid < st) red[tid] += red[tid + st];
    __syncthreads();
  }
  const float cx2 = red[0];
  __syncthreads();
  constexpr int CPT = (NOUT + BLOCK - 1) / BLOCK;
  const float onemc = fmaxf(1.f - cx2, EPSF);
  float yv[CPT];
  float ls = 0.f;
#pragma unroll
  for (int j = 0; j < CPT; ++j) {
    int o = tid + j * BLOCK;
    float y = 0.f;
    if (o < NOUT) {
      float d = 0.f;
      for (int k = 0; k < NIN; ++k) d = fmaf(xs[k], z[(size_t)k * NOUT + o], d);
      float znv = zn[o];
      float rv = r[o];
      float num = 2.f * (d / znv) * coshf(2.f * rv) - (1.f + cx2) * sinhf(2.f * rv);
      float mlr = 2.f * znv * asinhf(num / onemc);
      y = sinhf(mlr);
    }
    yv[j] = y; ls += y * y;
  }
  red[tid] = ls; __syncthreads();
  for (int st = BLOCK / 2; st > 0; st >>= 1) {
    if (tid < st) red[tid] += red[tid + st];
    __syncthreads();
  }
  const float denom = 1.f + sqrtf(1.f + red[0]);
#pragma unroll
  for (int j = 0; j < CPT; ++j) {
    int o = tid + j * BLOCK;
    if (o < NOUT) out[(size_t)b * NOUT + o] = yv[j] / denom;
  }
}

// ---------------- hrelu over rows (axis=-1) ---------------------------------
template <int N, int BLOCK>
__global__ __launch_bounds__(256) void hrelu_rows_kernel(
    const float* __restrict__ in, float* __restrict__ out) {
  const int b = blockIdx.x, tid = threadIdx.x;
  __shared__ float red[BLOCK];
  constexpr int CPT = N / BLOCK;
  float v[CPT];
  float s = 0.f;
#pragma unroll
  for (int j = 0; j < CPT; ++j) {
    v[j] = in[(size_t)b * N + tid + j * BLOCK];
    s += v[j] * v[j];
  }
  red[tid] = s; __syncthreads();
  for (int st = BLOCK / 2; st > 0; st >>= 1) {
    if (tid < st) red[tid] += red[tid + st];
    __syncthreads();
  }
  float n = sqrtf(fmaxf(red[0], EPSF));
  float f = atanhf(fminf(n, ATANH_CAP)) / n;
  __syncthreads();
  float s2 = 0.f;
#pragma unroll
  for (int j = 0; j < CPT; ++j) { v[j] = f * fmaxf(v[j], 0.f); s2 += v[j] * v[j]; }
  red[tid] = s2; __syncthreads();
  for (int st = BLOCK / 2; st > 0; st >>= 1) {
    if (tid < st) red[tid] += red[tid + st];
    __syncthreads();
  }
  float nt = sqrtf(fmaxf(red[0], EPSF));
  float gg = tanhf(nt) / nt;
#pragma unroll
  for (int j = 0; j < CPT; ++j)
    out[(size_t)b * N + tid + j * BLOCK] = gg * v[j];
}

// ---------------------------------------------------------------------------
static inline double beta_fn(double a, double b) {
  return std::exp(std::lgamma(a) + std::lgamma(b) - std::lgamma(a + b));
}

extern "C" void kernel_launch(void* const* d_in, const int* in_sizes, int n_in,
                              void* d_out, int out_size, void* d_ws, size_t ws_size,
                              hipStream_t stream) {
  const float* x   = (const float*)d_in[0];
  const float* z1  = (const float*)d_in[1];
  const float* b1  = (const float*)d_in[2];
  const float* z2  = (const float*)d_in[3];
  const float* b2  = (const float*)d_in[4];
  const float* z3  = (const float*)d_in[5];
  const float* b3  = (const float*)d_in[6];
  const float* z4  = (const float*)d_in[7];
  const float* b4  = (const float*)d_in[8];
  const float* zf1 = (const float*)d_in[9];
  const float* bf1 = (const float*)d_in[10];
  const float* zf2 = (const float*)d_in[11];
  const float* bf2 = (const float*)d_in[12];
  float* outp = (float*)d_out;

  float* ws    = (float*)d_ws;
  float* zn    = ws;                        // 2048
  float* flat  = ws + 2048;                 // 5632
  float* h1r   = ws + 7680;                 // 8192
  float* h1    = ws + 15872;                // 8704
  float* vm0   = ws + 24576;                // 786,432 (logmap'd input)
  float* mA    = vm0 + 786432;              // 2,097,152 (m1 / m3)
  float* mB    = mA + 2097152;              // 1,048,576 (m2 / m4)
  float* s2a   = mB + 1048576;              // 262,144 (s0 / s2 / s4)
  float* s2b   = s2a + 262144;              // 65,536 (s1 / s3)
  float* fA    = s2b + 65536;               // 65,536 (f1 / f3)
  float* fB    = fA + 65536;                // 16,384 (f2 / f4)
  unsigned short* zfu = (unsigned short*)(fB + 16384);
  unsigned short* zf1h = zfu;               //   3,072 (96*32)
  unsigned short* zf1l = zfu + 3072;
  unsigned short* zf2h = zfu + 6144;        //  51,200
  unsigned short* zf2l = zfu + 57344;
  unsigned short* zf3h = zfu + 108544;      // 401,408
  unsigned short* zf3l = zfu + 509952;
  unsigned short* zf4h = zfu + 911360;      // 147,456
  unsigned short* zf4l = zfu + 1058816;     // ends 1,206,272 ushorts

  const float s1  = (float)(beta_fn(27.0 / 2.0, 0.5) / beta_fn(3.0 / 2.0, 0.5));
  const float s2c = (float)(beta_fn(800.0 / 2.0, 0.5) / beta_fn(32.0 / 2.0, 0.5));
  const float s3  = (float)(beta_fn(3136.0 / 2.0, 0.5) / beta_fn(64.0 / 2.0, 0.5));
  const float s4  = (float)(beta_fn(1152.0 / 2.0, 0.5) / beta_fn(128.0 / 2.0, 0.5));

  auto g1 = [](int n) { return dim3((n + 255) / 256); };

  // prep: column norms + fragment-ordered hi/lo z
  znorm_kernel<<<2,  256, 0, stream>>>(z1, zn + 0, 27, 32);
  znorm_kernel<<<4,  256, 0, stream>>>(z2, zn + 32, 800, 64);
  znorm_kernel<<<8,  256, 0, stream>>>(z3, zn + 96, 3136, 128);
  znorm_kernel<<<8,  256, 0, stream>>>(z4, zn + 224, 1152, 128);
  znorm_kernel<<<32, 256, 0, stream>>>(zf1, zn + 352, 352, 512);
  znorm_kernel<<<63, 256, 0, stream>>>(zf2, zn + 864, 512, 1000);
  zfprep_kernel<3, 3, 12, 9, 32><<<12, 256, 0, stream>>>(z1, zf1h, zf1l);
  zfprep_kernel<32, 5, 25, 25, 64><<<200, 256, 0, stream>>>(z2, zf2h, zf2l);
  zfprep_kernel<64, 6, 49, 49, 128><<<1568, 256, 0, stream>>>(z3, zf3h, zf3l);
  zfprep_kernel<128, 7, 9, 9, 128><<<576, 256, 0, stream>>>(z4, zf4h, zf4l);

  // ---- layer 1: (16,3,128,128) -> m1 (16,32,64,64)
  logmap_s2_kernel<<<g1(262144), 256, 0, stream>>>(x, vm0, s2a, 3, 16384, 262144);
  hconv_mfma<3, 3, 12, 3, 1, 32, 128, 128, 8, 8, 4, 1>
      <<<4096, 256, 0, stream>>>(vm0, s2a, zf1h, zf1l, b1, zn + 0, mA, s2b, fA, s1);
  wavgpool_kernel<<<dim3(32, 16), 256, 0, stream>>>(mA, fA, flat, 32, 4096, 352, 0);

  // ---- layer 2: m1 -> m2 (16,64,32,32)
  hconv_mfma<32, 5, 25, 5, 2, 64, 64, 64, 8, 8, 4, 2>
      <<<1024, 512, 0, stream>>>(mA, s2b, zf2h, zf2l, b2, zn + 32, mB, s2a, fB, s2c);
  wavgpool_kernel<<<dim3(64, 16), 256, 0, stream>>>(mB, fB, flat, 64, 1024, 352, 32);

  // ---- layer 3: m2 -> m3 (16,128,16,16)
  hconv_mfma<64, 6, 49, 7, 3, 128, 32, 32, 4, 8, 2, 4>
      <<<512, 512, 0, stream>>>(mB, s2a, zf3h, zf3l, b3, zn + 96, mA, s2b, fA, s3);
  wavgpool_kernel<<<dim3(128, 16), 256, 0, stream>>>(mA, fA, flat, 128, 256, 352, 96);

  // ---- layer 4: m3 -> m4 (16,128,8,8)
  hconv_mfma<128, 7, 9, 3, 1, 128, 16, 16, 2, 8, 1, 8>
      <<<256, 512, 0, stream>>>(mA, s2b, zf4h, zf4l, b4, zn + 224, mB, s2a, fB, s4);
  wavgpool_kernel<<<dim3(128, 16), 256, 0, stream>>>(mB, fB, flat, 128, 64, 352, 224);

  // ---- head: flat (16,352) -> (16,512) -> hrelu -> (16,1000)
  pfc_kernel<352, 512, 256><<<16, 256, 0, stream>>>(flat, zf1, bf1, zn + 352, h1r);
  hrelu_rows_kernel<512, 256><<<16, 256, 0, stream>>>(h1r, h1);
  pfc_kernel<512, 1000, 256><<<16, 256, 0, stream>>>(h1, zf2, bf2, zn + 864, outp);

  (void)in_sizes; (void)n_in; (void)out_size; (void)ws_size;
}

// Round 6
// 313.742 us; speedup vs baseline: 9.8061x; 1.1682x over previous
//
#include <hip/hip_runtime.h>
#include <cmath>

// ---------------------------------------------------------------------------
// Hyperbolic MS-CNN (Poincare ball, c=1) — round 6.
//  * MFMA convs (split bf16 hi/lo, 3 MFMAs) with fused epilogue:
//    MLR -> sinh -> projection -> relu-tangent -> 2x2 maxpool -> s2/f maps.
//  * Fast transcendentals via v_exp/v_log/v_rcp.
//  * Two-stage parallel z-norms (replaces latency-bound single-block loops).
//  * L3 conv: 16 waves/block -> 100% wave-cap occupancy.
// ---------------------------------------------------------------------------

#define EPSF 1e-15f
#define ATANH_CAP 0.9999999f  // 1 - 1e-7

typedef __attribute__((ext_vector_type(8))) short short8;
typedef __attribute__((ext_vector_type(4))) float f32x4;

__device__ inline unsigned rne16(float f) {
  unsigned u = __float_as_uint(f);
  return (u + 0x7FFFu + ((u >> 16) & 1u)) >> 16;
}
__device__ inline float fexp2(float x) { return __builtin_amdgcn_exp2f(x); }
__device__ inline float flog2(float x) { return __builtin_amdgcn_logf(x); }
__device__ inline float frcp(float x) { return __builtin_amdgcn_rcpf(x); }

// atanh(min(n,cap))/n ; exact small-n series below 0.004
__device__ inline float atanh_over(float n) {
  float nc = fminf(n, ATANH_CAP);
  float f = 0.34657359f * flog2((1.f + nc) * frcp(1.f - nc)) * frcp(n);
  float s = 1.f + 0.33333333f * n * n;
  return (n < 0.004f) ? s : f;
}
// tanh(n)/n
__device__ inline float tanh_over(float n) {
  float p2 = fexp2(2.885390082f * n);  // e^{2n}
  float f = (1.f - 2.f * frcp(p2 + 1.f)) * frcp(n);
  float s = 1.f - 0.33333333f * n * n;
  return (n < 0.004f) ? s : f;
}
// sinh(twozn * asinh(q)) = sign(q) * (t^twozn - t^-twozn)/2, t=|q|+sqrt(q^2+1)
__device__ inline float sinh_zasinh(float q, float twozn) {
  float aq = fabsf(q);
  float t = aq + sqrtf(fmaf(aq, aq, 1.f));
  float p = fexp2(twozn * flog2(t));
  float y = 0.5f * (p - frcp(p));
  return copysignf(y, q);
}

// ---------------- z column norms, stage 1: partial sums ---------------------
// grid (ceil(Nout/64), 16); part layout [16][2048]; col range [coff, coff+Nout)
__global__ __launch_bounds__(256) void znorm_part_kernel(
    const float* __restrict__ z, float* __restrict__ part,
    int K, int Nout, int coff) {
  const int tid = threadIdx.x;
  const int col = blockIdx.x * 64 + (tid & 63);
  const int kg = (blockIdx.y << 2) + (tid >> 6);  // 0..63
  float s = 0.f;
  if (col < Nout)
    for (int k = kg; k < K; k += 64) {
      float v = z[(size_t)k * Nout + col];
      s += v * v;
    }
  __shared__ float red[256];
  red[tid] = s;
  __syncthreads();
  if (tid < 64 && col < Nout) {
    float t = red[tid] + red[tid + 64] + red[tid + 128] + red[tid + 192];
    part[(size_t)blockIdx.y * 2048 + coff + col] = t;
  }
}
// stage 2: sum 16 partials + sqrt, all z's at once (grid 8 x 256)
__global__ __launch_bounds__(256) void znorm_fin_kernel(
    const float* __restrict__ part, float* __restrict__ zn) {
  int c = blockIdx.x * 256 + threadIdx.x;
  float s = 0.f;
#pragma unroll
  for (int rr = 0; rr < 16; ++rr) s += part[rr * 2048 + c];
  zn[c] = sqrtf(fmaxf(s, EPSF));
}

// ---------------- z -> MFMA-fragment-ordered hi/lo bf16 ---------------------
// tile (ks, nt): lane l supplies B[k][n], k = ks*32+(l>>4)*8+i, n = nt*16+(l&15)
template <int CIN, int CSH, int TAPS, int KK, int COUT>
__global__ __launch_bounds__(256) void zfprep_kernel(
    const float* __restrict__ z, unsigned short* __restrict__ zh,
    unsigned short* __restrict__ zl) {
  constexpr int CPAD = 1 << CSH;
  constexpr int KP = TAPS * CPAD;
  constexpr int NT = COUT / 16;
  int t = blockIdx.x * 256 + threadIdx.x;
  if (t >= KP * COUT) return;
  int k = t / COUT, n = t - k * COUT;
  int ks = k >> 5, lg = (k >> 3) & 3, i = k & 7;
  int nt = n >> 4, lm = n & 15;
  size_t e = ((size_t)(ks * NT + nt) * 64 + lg * 16 + lm) * 8 + i;
  int tap = k >> CSH, c = k & (CPAD - 1);
  float val = (c < CIN && tap < KK) ? z[(size_t)(c * KK + tap) * COUT + n] : 0.f;
  unsigned hi = rne16(val);
  float hif = __uint_as_float(hi << 16);
  unsigned lo = rne16(val - hif);
  zh[e] = (unsigned short)hi;
  zl[e] = (unsigned short)lo;
}

// ---------------- logmap0 + per-pixel sum of squares ------------------------
__global__ __launch_bounds__(256) void logmap_s2_kernel(
    const float* __restrict__ in, float* __restrict__ out,
    float* __restrict__ s2, int C, int HW, int total) {
  int i = blockIdx.x * blockDim.x + threadIdx.x;
  if (i >= total) return;
  int b = i / HW, s = i - b * HW;
  const float* p = in + (size_t)b * C * HW + s;
  float ss = 0.f;
  for (int c = 0; c < C; ++c) { float v = p[(size_t)c * HW]; ss += v * v; }
  float n = sqrtf(fmaxf(ss, EPSF));
  float f = atanh_over(n);
  float* q = out + (size_t)b * C * HW + s;
  for (int c = 0; c < C; ++c) q[(size_t)c * HW] = f * p[(size_t)c * HW];
  s2[i] = f * f * ss;
}

// ---------------- weighted spatial mean: flat = (1/HW) sum f[i]*vm[c][i] ----
__global__ __launch_bounds__(256) void wavgpool_kernel(
    const float* __restrict__ vm, const float* __restrict__ f,
    float* __restrict__ flat, int C, int HW, int flatC, int coff) {
  int c = blockIdx.x, b = blockIdx.y, tid = threadIdx.x;
  const float* p = vm + ((size_t)b * C + c) * HW;
  const float* q = f + (size_t)b * HW;
  float s = 0.f;
  for (int i = tid; i < HW; i += blockDim.x) s += p[i] * q[i];
  __shared__ float red[256];
  red[tid] = s; __syncthreads();
  for (int st = 128; st > 0; st >>= 1) {
    if (tid < st) red[tid] += red[tid + st];
    __syncthreads();
  }
  if (tid == 0) flat[(size_t)b * flatC + coff + c] = red[0] / (float)HW;
}

// ---------------- MFMA fused hconv + hrelu-tangent + maxpool + maps ---------
// vin: tangent (B,CIN,H,W); s2map: per-pixel sum_c vin^2 (B,H,W)
// mout: pooled tangent (B,COUT,H/2,W/2); s2out/fout: (B,H/2,W/2)
template <int CIN, int CSH, int TAPS, int K, int PAD, int COUT, int H, int W,
          int TH, int TW, int WM, int WN>
__global__ __launch_bounds__(WM * WN * 64) void hconv_mfma(
    const float* __restrict__ vin, const float* __restrict__ s2map,
    const unsigned short* __restrict__ zfh,
    const unsigned short* __restrict__ zfl,
    const float* __restrict__ r, const float* __restrict__ zn,
    float* __restrict__ mout, float* __restrict__ s2out,
    float* __restrict__ fout, float scale) {
  constexpr int NTHR = WM * WN * 64;
  constexpr int CPAD = 1 << CSH;
  constexpr int KK = K * K;
  constexpr int MT = WM * 16;
  static_assert(MT == TH * TW, "tile rows mismatch");
  constexpr int NT = COUT / 16;
  constexpr int NTW = NT / WN;
  static_assert(NTW * WN == NT, "");
  constexpr int NK = TAPS * CPAD / 32;
  static_assert(NK * 32 == TAPS * CPAD, "K-step misalign");
  constexpr int SY = TH + K - 1, SX = TW + K - 1;
  constexpr int NPOS = SY * SX;
  constexpr int RWU = (CPAD >= 32) ? (CPAD + 8) : 16;  // 16B-aligned rows
  constexpr int TRS = MT + 4;
  constexpr int WINU = NPOS * RWU;
  constexpr int TRU = 2 * COUT * TRS;
  constexpr int SHU = (2 * WINU > TRU) ? 2 * WINU : TRU;
  constexpr int HO = H / 2, WO = W / 2;
  constexpr int PH = TH / 2, PW = TW / 2, NPP = PH * PW;
  constexpr int CG0 = NTHR / NPP;
  constexpr int CG = (CG0 < COUT) ? CG0 : COUT;
  constexpr int CPG = COUT / CG;
  static_assert(CPG * CG == COUT, "pool split");

  __shared__ __align__(16) unsigned short winbuf[SHU];
  __shared__ float s2w[NPOS];
  __shared__ float gA[MT], cA[MT];
  __shared__ float c1b[COUT], shb[COUT], z2b[COUT];
  __shared__ float redw[(WN > 1) ? WN * MT : 1];
  __shared__ float pacc[NTHR];
  unsigned short* winh = winbuf;
  unsigned short* winl = winbuf + WINU;

  const int tid = threadIdx.x;
  int bid = blockIdx.x;
  constexpr int TXC = W / TW, TYC = H / TH;
  const int tx = bid % TXC; bid /= TXC;
  const int ty = bid % TYC; const int b = bid / TYC;
  const int y0 = ty * TH, x0 = tx * TW;

  if (tid < COUT) {
    float rv = r[tid];
    float znv = zn[tid];
    float ch = coshf(2.f * rv), sh = sinhf(2.f * rv);
    c1b[tid] = 2.f * ch / znv;
    shb[tid] = sh;
    z2b[tid] = 2.f * znv;
  }
  // stage window as hi/lo bf16 planes (+ zero padding)
  const float* vb = vin + (size_t)b * CIN * H * W;
  for (int idx = tid; idx < CPAD * NPOS; idx += NTHR) {
    int c = idx / NPOS;
    int pos = idx - c * NPOS;
    int sy = pos / SX, sx = pos - sy * SX;
    float val = 0.f;
    if (c < CIN) {
      int gy = y0 + sy - PAD, gx = x0 + sx - PAD;
      if (gy >= 0 && gy < H && gx >= 0 && gx < W)
        val = vb[((size_t)c * H + gy) * W + gx];
    }
    unsigned hi = rne16(val);
    float hif = __uint_as_float(hi << 16);
    unsigned lo = rne16(val - hif);
    winh[pos * RWU + c] = (unsigned short)hi;
    winl[pos * RWU + c] = (unsigned short)lo;
  }
  const float* s2b = s2map + (size_t)b * H * W;
  for (int i = tid; i < NPOS; i += NTHR) {
    int sy = i / SX, sx = i - sy * SX;
    int gy = y0 + sy - PAD, gx = x0 + sx - PAD;
    s2w[i] = (gy >= 0 && gy < H && gx >= 0 && gx < W) ? s2b[gy * W + gx] : 0.f;
  }
  __syncthreads();

  if (tid < MT) {
    int py = tid / TW, px = tid - (tid / TW) * TW;
    float s = 0.f;
    for (int iy = 0; iy < K; ++iy)
      for (int ix = 0; ix < K; ++ix)
        s += s2w[(py + iy) * SX + (px + ix)];
    float n = sqrtf(fmaxf(scale * scale * s, EPSF));
    float th = n * tanh_over(n);           // tanh(n)
    gA[tid] = th * scale * frcp(n);        // maps raw dot -> expmap'd dot
    cA[tid] = th * th;                     // cx2
  }
  __syncthreads();

  const int w = __builtin_amdgcn_readfirstlane(tid >> 6);
  const int wm = w % WM, wn = w / WM;
  const int lane = tid & 63, lm = lane & 15, lg = lane >> 4;
  const int m = wm * 16 + lm;
  const int py = m / TW, px = m - (m / TW) * TW;
  const int nt0 = wn * NTW;

  f32x4 acc[NTW];
#pragma unroll
  for (int j = 0; j < NTW; ++j) acc[j] = (f32x4){0.f, 0.f, 0.f, 0.f};

  for (int ks = 0; ks < NK; ++ks) {
    const int kbase = ks * 32 + lg * 8;
    const int tap = kbase >> CSH;
    const int c0 = kbase & (CPAD - 1);
    const unsigned short* bp = zfh + (size_t)(ks * NT + nt0) * 512 + lane * 8;
    const unsigned short* bq = zfl + (size_t)(ks * NT + nt0) * 512 + lane * 8;
    uint4 Bh[NTW], Bl[NTW];
#pragma unroll
    for (int j = 0; j < NTW; ++j) {
      Bh[j] = *(const uint4*)(bp + j * 512);
      Bl[j] = *(const uint4*)(bq + j * 512);
    }
    short8 ahi = {}, alo = {};
    bool valid = true;
    if constexpr (TAPS != KK) valid = (tap < KK);
    if (valid) {
      const int iy = tap / K, ix = tap - (tap / K) * K;
      const int lofs = ((py + iy) * SX + (px + ix)) * RWU + c0;
      ahi = *(const short8*)(winh + lofs);
      alo = *(const short8*)(winl + lofs);
    }
#pragma unroll
    for (int j = 0; j < NTW; ++j) {
      short8 bhv = __builtin_bit_cast(short8, Bh[j]);
      short8 blv = __builtin_bit_cast(short8, Bl[j]);
      acc[j] = __builtin_amdgcn_mfma_f32_16x16x32_bf16(ahi, bhv, acc[j], 0, 0, 0);
      acc[j] = __builtin_amdgcn_mfma_f32_16x16x32_bf16(ahi, blv, acc[j], 0, 0, 0);
      acc[j] = __builtin_amdgcn_mfma_f32_16x16x32_bf16(alo, bhv, acc[j], 0, 0, 0);
    }
  }

  // epilogue: D row = wm*16 + lg*4 + reg, col = (nt0+j)*16 + lm
  float ls[4] = {0.f, 0.f, 0.f, 0.f};
  float gR[4], rcpom[4], onePc[4];
#pragma unroll
  for (int reg = 0; reg < 4; ++reg) {
    int rr = wm * 16 + lg * 4 + reg;
    float cx2 = cA[rr];
    gR[reg] = gA[rr];
    rcpom[reg] = frcp(fmaxf(1.f - cx2, EPSF));
    onePc[reg] = 1.f + cx2;
  }
#pragma unroll
  for (int j = 0; j < NTW; ++j) {
    int o = (nt0 + j) * 16 + lm;
    float c1 = c1b[o], sh = shb[o], z2 = z2b[o];
#pragma unroll
    for (int reg = 0; reg < 4; ++reg) {
      float num = c1 * (gR[reg] * acc[j][reg]) - onePc[reg] * sh;
      float yv = sinh_zasinh(num * rcpom[reg], z2);
      acc[j][reg] = yv;
      ls[reg] += yv * yv;
    }
  }
#pragma unroll
  for (int mask = 1; mask < 16; mask <<= 1)
#pragma unroll
    for (int reg = 0; reg < 4; ++reg)
      ls[reg] += __shfl_xor(ls[reg], mask);

  if constexpr (WN > 1) {
    if (lm == 0) {
#pragma unroll
      for (int reg = 0; reg < 4; ++reg)
        redw[wn * MT + wm * 16 + lg * 4 + reg] = ls[reg];
    }
  }
  __syncthreads();  // redw visible; all waves done reading win planes
  if constexpr (WN > 1) {
#pragma unroll
    for (int reg = 0; reg < 4; ++reg) {
      float s = 0.f;
#pragma unroll
      for (int k2 = 0; k2 < WN; ++k2)
        s += redw[k2 * MT + wm * 16 + lg * 4 + reg];
      ls[reg] = s;
    }
  }
  float fs[4];
#pragma unroll
  for (int reg = 0; reg < 4; ++reg) {
    float inv = frcp(1.f + sqrtf(1.f + ls[reg]));   // ball projection
    float ny = sqrtf(fmaxf(ls[reg] * inv * inv, EPSF));
    fs[reg] = atanh_over(ny) * inv;                 // logmap0 * proj
  }
  float* tr = (float*)winbuf;  // [COUT][TRS] overlay
#pragma unroll
  for (int j = 0; j < NTW; ++j) {
    int o = (nt0 + j) * 16 + lm;
#pragma unroll
    for (int reg = 0; reg < 4; ++reg) {
      int rr = wm * 16 + lg * 4 + reg;
      tr[o * TRS + rr] = fs[reg] * fmaxf(acc[j][reg], 0.f);
    }
  }
  __syncthreads();

  // fused 2x2 maxpool (tangent space) + per-pooled-pixel s2/f maps
  const int y0p = y0 >> 1, x0p = x0 >> 1;
  if (tid < NPP * CG) {
    int cg = tid / NPP, p = tid - cg * NPP;
    int ppy = p / PW, ppx = p - ppy * PW;
    const float* base = tr + (ppy * 2) * TW + ppx * 2;
    float ss = 0.f;
#pragma unroll
    for (int j = 0; j < CPG; ++j) {
      int c = cg * CPG + j;
      const float* rp = base + c * TRS;
      float mv = fmaxf(fmaxf(rp[0], rp[1]), fmaxf(rp[TW], rp[TW + 1]));
      mout[((size_t)(b * COUT + c) * HO + y0p + ppy) * WO + x0p + ppx] = mv;
      ss += mv * mv;
    }
    pacc[cg * NPP + p] = ss;
  }
  __syncthreads();
  if (tid < NPP) {
    float ss = 0.f;
    for (int k2 = 0; k2 < CG; ++k2) ss += pacc[k2 * NPP + tid];
    int ppy = tid / PW, ppx = tid - (tid / PW) * PW;
    size_t pix = ((size_t)b * HO + y0p + ppy) * WO + x0p + ppx;
    s2out[pix] = ss;
    float n = sqrtf(fmaxf(ss, EPSF));
    fout[pix] = tanh_over(n);
  }
}

// ---------------- Poincare FC over rows (head; libm precision) --------------
template <int NIN, int NOUT, int BLOCK>
__global__ __launch_bounds__(256) void pfc_kernel(
    const float* __restrict__ x, const float* __restrict__ z,
    const float* __restrict__ r, const float* __restrict__ zn,
    float* __restrict__ out) {
  const int b = blockIdx.x, tid = threadIdx.x;
  __shared__ float xs[NIN];
  __shared__ float red[BLOCK];
  for (int i = tid; i < NIN; i += BLOCK) xs[i] = x[(size_t)b * NIN + i];
  __syncthreads();
  float s = 0.f;
  for (int i = tid; i < NIN; i += BLOCK) { float v = xs[i]; s += v * v; }
  red[tid] = s; __syncthreads();
  for (int st = BLOCK / 2; st > 0; st >>= 1) {
    if (tid < st) red[tid] += red[tid + st];
    __syncthreads();
  }
  const float cx2 = red[0];
  __syncthreads();
  constexpr int CPT = (NOUT + BLOCK - 1) / BLOCK;
  const float onemc = fmaxf(1.f - cx2, EPSF);
  float yv[CPT];
  float ls = 0.f;
#pragma unroll
  for (int j = 0; j < CPT; ++j) {
    int o = tid + j * BLOCK;
    float y = 0.f;
    if (o < NOUT) {
      float d = 0.f;
      for (int k = 0; k < NIN; ++k) d = fmaf(xs[k], z[(size_t)k * NOUT + o], d);
      float znv = zn[o];
      float rv = r[o];
      float num = 2.f * (d / znv) * coshf(2.f * rv) - (1.f + cx2) * sinhf(2.f * rv);
      float mlr = 2.f * znv * asinhf(num / onemc);
      y = sinhf(mlr);
    }
    yv[j] = y; ls += y * y;
  }
  red[tid] = ls; __syncthreads();
  for (int st = BLOCK / 2; st > 0; st >>= 1) {
    if (tid < st) red[tid] += red[tid + st];
    __syncthreads();
  }
  const float denom = 1.f + sqrtf(1.f + red[0]);
#pragma unroll
  for (int j = 0; j < CPT; ++j) {
    int o = tid + j * BLOCK;
    if (o < NOUT) out[(size_t)b * NOUT + o] = yv[j] / denom;
  }
}

// ---------------- hrelu over rows (axis=-1) ---------------------------------
template <int N, int BLOCK>
__global__ __launch_bounds__(256) void hrelu_rows_kernel(
    const float* __restrict__ in, float* __restrict__ out) {
  const int b = blockIdx.x, tid = threadIdx.x;
  __shared__ float red[BLOCK];
  constexpr int CPT = N / BLOCK;
  float v[CPT];
  float s = 0.f;
#pragma unroll
  for (int j = 0; j < CPT; ++j) {
    v[j] = in[(size_t)b * N + tid + j * BLOCK];
    s += v[j] * v[j];
  }
  red[tid] = s; __syncthreads();
  for (int st = BLOCK / 2; st > 0; st >>= 1) {
    if (tid < st) red[tid] += red[tid + st];
    __syncthreads();
  }
  float n = sqrtf(fmaxf(red[0], EPSF));
  float f = atanhf(fminf(n, ATANH_CAP)) / n;
  __syncthreads();
  float s2 = 0.f;
#pragma unroll
  for (int j = 0; j < CPT; ++j) { v[j] = f * fmaxf(v[j], 0.f); s2 += v[j] * v[j]; }
  red[tid] = s2; __syncthreads();
  for (int st = BLOCK / 2; st > 0; st >>= 1) {
    if (tid < st) red[tid] += red[tid + st];
    __syncthreads();
  }
  float nt = sqrtf(fmaxf(red[0], EPSF));
  float gg = tanhf(nt) / nt;
#pragma unroll
  for (int j = 0; j < CPT; ++j)
    out[(size_t)b * N + tid + j * BLOCK] = gg * v[j];
}

// ---------------------------------------------------------------------------
static inline double beta_fn(double a, double b) {
  return std::exp(std::lgamma(a) + std::lgamma(b) - std::lgamma(a + b));
}

extern "C" void kernel_launch(void* const* d_in, const int* in_sizes, int n_in,
                              void* d_out, int out_size, void* d_ws, size_t ws_size,
                              hipStream_t stream) {
  const float* x   = (const float*)d_in[0];
  const float* z1  = (const float*)d_in[1];
  const float* b1  = (const float*)d_in[2];
  const float* z2  = (const float*)d_in[3];
  const float* b2  = (const float*)d_in[4];
  const float* z3  = (const float*)d_in[5];
  const float* b3  = (const float*)d_in[6];
  const float* z4  = (const float*)d_in[7];
  const float* b4  = (const float*)d_in[8];
  const float* zf1 = (const float*)d_in[9];
  const float* bf1 = (const float*)d_in[10];
  const float* zf2 = (const float*)d_in[11];
  const float* bf2 = (const float*)d_in[12];
  float* outp = (float*)d_out;

  float* ws    = (float*)d_ws;
  float* zn    = ws;                        // 2048
  float* flat  = ws + 2048;                 // 5632
  float* h1r   = ws + 7680;                 // 8192
  float* h1    = ws + 15872;                // 8704
  float* vm0   = ws + 24576;                // 786,432 (logmap'd input)
  float* mA    = vm0 + 786432;              // 2,097,152 (m1 / m3)
  float* mB    = mA + 2097152;              // 1,048,576 (m2 / m4)
  float* s2a   = mB + 1048576;              // 262,144 (s0 / s2 / s4)
  float* s2b   = s2a + 262144;              // 65,536 (s1 / s3)
  float* fA    = s2b + 65536;               // 65,536 (f1 / f3)
  float* fB    = fA + 65536;                // 16,384 (f2 / f4)
  float* part  = fB + 16384;                // 32,768 (16 x 2048 partials)
  unsigned short* zfu = (unsigned short*)(part + 32768);
  unsigned short* zf1h = zfu;               //   3,072 (96*32)
  unsigned short* zf1l = zfu + 3072;
  unsigned short* zf2h = zfu + 6144;        //  51,200
  unsigned short* zf2l = zfu + 57344;
  unsigned short* zf3h = zfu + 108544;      // 401,408
  unsigned short* zf3l = zfu + 509952;
  unsigned short* zf4h = zfu + 911360;      // 147,456
  unsigned short* zf4l = zfu + 1058816;     // ends 1,206,272 ushorts

  const float s1  = (float)(beta_fn(27.0 / 2.0, 0.5) / beta_fn(3.0 / 2.0, 0.5));
  const float s2c = (float)(beta_fn(800.0 / 2.0, 0.5) / beta_fn(32.0 / 2.0, 0.5));
  const float s3  = (float)(beta_fn(3136.0 / 2.0, 0.5) / beta_fn(64.0 / 2.0, 0.5));
  const float s4  = (float)(beta_fn(1152.0 / 2.0, 0.5) / beta_fn(128.0 / 2.0, 0.5));

  auto g1 = [](int n) { return dim3((n + 255) / 256); };

  // prep: column norms (two-stage, parallel over K) + fragment-ordered z
  znorm_part_kernel<<<dim3(1, 16),  256, 0, stream>>>(z1, part, 27, 32, 0);
  znorm_part_kernel<<<dim3(1, 16),  256, 0, stream>>>(z2, part, 800, 64, 32);
  znorm_part_kernel<<<dim3(2, 16),  256, 0, stream>>>(z3, part, 3136, 128, 96);
  znorm_part_kernel<<<dim3(2, 16),  256, 0, stream>>>(z4, part, 1152, 128, 224);
  znorm_part_kernel<<<dim3(8, 16),  256, 0, stream>>>(zf1, part, 352, 512, 352);
  znorm_part_kernel<<<dim3(16, 16), 256, 0, stream>>>(zf2, part, 512, 1000, 864);
  znorm_fin_kernel<<<8, 256, 0, stream>>>(part, zn);
  zfprep_kernel<3, 3, 12, 9, 32><<<12, 256, 0, stream>>>(z1, zf1h, zf1l);
  zfprep_kernel<32, 5, 25, 25, 64><<<200, 256, 0, stream>>>(z2, zf2h, zf2l);
  zfprep_kernel<64, 6, 49, 49, 128><<<1568, 256, 0, stream>>>(z3, zf3h, zf3l);
  zfprep_kernel<128, 7, 9, 9, 128><<<576, 256, 0, stream>>>(z4, zf4h, zf4l);

  // ---- layer 1: (16,3,128,128) -> m1 (16,32,64,64)
  logmap_s2_kernel<<<g1(262144), 256, 0, stream>>>(x, vm0, s2a, 3, 16384, 262144);
  hconv_mfma<3, 3, 12, 3, 1, 32, 128, 128, 8, 8, 4, 1>
      <<<4096, 256, 0, stream>>>(vm0, s2a, zf1h, zf1l, b1, zn + 0, mA, s2b, fA, s1);
  wavgpool_kernel<<<dim3(32, 16), 256, 0, stream>>>(mA, fA, flat, 32, 4096, 352, 0);

  // ---- layer 2: m1 -> m2 (16,64,32,32)
  hconv_mfma<32, 5, 25, 5, 2, 64, 64, 64, 8, 8, 4, 2>
      <<<1024, 512, 0, stream>>>(mA, s2b, zf2h, zf2l, b2, zn + 32, mB, s2a, fB, s2c);
  wavgpool_kernel<<<dim3(64, 16), 256, 0, stream>>>(mB, fB, flat, 64, 1024, 352, 32);

  // ---- layer 3: m2 -> m3 (16,128,16,16)  [16 waves -> 100% wave cap]
  hconv_mfma<64, 6, 49, 7, 3, 128, 32, 32, 4, 8, 2, 8>
      <<<512, 1024, 0, stream>>>(mB, s2a, zf3h, zf3l, b3, zn + 96, mA, s2b, fA, s3);
  wavgpool_kernel<<<dim3(128, 16), 256, 0, stream>>>(mA, fA, flat, 128, 256, 352, 96);

  // ---- layer 4: m3 -> m4 (16,128,8,8)
  hconv_mfma<128, 7, 9, 3, 1, 128, 16, 16, 2, 8, 1, 8>
      <<<256, 512, 0, stream>>>(mA, s2b, zf4h, zf4l, b4, zn + 224, mB, s2a, fB, s4);
  wavgpool_kernel<<<dim3(128, 16), 256, 0, stream>>>(mB, fB, flat, 128, 64, 352, 224);

  // ---- head: flat (16,352) -> (16,512) -> hrelu -> (16,1000)
  pfc_kernel<352, 512, 256><<<16, 256, 0, stream>>>(flat, zf1, bf1, zn + 352, h1r);
  hrelu_rows_kernel<512, 256><<<16, 256, 0, stream>>>(h1r, h1);
  pfc_kernel<512, 1000, 256><<<16, 256, 0, stream>>>(h1, zf2, bf2, zn + 864, outp);

  (void)in_sizes; (void)n_in; (void)out_size; (void)ws_size;
}

// Round 7
// 303.106 us; speedup vs baseline: 10.1501x; 1.0351x over previous
//
#include <hip/hip_runtime.h>
#include <cmath>

// ---------------------------------------------------------------------------
// Hyperbolic MS-CNN (Poincare ball, c=1) — round 7.
//  * MFMA convs (split bf16 hi/lo, 3 MFMAs) + fused epilogue (MLR -> sinh ->
//    projection -> relu-tangent -> maxpool -> s2/f maps).
//  * B-fragment double-buffer prefetch (hides L2 latency under MFMA).
//  * Vectorized conflict-free LDS staging (ds_write_b128 granules).
// ---------------------------------------------------------------------------

#define EPSF 1e-15f
#define ATANH_CAP 0.9999999f  // 1 - 1e-7

typedef __attribute__((ext_vector_type(8))) short short8;
typedef __attribute__((ext_vector_type(4))) float f32x4;

__device__ inline unsigned rne16(float f) {
  unsigned u = __float_as_uint(f);
  return (u + 0x7FFFu + ((u >> 16) & 1u)) >> 16;
}
__device__ inline float fexp2(float x) { return __builtin_amdgcn_exp2f(x); }
__device__ inline float flog2(float x) { return __builtin_amdgcn_logf(x); }
__device__ inline float frcp(float x) { return __builtin_amdgcn_rcpf(x); }

__device__ inline float atanh_over(float n) {
  float nc = fminf(n, ATANH_CAP);
  float f = 0.34657359f * flog2((1.f + nc) * frcp(1.f - nc)) * frcp(n);
  float s = 1.f + 0.33333333f * n * n;
  return (n < 0.004f) ? s : f;
}
__device__ inline float tanh_over(float n) {
  float p2 = fexp2(2.885390082f * n);  // e^{2n}
  float f = (1.f - 2.f * frcp(p2 + 1.f)) * frcp(n);
  float s = 1.f - 0.33333333f * n * n;
  return (n < 0.004f) ? s : f;
}
__device__ inline float sinh_zasinh(float q, float twozn) {
  float aq = fabsf(q);
  float t = aq + sqrtf(fmaf(aq, aq, 1.f));
  float p = fexp2(twozn * flog2(t));
  float y = 0.5f * (p - frcp(p));
  return copysignf(y, q);
}

// ---------------- z column norms, stage 1: partial sums ---------------------
__global__ __launch_bounds__(256) void znorm_part_kernel(
    const float* __restrict__ z, float* __restrict__ part,
    int K, int Nout, int coff) {
  const int tid = threadIdx.x;
  const int col = blockIdx.x * 64 + (tid & 63);
  const int kg = (blockIdx.y << 2) + (tid >> 6);
  float s = 0.f;
  if (col < Nout)
    for (int k = kg; k < K; k += 64) {
      float v = z[(size_t)k * Nout + col];
      s += v * v;
    }
  __shared__ float red[256];
  red[tid] = s;
  __syncthreads();
  if (tid < 64 && col < Nout) {
    float t = red[tid] + red[tid + 64] + red[tid + 128] + red[tid + 192];
    part[(size_t)blockIdx.y * 2048 + coff + col] = t;
  }
}
__global__ __launch_bounds__(256) void znorm_fin_kernel(
    const float* __restrict__ part, float* __restrict__ zn) {
  int c = blockIdx.x * 256 + threadIdx.x;
  float s = 0.f;
#pragma unroll
  for (int rr = 0; rr < 16; ++rr) s += part[rr * 2048 + c];
  zn[c] = sqrtf(fmaxf(s, EPSF));
}

// ---------------- z -> MFMA-fragment-ordered hi/lo bf16 ---------------------
template <int CIN, int CSH, int TAPS, int KK, int COUT>
__global__ __launch_bounds__(256) void zfprep_kernel(
    const float* __restrict__ z, unsigned short* __restrict__ zh,
    unsigned short* __restrict__ zl) {
  constexpr int CPAD = 1 << CSH;
  constexpr int KP = TAPS * CPAD;
  constexpr int NT = COUT / 16;
  int t = blockIdx.x * 256 + threadIdx.x;
  if (t >= KP * COUT) return;
  int k = t / COUT, n = t - k * COUT;
  int ks = k >> 5, lg = (k >> 3) & 3, i = k & 7;
  int nt = n >> 4, lm = n & 15;
  size_t e = ((size_t)(ks * NT + nt) * 64 + lg * 16 + lm) * 8 + i;
  int tap = k >> CSH, c = k & (CPAD - 1);
  float val = (c < CIN && tap < KK) ? z[(size_t)(c * KK + tap) * COUT + n] : 0.f;
  unsigned hi = rne16(val);
  float hif = __uint_as_float(hi << 16);
  unsigned lo = rne16(val - hif);
  zh[e] = (unsigned short)hi;
  zl[e] = (unsigned short)lo;
}

// ---------------- logmap0 + per-pixel sum of squares ------------------------
__global__ __launch_bounds__(256) void logmap_s2_kernel(
    const float* __restrict__ in, float* __restrict__ out,
    float* __restrict__ s2, int C, int HW, int total) {
  int i = blockIdx.x * blockDim.x + threadIdx.x;
  if (i >= total) return;
  int b = i / HW, s = i - b * HW;
  const float* p = in + (size_t)b * C * HW + s;
  float ss = 0.f;
  for (int c = 0; c < C; ++c) { float v = p[(size_t)c * HW]; ss += v * v; }
  float n = sqrtf(fmaxf(ss, EPSF));
  float f = atanh_over(n);
  float* q = out + (size_t)b * C * HW + s;
  for (int c = 0; c < C; ++c) q[(size_t)c * HW] = f * p[(size_t)c * HW];
  s2[i] = f * f * ss;
}

// ---------------- weighted spatial mean -------------------------------------
__global__ __launch_bounds__(256) void wavgpool_kernel(
    const float* __restrict__ vm, const float* __restrict__ f,
    float* __restrict__ flat, int C, int HW, int flatC, int coff) {
  int c = blockIdx.x, b = blockIdx.y, tid = threadIdx.x;
  const float* p = vm + ((size_t)b * C + c) * HW;
  const float* q = f + (size_t)b * HW;
  float s = 0.f;
  for (int i = tid; i < HW; i += blockDim.x) s += p[i] * q[i];
  __shared__ float red[256];
  red[tid] = s; __syncthreads();
  for (int st = 128; st > 0; st >>= 1) {
    if (tid < st) red[tid] += red[tid + st];
    __syncthreads();
  }
  if (tid == 0) flat[(size_t)b * flatC + coff + c] = red[0] / (float)HW;
}

// ---------------- MFMA fused hconv + hrelu-tangent + maxpool + maps ---------
template <int CIN, int CSH, int TAPS, int K, int PAD, int COUT, int H, int W,
          int TH, int TW, int WM, int WN>
__global__ __launch_bounds__(WM * WN * 64) void hconv_mfma(
    const float* __restrict__ vin, const float* __restrict__ s2map,
    const unsigned short* __restrict__ zfh,
    const unsigned short* __restrict__ zfl,
    const float* __restrict__ r, const float* __restrict__ zn,
    float* __restrict__ mout, float* __restrict__ s2out,
    float* __restrict__ fout, float scale) {
  constexpr int NTHR = WM * WN * 64;
  constexpr int CPAD = 1 << CSH;
  constexpr int KK = K * K;
  constexpr int MT = WM * 16;
  static_assert(MT == TH * TW, "tile rows mismatch");
  constexpr int NT = COUT / 16;
  constexpr int NTW = NT / WN;
  static_assert(NTW * WN == NT, "");
  constexpr int NK = TAPS * CPAD / 32;
  static_assert(NK * 32 == TAPS * CPAD, "K-step misalign");
  constexpr int SY = TH + K - 1, SX = TW + K - 1;
  constexpr int NPOS = SY * SX;
  constexpr int RWU = (CPAD >= 32) ? (CPAD + 8) : CPAD;  // 16B-aligned rows
  constexpr int CGR = CPAD / 8;  // 8-ushort granules per row
  constexpr int TRS = MT + 4;
  constexpr int WINU = NPOS * RWU;
  constexpr int TRU = 2 * COUT * TRS;
  constexpr int SHU = (2 * WINU > TRU) ? 2 * WINU : TRU;
  constexpr int HO = H / 2, WO = W / 2;
  constexpr int PH = TH / 2, PW = TW / 2, NPP = PH * PW;
  constexpr int CG0 = NTHR / NPP;
  constexpr int CG = (CG0 < COUT) ? CG0 : COUT;
  constexpr int CPG = COUT / CG;
  static_assert(CPG * CG == COUT, "pool split");

  __shared__ __align__(16) unsigned short winbuf[SHU];
  __shared__ float s2w[NPOS];
  __shared__ float gA[MT], cA[MT];
  __shared__ float c1b[COUT], shb[COUT], z2b[COUT];
  __shared__ float redw[(WN > 1) ? WN * MT : 1];
  __shared__ float pacc[NTHR];
  unsigned short* winh = winbuf;
  unsigned short* winl = winbuf + WINU;

  const int tid = threadIdx.x;
  int bid = blockIdx.x;
  constexpr int TXC = W / TW, TYC = H / TH;
  const int tx = bid % TXC; bid /= TXC;
  const int ty = bid % TYC; const int b = bid / TYC;
  const int y0 = ty * TH, x0 = tx * TW;

  if (tid < COUT) {
    float rv = r[tid];
    float znv = zn[tid];
    float ch = coshf(2.f * rv), sh = sinhf(2.f * rv);
    c1b[tid] = 2.f * ch / znv;
    shb[tid] = sh;
    z2b[tid] = 2.f * znv;
  }
  // vectorized staging: thread = (granule cg, pos); coalesced global reads,
  // one ds_write_b128 per plane (conflict-free: row stride spreads quads)
  const float* vb = vin + (size_t)b * CIN * H * W;
  for (int idx = tid; idx < CGR * NPOS; idx += NTHR) {
    int cg = idx / NPOS;
    int pos = idx - cg * NPOS;
    int sy = pos / SX, sx = pos - sy * SX;
    int gy = y0 + sy - PAD, gx = x0 + sx - PAD;
    bool inb = (gy >= 0 && gy < H && gx >= 0 && gx < W);
    const float* gp = vb + (size_t)(cg * 8) * H * W + gy * W + gx;
    short8 hv, lv;
#pragma unroll
    for (int j = 0; j < 8; ++j) {
      float val = 0.f;
      if constexpr (CIN == CPAD) {
        if (inb) val = gp[(size_t)j * H * W];
      } else {
        if (inb && (cg * 8 + j) < CIN) val = gp[(size_t)j * H * W];
      }
      unsigned hi = rne16(val);
      float hif = __uint_as_float(hi << 16);
      unsigned lo = rne16(val - hif);
      hv[j] = (short)hi;
      lv[j] = (short)lo;
    }
    *(short8*)(winh + pos * RWU + cg * 8) = hv;
    *(short8*)(winl + pos * RWU + cg * 8) = lv;
  }
  const float* s2bp = s2map + (size_t)b * H * W;
  for (int i = tid; i < NPOS; i += NTHR) {
    int sy = i / SX, sx = i - sy * SX;
    int gy = y0 + sy - PAD, gx = x0 + sx - PAD;
    s2w[i] = (gy >= 0 && gy < H && gx >= 0 && gx < W) ? s2bp[gy * W + gx] : 0.f;
  }
  __syncthreads();

  if (tid < MT) {
    int py = tid / TW, px = tid - (tid / TW) * TW;
    float s = 0.f;
    for (int iy = 0; iy < K; ++iy)
      for (int ix = 0; ix < K; ++ix)
        s += s2w[(py + iy) * SX + (px + ix)];
    float n = sqrtf(fmaxf(scale * scale * s, EPSF));
    float th = n * tanh_over(n);
    gA[tid] = th * scale * frcp(n);
    cA[tid] = th * th;
  }
  __syncthreads();

  const int w = __builtin_amdgcn_readfirstlane(tid >> 6);
  const int wm = w % WM, wn = w / WM;
  const int lane = tid & 63, lm = lane & 15, lg = lane >> 4;
  const int m = wm * 16 + lm;
  const int py = m / TW, px = m - (m / TW) * TW;
  const int nt0 = wn * NTW;

  f32x4 acc[NTW];
#pragma unroll
  for (int j = 0; j < NTW; ++j) acc[j] = (f32x4){0.f, 0.f, 0.f, 0.f};

  const unsigned short* bph = zfh + (size_t)nt0 * 512 + lane * 8;
  const unsigned short* bpl = zfl + (size_t)nt0 * 512 + lane * 8;
  constexpr size_t BSTEP = (size_t)NT * 512;

#define LOADB(BH, BL, KS)                                             \
  do {                                                                \
    const unsigned short* ph_ = bph + (size_t)(KS)*BSTEP;             \
    const unsigned short* pl_ = bpl + (size_t)(KS)*BSTEP;             \
    _Pragma("unroll") for (int j_ = 0; j_ < NTW; ++j_) {              \
      BH[j_] = *(const uint4*)(ph_ + j_ * 512);                       \
      BL[j_] = *(const uint4*)(pl_ + j_ * 512);                       \
    }                                                                 \
  } while (0)

#define STEPK(KS, BH, BL)                                             \
  do {                                                                \
    const int kbase_ = (KS)*32 + lg * 8;                              \
    const int tap_ = kbase_ >> CSH;                                   \
    const int c0_ = kbase_ & (CPAD - 1);                              \
    short8 ahi_ = {}, alo_ = {};                                      \
    bool valid_ = true;                                               \
    if constexpr (TAPS != KK) valid_ = (tap_ < KK);                   \
    if (valid_) {                                                     \
      const int iy_ = tap_ / K, ix_ = tap_ - (tap_ / K) * K;          \
      const int lofs_ = ((py + iy_) * SX + (px + ix_)) * RWU + c0_;   \
      ahi_ = *(const short8*)(winh + lofs_);                          \
      alo_ = *(const short8*)(winl + lofs_);                          \
    }                                                                 \
    _Pragma("unroll") for (int j_ = 0; j_ < NTW; ++j_) {              \
      short8 bhv_ = __builtin_bit_cast(short8, BH[j_]);               \
      short8 blv_ = __builtin_bit_cast(short8, BL[j_]);               \
      acc[j_] = __builtin_amdgcn_mfma_f32_16x16x32_bf16(ahi_, bhv_,   \
                                                        acc[j_], 0, 0, 0); \
      acc[j_] = __builtin_amdgcn_mfma_f32_16x16x32_bf16(ahi_, blv_,   \
                                                        acc[j_], 0, 0, 0); \
      acc[j_] = __builtin_amdgcn_mfma_f32_16x16x32_bf16(alo_, bhv_,   \
                                                        acc[j_], 0, 0, 0); \
    }                                                                 \
  } while (0)

  {
    uint4 BhA[NTW], BlA[NTW], BhB[NTW], BlB[NTW];
    LOADB(BhA, BlA, 0);
    int ks = 0;
    for (;;) {
      if (ks + 1 < NK) LOADB(BhB, BlB, ks + 1);
      STEPK(ks, BhA, BlA);
      if (++ks == NK) break;
      if (ks + 1 < NK) LOADB(BhA, BlA, ks + 1);
      STEPK(ks, BhB, BlB);
      if (++ks == NK) break;
    }
  }
#undef LOADB
#undef STEPK

  // epilogue: D row = wm*16 + lg*4 + reg, col = (nt0+j)*16 + lm
  float ls[4] = {0.f, 0.f, 0.f, 0.f};
  float gR[4], rcpom[4], onePc[4];
#pragma unroll
  for (int reg = 0; reg < 4; ++reg) {
    int rr = wm * 16 + lg * 4 + reg;
    float cx2 = cA[rr];
    gR[reg] = gA[rr];
    rcpom[reg] = frcp(fmaxf(1.f - cx2, EPSF));
    onePc[reg] = 1.f + cx2;
  }
#pragma unroll
  for (int j = 0; j < NTW; ++j) {
    int o = (nt0 + j) * 16 + lm;
    float c1 = c1b[o], sh = shb[o], z2 = z2b[o];
#pragma unroll
    for (int reg = 0; reg < 4; ++reg) {
      float num = c1 * (gR[reg] * acc[j][reg]) - onePc[reg] * sh;
      float yv = sinh_zasinh(num * rcpom[reg], z2);
      acc[j][reg] = yv;
      ls[reg] += yv * yv;
    }
  }
#pragma unroll
  for (int mask = 1; mask < 16; mask <<= 1)
#pragma unroll
    for (int reg = 0; reg < 4; ++reg)
      ls[reg] += __shfl_xor(ls[reg], mask);

  if constexpr (WN > 1) {
    if (lm == 0) {
#pragma unroll
      for (int reg = 0; reg < 4; ++reg)
        redw[wn * MT + wm * 16 + lg * 4 + reg] = ls[reg];
    }
  }
  __syncthreads();  // redw visible; all waves done reading win planes
  if constexpr (WN > 1) {
#pragma unroll
    for (int reg = 0; reg < 4; ++reg) {
      float s = 0.f;
#pragma unroll
      for (int k2 = 0; k2 < WN; ++k2)
        s += redw[k2 * MT + wm * 16 + lg * 4 + reg];
      ls[reg] = s;
    }
  }
  float fs[4];
#pragma unroll
  for (int reg = 0; reg < 4; ++reg) {
    float inv = frcp(1.f + sqrtf(1.f + ls[reg]));
    float ny = sqrtf(fmaxf(ls[reg] * inv * inv, EPSF));
    fs[reg] = atanh_over(ny) * inv;
  }
  float* tr = (float*)winbuf;  // [COUT][TRS] overlay
#pragma unroll
  for (int j = 0; j < NTW; ++j) {
    int o = (nt0 + j) * 16 + lm;
#pragma unroll
    for (int reg = 0; reg < 4; ++reg) {
      int rr = wm * 16 + lg * 4 + reg;
      tr[o * TRS + rr] = fs[reg] * fmaxf(acc[j][reg], 0.f);
    }
  }
  __syncthreads();

  // fused 2x2 maxpool (tangent space) + per-pooled-pixel s2/f maps
  const int y0p = y0 >> 1, x0p = x0 >> 1;
  if (tid < NPP * CG) {
    int cg = tid / NPP, p = tid - cg * NPP;
    int ppy = p / PW, ppx = p - ppy * PW;
    const float* base = tr + (ppy * 2) * TW + ppx * 2;
    float ss = 0.f;
#pragma unroll
    for (int j = 0; j < CPG; ++j) {
      int c = cg * CPG + j;
      const float* rp = base + c * TRS;
      float mv = fmaxf(fmaxf(rp[0], rp[1]), fmaxf(rp[TW], rp[TW + 1]));
      mout[((size_t)(b * COUT + c) * HO + y0p + ppy) * WO + x0p + ppx] = mv;
      ss += mv * mv;
    }
    pacc[cg * NPP + p] = ss;
  }
  __syncthreads();
  if (tid < NPP) {
    float ss = 0.f;
    for (int k2 = 0; k2 < CG; ++k2) ss += pacc[k2 * NPP + tid];
    int ppy = tid / PW, ppx = tid - (tid / PW) * PW;
    size_t pix = ((size_t)b * HO + y0p + ppy) * WO + x0p + ppx;
    s2out[pix] = ss;
    float n = sqrtf(fmaxf(ss, EPSF));
    fout[pix] = tanh_over(n);
  }
}

// ---------------- Poincare FC over rows (head; libm precision) --------------
template <int NIN, int NOUT, int BLOCK>
__global__ __launch_bounds__(256) void pfc_kernel(
    const float* __restrict__ x, const float* __restrict__ z,
    const float* __restrict__ r, const float* __restrict__ zn,
    float* __restrict__ out) {
  const int b = blockIdx.x, tid = threadIdx.x;
  __shared__ float xs[NIN];
  __shared__ float red[BLOCK];
  for (int i = tid; i < NIN; i += BLOCK) xs[i] = x[(size_t)b * NIN + i];
  __syncthreads();
  float s = 0.f;
  for (int i = tid; i < NIN; i += BLOCK) { float v = xs[i]; s += v * v; }
  red[tid] = s; __syncthreads();
  for (int st = BLOCK / 2; st > 0; st >>= 1) {
    if (tid < st) red[tid] += red[tid + st];
    __syncthreads();
  }
  const float cx2 = red[0];
  __syncthreads();
  constexpr int CPT = (NOUT + BLOCK - 1) / BLOCK;
  const float onemc = fmaxf(1.f - cx2, EPSF);
  float yv[CPT];
  float ls = 0.f;
#pragma unroll
  for (int j = 0; j < CPT; ++j) {
    int o = tid + j * BLOCK;
    float y = 0.f;
    if (o < NOUT) {
      float d = 0.f;
      for (int k = 0; k < NIN; ++k) d = fmaf(xs[k], z[(size_t)k * NOUT + o], d);
      float znv = zn[o];
      float rv = r[o];
      float num = 2.f * (d / znv) * coshf(2.f * rv) - (1.f + cx2) * sinhf(2.f * rv);
      float mlr = 2.f * znv * asinhf(num / onemc);
      y = sinhf(mlr);
    }
    yv[j] = y; ls += y * y;
  }
  red[tid] = ls; __syncthreads();
  for (int st = BLOCK / 2; st > 0; st >>= 1) {
    if (tid < st) red[tid] += red[tid + st];
    __syncthreads();
  }
  const float denom = 1.f + sqrtf(1.f + red[0]);
#pragma unroll
  for (int j = 0; j < CPT; ++j) {
    int o = tid + j * BLOCK;
    if (o < NOUT) out[(size_t)b * NOUT + o] = yv[j] / denom;
  }
}

// ---------------- hrelu over rows (axis=-1) ---------------------------------
template <int N, int BLOCK>
__global__ __launch_bounds__(256) void hrelu_rows_kernel(
    const float* __restrict__ in, float* __restrict__ out) {
  const int b = blockIdx.x, tid = threadIdx.x;
  __shared__ float red[BLOCK];
  constexpr int CPT = N / BLOCK;
  float v[CPT];
  float s = 0.f;
#pragma unroll
  for (int j = 0; j < CPT; ++j) {
    v[j] = in[(size_t)b * N + tid + j * BLOCK];
    s += v[j] * v[j];
  }
  red[tid] = s; __syncthreads();
  for (int st = BLOCK / 2; st > 0; st >>= 1) {
    if (tid < st) red[tid] += red[tid + st];
    __syncthreads();
  }
  float n = sqrtf(fmaxf(red[0], EPSF));
  float f = atanhf(fminf(n, ATANH_CAP)) / n;
  __syncthreads();
  float s2 = 0.f;
#pragma unroll
  for (int j = 0; j < CPT; ++j) { v[j] = f * fmaxf(v[j], 0.f); s2 += v[j] * v[j]; }
  red[tid] = s2; __syncthreads();
  for (int st = BLOCK / 2; st > 0; st >>= 1) {
    if (tid < st) red[tid] += red[tid + st];
    __syncthreads();
  }
  float nt = sqrtf(fmaxf(red[0], EPSF));
  float gg = tanhf(nt) / nt;
#pragma unroll
  for (int j = 0; j < CPT; ++j)
    out[(size_t)b * N + tid + j * BLOCK] = gg * v[j];
}

// ---------------------------------------------------------------------------
static inline double beta_fn(double a, double b) {
  return std::exp(std::lgamma(a) + std::lgamma(b) - std::lgamma(a + b));
}

extern "C" void kernel_launch(void* const* d_in, const int* in_sizes, int n_in,
                              void* d_out, int out_size, void* d_ws, size_t ws_size,
                              hipStream_t stream) {
  const float* x   = (const float*)d_in[0];
  const float* z1  = (const float*)d_in[1];
  const float* b1  = (const float*)d_in[2];
  const float* z2  = (const float*)d_in[3];
  const float* b2  = (const float*)d_in[4];
  const float* z3  = (const float*)d_in[5];
  const float* b3  = (const float*)d_in[6];
  const float* z4  = (const float*)d_in[7];
  const float* b4  = (const float*)d_in[8];
  const float* zf1 = (const float*)d_in[9];
  const float* bf1 = (const float*)d_in[10];
  const float* zf2 = (const float*)d_in[11];
  const float* bf2 = (const float*)d_in[12];
  float* outp = (float*)d_out;

  float* ws    = (float*)d_ws;
  float* zn    = ws;                        // 2048
  float* flat  = ws + 2048;                 // 5632
  float* h1r   = ws + 7680;                 // 8192
  float* h1    = ws + 15872;                // 8704
  float* vm0   = ws + 24576;                // 786,432 (logmap'd input)
  float* mA    = vm0 + 786432;              // 2,097,152 (m1 / m3)
  float* mB    = mA + 2097152;              // 1,048,576 (m2 / m4)
  float* s2a   = mB + 1048576;              // 262,144 (s0 / s2 / s4)
  float* s2b   = s2a + 262144;              // 65,536 (s1 / s3)
  float* fA    = s2b + 65536;               // 65,536 (f1 / f3)
  float* fB    = fA + 65536;                // 16,384 (f2 / f4)
  float* part  = fB + 16384;                // 32,768 (16 x 2048 partials)
  unsigned short* zfu = (unsigned short*)(part + 32768);
  unsigned short* zf1h = zfu;               //   3,072 (96*32)
  unsigned short* zf1l = zfu + 3072;
  unsigned short* zf2h = zfu + 6144;        //  51,200
  unsigned short* zf2l = zfu + 57344;
  unsigned short* zf3h = zfu + 108544;      // 401,408
  unsigned short* zf3l = zfu + 509952;
  unsigned short* zf4h = zfu + 911360;      // 147,456
  unsigned short* zf4l = zfu + 1058816;     // ends 1,206,272 ushorts

  const float s1  = (float)(beta_fn(27.0 / 2.0, 0.5) / beta_fn(3.0 / 2.0, 0.5));
  const float s2c = (float)(beta_fn(800.0 / 2.0, 0.5) / beta_fn(32.0 / 2.0, 0.5));
  const float s3  = (float)(beta_fn(3136.0 / 2.0, 0.5) / beta_fn(64.0 / 2.0, 0.5));
  const float s4  = (float)(beta_fn(1152.0 / 2.0, 0.5) / beta_fn(128.0 / 2.0, 0.5));

  auto g1 = [](int n) { return dim3((n + 255) / 256); };

  // prep: column norms (two-stage) + fragment-ordered z
  znorm_part_kernel<<<dim3(1, 16),  256, 0, stream>>>(z1, part, 27, 32, 0);
  znorm_part_kernel<<<dim3(1, 16),  256, 0, stream>>>(z2, part, 800, 64, 32);
  znorm_part_kernel<<<dim3(2, 16),  256, 0, stream>>>(z3, part, 3136, 128, 96);
  znorm_part_kernel<<<dim3(2, 16),  256, 0, stream>>>(z4, part, 1152, 128, 224);
  znorm_part_kernel<<<dim3(8, 16),  256, 0, stream>>>(zf1, part, 352, 512, 352);
  znorm_part_kernel<<<dim3(16, 16), 256, 0, stream>>>(zf2, part, 512, 1000, 864);
  znorm_fin_kernel<<<8, 256, 0, stream>>>(part, zn);
  zfprep_kernel<3, 3, 12, 9, 32><<<12, 256, 0, stream>>>(z1, zf1h, zf1l);
  zfprep_kernel<32, 5, 25, 25, 64><<<200, 256, 0, stream>>>(z2, zf2h, zf2l);
  zfprep_kernel<64, 6, 49, 49, 128><<<1568, 256, 0, stream>>>(z3, zf3h, zf3l);
  zfprep_kernel<128, 7, 9, 9, 128><<<576, 256, 0, stream>>>(z4, zf4h, zf4l);

  // ---- layer 1: (16,3,128,128) -> m1 (16,32,64,64)
  logmap_s2_kernel<<<g1(262144), 256, 0, stream>>>(x, vm0, s2a, 3, 16384, 262144);
  hconv_mfma<3, 3, 12, 3, 1, 32, 128, 128, 8, 8, 4, 1>
      <<<4096, 256, 0, stream>>>(vm0, s2a, zf1h, zf1l, b1, zn + 0, mA, s2b, fA, s1);
  wavgpool_kernel<<<dim3(32, 16), 256, 0, stream>>>(mA, fA, flat, 32, 4096, 352, 0);

  // ---- layer 2: m1 -> m2 (16,64,32,32)  [16 waves]
  hconv_mfma<32, 5, 25, 5, 2, 64, 64, 64, 8, 8, 4, 4>
      <<<1024, 1024, 0, stream>>>(mA, s2b, zf2h, zf2l, b2, zn + 32, mB, s2a, fB, s2c);
  wavgpool_kernel<<<dim3(64, 16), 256, 0, stream>>>(mB, fB, flat, 64, 1024, 352, 32);

  // ---- layer 3: m2 -> m3 (16,128,16,16)  [16 waves]
  hconv_mfma<64, 6, 49, 7, 3, 128, 32, 32, 4, 8, 2, 8>
      <<<512, 1024, 0, stream>>>(mB, s2a, zf3h, zf3l, b3, zn + 96, mA, s2b, fA, s3);
  wavgpool_kernel<<<dim3(128, 16), 256, 0, stream>>>(mA, fA, flat, 128, 256, 352, 96);

  // ---- layer 4: m3 -> m4 (16,128,8,8)
  hconv_mfma<128, 7, 9, 3, 1, 128, 16, 16, 2, 8, 1, 8>
      <<<256, 512, 0, stream>>>(mA, s2b, zf4h, zf4l, b4, zn + 224, mB, s2a, fB, s4);
  wavgpool_kernel<<<dim3(128, 16), 256, 0, stream>>>(mB, fB, flat, 128, 64, 352, 224);

  // ---- head: flat (16,352) -> (16,512) -> hrelu -> (16,1000)
  pfc_kernel<352, 512, 256><<<16, 256, 0, stream>>>(flat, zf1, bf1, zn + 352, h1r);
  hrelu_rows_kernel<512, 256><<<16, 256, 0, stream>>>(h1r, h1);
  pfc_kernel<512, 1000, 256><<<16, 256, 0, stream>>>(h1, zf2, bf2, zn + 864, outp);

  (void)in_sizes; (void)n_in; (void)out_size; (void)ws_size;
}

// Round 8
// 292.433 us; speedup vs baseline: 10.5206x; 1.0365x over previous
//
#include <hip/hip_runtime.h>
#include <cmath>

// ---------------------------------------------------------------------------
// Hyperbolic MS-CNN (Poincare ball, c=1) — round 8.
//  * MFMA convs (split bf16 hi/lo, 3 MFMAs) + fused epilogue (MLR -> sinh ->
//    projection -> relu-tangent -> maxpool -> s2/f maps).
//  * MREP: each wave applies one B-register-load to MREP A-fragments
//    (4x fewer B reads from L2 -- the round-7 bottleneck).
//  * B-fragment double-buffer prefetch; vectorized LDS staging.
// ---------------------------------------------------------------------------

#define EPSF 1e-15f
#define ATANH_CAP 0.9999999f  // 1 - 1e-7

typedef __attribute__((ext_vector_type(8))) short short8;
typedef __attribute__((ext_vector_type(4))) float f32x4;

__device__ inline unsigned rne16(float f) {
  unsigned u = __float_as_uint(f);
  return (u + 0x7FFFu + ((u >> 16) & 1u)) >> 16;
}
__device__ inline float fexp2(float x) { return __builtin_amdgcn_exp2f(x); }
__device__ inline float flog2(float x) { return __builtin_amdgcn_logf(x); }
__device__ inline float frcp(float x) { return __builtin_amdgcn_rcpf(x); }

__device__ inline float atanh_over(float n) {
  float nc = fminf(n, ATANH_CAP);
  float f = 0.34657359f * flog2((1.f + nc) * frcp(1.f - nc)) * frcp(n);
  float s = 1.f + 0.33333333f * n * n;
  return (n < 0.004f) ? s : f;
}
__device__ inline float tanh_over(float n) {
  float p2 = fexp2(2.885390082f * n);  // e^{2n}
  float f = (1.f - 2.f * frcp(p2 + 1.f)) * frcp(n);
  float s = 1.f - 0.33333333f * n * n;
  return (n < 0.004f) ? s : f;
}
__device__ inline float sinh_zasinh(float q, float twozn) {
  float aq = fabsf(q);
  float t = aq + sqrtf(fmaf(aq, aq, 1.f));
  float p = fexp2(twozn * flog2(t));
  float y = 0.5f * (p - frcp(p));
  return copysignf(y, q);
}

// ---------------- z column norms, two-stage ---------------------------------
__global__ __launch_bounds__(256) void znorm_part_kernel(
    const float* __restrict__ z, float* __restrict__ part,
    int K, int Nout, int coff) {
  const int tid = threadIdx.x;
  const int col = blockIdx.x * 64 + (tid & 63);
  const int kg = (blockIdx.y << 2) + (tid >> 6);
  float s = 0.f;
  if (col < Nout)
    for (int k = kg; k < K; k += 64) {
      float v = z[(size_t)k * Nout + col];
      s += v * v;
    }
  __shared__ float red[256];
  red[tid] = s;
  __syncthreads();
  if (tid < 64 && col < Nout) {
    float t = red[tid] + red[tid + 64] + red[tid + 128] + red[tid + 192];
    part[(size_t)blockIdx.y * 2048 + coff + col] = t;
  }
}
__global__ __launch_bounds__(256) void znorm_fin_kernel(
    const float* __restrict__ part, float* __restrict__ zn) {
  int c = blockIdx.x * 256 + threadIdx.x;
  float s = 0.f;
#pragma unroll
  for (int rr = 0; rr < 16; ++rr) s += part[rr * 2048 + c];
  zn[c] = sqrtf(fmaxf(s, EPSF));
}

// ---------------- z -> MFMA-fragment-ordered hi/lo bf16 ---------------------
template <int CIN, int CSH, int TAPS, int KK, int COUT>
__global__ __launch_bounds__(256) void zfprep_kernel(
    const float* __restrict__ z, unsigned short* __restrict__ zh,
    unsigned short* __restrict__ zl) {
  constexpr int CPAD = 1 << CSH;
  constexpr int KP = TAPS * CPAD;
  constexpr int NT = COUT / 16;
  int t = blockIdx.x * 256 + threadIdx.x;
  if (t >= KP * COUT) return;
  int k = t / COUT, n = t - k * COUT;
  int ks = k >> 5, lg = (k >> 3) & 3, i = k & 7;
  int nt = n >> 4, lm = n & 15;
  size_t e = ((size_t)(ks * NT + nt) * 64 + lg * 16 + lm) * 8 + i;
  int tap = k >> CSH, c = k & (CPAD - 1);
  float val = (c < CIN && tap < KK) ? z[(size_t)(c * KK + tap) * COUT + n] : 0.f;
  unsigned hi = rne16(val);
  float hif = __uint_as_float(hi << 16);
  unsigned lo = rne16(val - hif);
  zh[e] = (unsigned short)hi;
  zl[e] = (unsigned short)lo;
}

// ---------------- logmap0 + per-pixel sum of squares ------------------------
__global__ __launch_bounds__(256) void logmap_s2_kernel(
    const float* __restrict__ in, float* __restrict__ out,
    float* __restrict__ s2, int C, int HW, int total) {
  int i = blockIdx.x * blockDim.x + threadIdx.x;
  if (i >= total) return;
  int b = i / HW, s = i - b * HW;
  const float* p = in + (size_t)b * C * HW + s;
  float ss = 0.f;
  for (int c = 0; c < C; ++c) { float v = p[(size_t)c * HW]; ss += v * v; }
  float n = sqrtf(fmaxf(ss, EPSF));
  float f = atanh_over(n);
  float* q = out + (size_t)b * C * HW + s;
  for (int c = 0; c < C; ++c) q[(size_t)c * HW] = f * p[(size_t)c * HW];
  s2[i] = f * f * ss;
}

// ---------------- weighted spatial mean -------------------------------------
__global__ __launch_bounds__(256) void wavgpool_kernel(
    const float* __restrict__ vm, const float* __restrict__ f,
    float* __restrict__ flat, int C, int HW, int flatC, int coff) {
  int c = blockIdx.x, b = blockIdx.y, tid = threadIdx.x;
  const float* p = vm + ((size_t)b * C + c) * HW;
  const float* q = f + (size_t)b * HW;
  float s = 0.f;
  for (int i = tid; i < HW; i += blockDim.x) s += p[i] * q[i];
  __shared__ float red[256];
  red[tid] = s; __syncthreads();
  for (int st = 128; st > 0; st >>= 1) {
    if (tid < st) red[tid] += red[tid + st];
    __syncthreads();
  }
  if (tid == 0) flat[(size_t)b * flatC + coff + c] = red[0] / (float)HW;
}

// ---------------- MFMA fused hconv + hrelu-tangent + maxpool + maps ---------
// Wave layout: WM wave-groups in M, each wave covers MREP*16 rows; WN in N.
template <int CIN, int CSH, int TAPS, int K, int PAD, int COUT, int H, int W,
          int TH, int TW, int WM, int MREP, int WN>
__global__ __launch_bounds__(WM * WN * 64) void hconv_mfma(
    const float* __restrict__ vin, const float* __restrict__ s2map,
    const unsigned short* __restrict__ zfh,
    const unsigned short* __restrict__ zfl,
    const float* __restrict__ r, const float* __restrict__ zn,
    float* __restrict__ mout, float* __restrict__ s2out,
    float* __restrict__ fout, float scale) {
  constexpr int NTHR = WM * WN * 64;
  constexpr int CPAD = 1 << CSH;
  constexpr int KK = K * K;
  constexpr int MT = WM * MREP * 16;
  static_assert(MT == TH * TW, "tile rows mismatch");
  constexpr int NT = COUT / 16;
  constexpr int NTW = NT / WN;
  static_assert(NTW * WN == NT, "");
  constexpr int NK = TAPS * CPAD / 32;
  static_assert(NK * 32 == TAPS * CPAD, "K-step misalign");
  constexpr int SY = TH + K - 1, SX = TW + K - 1;
  constexpr int NPOS = SY * SX;
  constexpr int RWU = (CPAD >= 32) ? (CPAD + 8) : CPAD;  // 16B-aligned rows
  constexpr int CGR = CPAD / 8;  // 8-ushort granules per row
  constexpr int TRS = MT + 4;
  constexpr int WINU = NPOS * RWU;
  constexpr int TRU = 2 * COUT * TRS;
  constexpr int SHU = (2 * WINU > TRU) ? 2 * WINU : TRU;
  constexpr int HO = H / 2, WO = W / 2;
  constexpr int PH = TH / 2, PW = TW / 2, NPP = PH * PW;
  constexpr int CG0 = NTHR / NPP;
  constexpr int CG = (CG0 < COUT) ? CG0 : COUT;
  constexpr int CPG = COUT / CG;
  static_assert(CPG * CG == COUT, "pool split");

  __shared__ __align__(16) unsigned short winbuf[SHU];
  __shared__ float s2w[NPOS];
  __shared__ float gA[MT], cA[MT];
  __shared__ float c1b[COUT], shb[COUT], z2b[COUT];
  __shared__ float redw[(WN > 1) ? WN * MT : 1];
  __shared__ float pacc[NTHR];
  unsigned short* winh = winbuf;
  unsigned short* winl = winbuf + WINU;

  const int tid = threadIdx.x;
  int bid = blockIdx.x;
  constexpr int TXC = W / TW, TYC = H / TH;
  const int tx = bid % TXC; bid /= TXC;
  const int ty = bid % TYC; const int b = bid / TYC;
  const int y0 = ty * TH, x0 = tx * TW;

  if (tid < COUT) {
    float rv = r[tid];
    float znv = zn[tid];
    float ch = coshf(2.f * rv), sh = sinhf(2.f * rv);
    c1b[tid] = 2.f * ch / znv;
    shb[tid] = sh;
    z2b[tid] = 2.f * znv;
  }
  // staging: pos-minor granules; one ds_write_b128 per plane per (pos,cg)
  const float* vb = vin + (size_t)b * CIN * H * W;
  for (int idx = tid; idx < CGR * NPOS; idx += NTHR) {
    int pos = idx / CGR;
    int cg = idx - pos * CGR;
    int sy = pos / SX, sx = pos - sy * SX;
    int gy = y0 + sy - PAD, gx = x0 + sx - PAD;
    bool inb = (gy >= 0 && gy < H && gx >= 0 && gx < W);
    const float* gp = vb + (size_t)(cg * 8) * H * W + gy * W + gx;
    short8 hv, lv;
#pragma unroll
    for (int j = 0; j < 8; ++j) {
      float val = 0.f;
      if constexpr (CIN == CPAD) {
        if (inb) val = gp[(size_t)j * H * W];
      } else {
        if (inb && (cg * 8 + j) < CIN) val = gp[(size_t)j * H * W];
      }
      unsigned hi = rne16(val);
      float hif = __uint_as_float(hi << 16);
      unsigned lo = rne16(val - hif);
      hv[j] = (short)hi;
      lv[j] = (short)lo;
    }
    *(short8*)(winh + pos * RWU + cg * 8) = hv;
    *(short8*)(winl + pos * RWU + cg * 8) = lv;
  }
  const float* s2bp = s2map + (size_t)b * H * W;
  for (int i = tid; i < NPOS; i += NTHR) {
    int sy = i / SX, sx = i - sy * SX;
    int gy = y0 + sy - PAD, gx = x0 + sx - PAD;
    s2w[i] = (gy >= 0 && gy < H && gx >= 0 && gx < W) ? s2bp[gy * W + gx] : 0.f;
  }
  __syncthreads();

  if (tid < MT) {
    int py = tid / TW, px = tid - (tid / TW) * TW;
    float s = 0.f;
    for (int iy = 0; iy < K; ++iy)
      for (int ix = 0; ix < K; ++ix)
        s += s2w[(py + iy) * SX + (px + ix)];
    float n = sqrtf(fmaxf(scale * scale * s, EPSF));
    float th = n * tanh_over(n);
    gA[tid] = th * scale * frcp(n);
    cA[tid] = th * th;
  }
  __syncthreads();

  const int w = __builtin_amdgcn_readfirstlane(tid >> 6);
  const int wm = w % WM, wn = w / WM;
  const int lane = tid & 63, lm = lane & 15, lg = lane >> 4;
  const int nt0 = wn * NTW;

  // per-rep A row coordinates
  int pyr[MREP], pxr[MREP];
#pragma unroll
  for (int rep = 0; rep < MREP; ++rep) {
    int m = (wm * MREP + rep) * 16 + lm;
    pyr[rep] = m / TW;
    pxr[rep] = m - (m / TW) * TW;
  }

  f32x4 acc[MREP][NTW];
#pragma unroll
  for (int rep = 0; rep < MREP; ++rep)
#pragma unroll
    for (int j = 0; j < NTW; ++j) acc[rep][j] = (f32x4){0.f, 0.f, 0.f, 0.f};

  const unsigned short* bph = zfh + (size_t)nt0 * 512 + lane * 8;
  const unsigned short* bpl = zfl + (size_t)nt0 * 512 + lane * 8;
  constexpr size_t BSTEP = (size_t)NT * 512;

#define LOADB(BH, BL, KS)                                             \
  do {                                                                \
    const unsigned short* ph_ = bph + (size_t)(KS)*BSTEP;             \
    const unsigned short* pl_ = bpl + (size_t)(KS)*BSTEP;             \
    _Pragma("unroll") for (int j_ = 0; j_ < NTW; ++j_) {              \
      BH[j_] = *(const uint4*)(ph_ + j_ * 512);                       \
      BL[j_] = *(const uint4*)(pl_ + j_ * 512);                       \
    }                                                                 \
  } while (0)

#define STEPK(KS, BH, BL)                                             \
  do {                                                                \
    const int kbase_ = (KS)*32 + lg * 8;                              \
    const int tap_ = kbase_ >> CSH;                                   \
    const int c0_ = kbase_ & (CPAD - 1);                              \
    bool valid_ = true;                                               \
    if constexpr (TAPS != KK) valid_ = (tap_ < KK);                   \
    const int iy_ = tap_ / K, ix_ = tap_ - (tap_ / K) * K;            \
    _Pragma("unroll") for (int rep_ = 0; rep_ < MREP; ++rep_) {       \
      short8 ahi_ = {}, alo_ = {};                                    \
      if (valid_) {                                                   \
        const int lofs_ =                                             \
            ((pyr[rep_] + iy_) * SX + (pxr[rep_] + ix_)) * RWU + c0_; \
        ahi_ = *(const short8*)(winh + lofs_);                        \
        alo_ = *(const short8*)(winl + lofs_);                        \
      }                                                               \
      _Pragma("unroll") for (int j_ = 0; j_ < NTW; ++j_) {            \
        short8 bhv_ = __builtin_bit_cast(short8, BH[j_]);             \
        short8 blv_ = __builtin_bit_cast(short8, BL[j_]);             \
        acc[rep_][j_] = __builtin_amdgcn_mfma_f32_16x16x32_bf16(      \
            ahi_, bhv_, acc[rep_][j_], 0, 0, 0);                      \
        acc[rep_][j_] = __builtin_amdgcn_mfma_f32_16x16x32_bf16(      \
            ahi_, blv_, acc[rep_][j_], 0, 0, 0);                      \
        acc[rep_][j_] = __builtin_amdgcn_mfma_f32_16x16x32_bf16(      \
            alo_, bhv_, acc[rep_][j_], 0, 0, 0);                      \
      }                                                               \
    }                                                                 \
  } while (0)

  {
    uint4 BhA[NTW], BlA[NTW], BhB[NTW], BlB[NTW];
    LOADB(BhA, BlA, 0);
    int ks = 0;
    for (;;) {
      if (ks + 1 < NK) LOADB(BhB, BlB, ks + 1);
      STEPK(ks, BhA, BlA);
      if (++ks == NK) break;
      if (ks + 1 < NK) LOADB(BhA, BlA, ks + 1);
      STEPK(ks, BhB, BlB);
      if (++ks == NK) break;
    }
  }
#undef LOADB
#undef STEPK

  // ---- epilogue pass 1: MLR transform + row sums of y^2
  float lsA[MREP][4];
#pragma unroll
  for (int rep = 0; rep < MREP; ++rep) {
    const int rbase = (wm * MREP + rep) * 16 + lg * 4;
    float ls[4] = {0.f, 0.f, 0.f, 0.f};
    float gR[4], rcpom[4], onePc[4];
#pragma unroll
    for (int reg = 0; reg < 4; ++reg) {
      float cx2 = cA[rbase + reg];
      gR[reg] = gA[rbase + reg];
      rcpom[reg] = frcp(fmaxf(1.f - cx2, EPSF));
      onePc[reg] = 1.f + cx2;
    }
#pragma unroll
    for (int j = 0; j < NTW; ++j) {
      int o = (nt0 + j) * 16 + lm;
      float c1 = c1b[o], sh = shb[o], z2 = z2b[o];
#pragma unroll
      for (int reg = 0; reg < 4; ++reg) {
        float num = c1 * (gR[reg] * acc[rep][j][reg]) - onePc[reg] * sh;
        float yv = sinh_zasinh(num * rcpom[reg], z2);
        acc[rep][j][reg] = yv;
        ls[reg] += yv * yv;
      }
    }
#pragma unroll
    for (int mask = 1; mask < 16; mask <<= 1)
#pragma unroll
      for (int reg = 0; reg < 4; ++reg)
        ls[reg] += __shfl_xor(ls[reg], mask);
#pragma unroll
    for (int reg = 0; reg < 4; ++reg) lsA[rep][reg] = ls[reg];
    if constexpr (WN > 1) {
      if (lm == 0) {
#pragma unroll
        for (int reg = 0; reg < 4; ++reg)
          redw[wn * MT + rbase + reg] = ls[reg];
      }
    }
  }
  __syncthreads();  // redw visible; all waves done reading win planes

  // ---- epilogue pass 2: projection + relu tangent -> tr overlay
  float* tr = (float*)winbuf;  // [COUT][TRS]
#pragma unroll
  for (int rep = 0; rep < MREP; ++rep) {
    const int rbase = (wm * MREP + rep) * 16 + lg * 4;
    float fs[4];
#pragma unroll
    for (int reg = 0; reg < 4; ++reg) {
      float s;
      if constexpr (WN > 1) {
        s = 0.f;
#pragma unroll
        for (int k2 = 0; k2 < WN; ++k2) s += redw[k2 * MT + rbase + reg];
      } else {
        s = lsA[rep][reg];
      }
      float inv = frcp(1.f + sqrtf(1.f + s));
      float ny = sqrtf(fmaxf(s * inv * inv, EPSF));
      fs[reg] = atanh_over(ny) * inv;
    }
#pragma unroll
    for (int j = 0; j < NTW; ++j) {
      int o = (nt0 + j) * 16 + lm;
#pragma unroll
      for (int reg = 0; reg < 4; ++reg)
        tr[o * TRS + rbase + reg] = fs[reg] * fmaxf(acc[rep][j][reg], 0.f);
    }
  }
  __syncthreads();

  // fused 2x2 maxpool (tangent space) + per-pooled-pixel s2/f maps
  const int y0p = y0 >> 1, x0p = x0 >> 1;
  if (tid < NPP * CG) {
    int cg = tid / NPP, p = tid - cg * NPP;
    int ppy = p / PW, ppx = p - ppy * PW;
    const float* base = tr + (ppy * 2) * TW + ppx * 2;
    float ss = 0.f;
#pragma unroll
    for (int j = 0; j < CPG; ++j) {
      int c = cg * CPG + j;
      const float* rp = base + c * TRS;
      float mv = fmaxf(fmaxf(rp[0], rp[1]), fmaxf(rp[TW], rp[TW + 1]));
      mout[((size_t)(b * COUT + c) * HO + y0p + ppy) * WO + x0p + ppx] = mv;
      ss += mv * mv;
    }
    pacc[cg * NPP + p] = ss;
  }
  __syncthreads();
  if (tid < NPP) {
    float ss = 0.f;
    for (int k2 = 0; k2 < CG; ++k2) ss += pacc[k2 * NPP + tid];
    int ppy = tid / PW, ppx = tid - (tid / PW) * PW;
    size_t pix = ((size_t)b * HO + y0p + ppy) * WO + x0p + ppx;
    s2out[pix] = ss;
    float n = sqrtf(fmaxf(ss, EPSF));
    fout[pix] = tanh_over(n);
  }
}

// ---------------- Poincare FC over rows (head; libm precision) --------------
template <int NIN, int NOUT, int BLOCK>
__global__ __launch_bounds__(256) void pfc_kernel(
    const float* __restrict__ x, const float* __restrict__ z,
    const float* __restrict__ r, const float* __restrict__ zn,
    float* __restrict__ out) {
  const int b = blockIdx.x, tid = threadIdx.x;
  __shared__ float xs[NIN];
  __shared__ float red[BLOCK];
  for (int i = tid; i < NIN; i += BLOCK) xs[i] = x[(size_t)b * NIN + i];
  __syncthreads();
  float s = 0.f;
  for (int i = tid; i < NIN; i += BLOCK) { float v = xs[i]; s += v * v; }
  red[tid] = s; __syncthreads();
  for (int st = BLOCK / 2; st > 0; st >>= 1) {
    if (tid < st) red[tid] += red[tid + st];
    __syncthreads();
  }
  const float cx2 = red[0];
  __syncthreads();
  constexpr int CPT = (NOUT + BLOCK - 1) / BLOCK;
  const float onemc = fmaxf(1.f - cx2, EPSF);
  float yv[CPT];
  float ls = 0.f;
#pragma unroll
  for (int j = 0; j < CPT; ++j) {
    int o = tid + j * BLOCK;
    float y = 0.f;
    if (o < NOUT) {
      float d = 0.f;
      for (int k = 0; k < NIN; ++k) d = fmaf(xs[k], z[(size_t)k * NOUT + o], d);
      float znv = zn[o];
      float rv = r[o];
      float num = 2.f * (d / znv) * coshf(2.f * rv) - (1.f + cx2) * sinhf(2.f * rv);
      float mlr = 2.f * znv * asinhf(num / onemc);
      y = sinhf(mlr);
    }
    yv[j] = y; ls += y * y;
  }
  red[tid] = ls; __syncthreads();
  for (int st = BLOCK / 2; st > 0; st >>= 1) {
    if (tid < st) red[tid] += red[tid + st];
    __syncthreads();
  }
  const float denom = 1.f + sqrtf(1.f + red[0]);
#pragma unroll
  for (int j = 0; j < CPT; ++j) {
    int o = tid + j * BLOCK;
    if (o < NOUT) out[(size_t)b * NOUT + o] = yv[j] / denom;
  }
}

// ---------------- hrelu over rows (axis=-1) ---------------------------------
template <int N, int BLOCK>
__global__ __launch_bounds__(256) void hrelu_rows_kernel(
    const float* __restrict__ in, float* __restrict__ out) {
  const int b = blockIdx.x, tid = threadIdx.x;
  __shared__ float red[BLOCK];
  constexpr int CPT = N / BLOCK;
  float v[CPT];
  float s = 0.f;
#pragma unroll
  for (int j = 0; j < CPT; ++j) {
    v[j] = in[(size_t)b * N + tid + j * BLOCK];
    s += v[j] * v[j];
  }
  red[tid] = s; __syncthreads();
  for (int st = BLOCK / 2; st > 0; st >>= 1) {
    if (tid < st) red[tid] += red[tid + st];
    __syncthreads();
  }
  float n = sqrtf(fmaxf(red[0], EPSF));
  float f = atanhf(fminf(n, ATANH_CAP)) / n;
  __syncthreads();
  float s2 = 0.f;
#pragma unroll
  for (int j = 0; j < CPT; ++j) { v[j] = f * fmaxf(v[j], 0.f); s2 += v[j] * v[j]; }
  red[tid] = s2; __syncthreads();
  for (int st = BLOCK / 2; st > 0; st >>= 1) {
    if (tid < st) red[tid] += red[tid + st];
    __syncthreads();
  }
  float nt = sqrtf(fmaxf(red[0], EPSF));
  float gg = tanhf(nt) / nt;
#pragma unroll
  for (int j = 0; j < CPT; ++j)
    out[(size_t)b * N + tid + j * BLOCK] = gg * v[j];
}

// ---------------------------------------------------------------------------
static inline double beta_fn(double a, double b) {
  return std::exp(std::lgamma(a) + std::lgamma(b) - std::lgamma(a + b));
}

extern "C" void kernel_launch(void* const* d_in, const int* in_sizes, int n_in,
                              void* d_out, int out_size, void* d_ws, size_t ws_size,
                              hipStream_t stream) {
  const float* x   = (const float*)d_in[0];
  const float* z1  = (const float*)d_in[1];
  const float* b1  = (const float*)d_in[2];
  const float* z2  = (const float*)d_in[3];
  const float* b2  = (const float*)d_in[4];
  const float* z3  = (const float*)d_in[5];
  const float* b3  = (const float*)d_in[6];
  const float* z4  = (const float*)d_in[7];
  const float* b4  = (const float*)d_in[8];
  const float* zf1 = (const float*)d_in[9];
  const float* bf1 = (const float*)d_in[10];
  const float* zf2 = (const float*)d_in[11];
  const float* bf2 = (const float*)d_in[12];
  float* outp = (float*)d_out;

  float* ws    = (float*)d_ws;
  float* zn    = ws;                        // 2048
  float* flat  = ws + 2048;                 // 5632
  float* h1r   = ws + 7680;                 // 8192
  float* h1    = ws + 15872;                // 8704
  float* vm0   = ws + 24576;                // 786,432 (logmap'd input)
  float* mA    = vm0 + 786432;              // 2,097,152 (m1 / m3)
  float* mB    = mA + 2097152;              // 1,048,576 (m2 / m4)
  float* s2a   = mB + 1048576;              // 262,144 (s0 / s2 / s4)
  float* s2b   = s2a + 262144;              // 65,536 (s1 / s3)
  float* fA    = s2b + 65536;               // 65,536 (f1 / f3)
  float* fB    = fA + 65536;                // 16,384 (f2 / f4)
  float* part  = fB + 16384;                // 32,768 (16 x 2048 partials)
  unsigned short* zfu = (unsigned short*)(part + 32768);
  unsigned short* zf1h = zfu;               //   3,072 (96*32)
  unsigned short* zf1l = zfu + 3072;
  unsigned short* zf2h = zfu + 6144;        //  51,200
  unsigned short* zf2l = zfu + 57344;
  unsigned short* zf3h = zfu + 108544;      // 401,408
  unsigned short* zf3l = zfu + 509952;
  unsigned short* zf4h = zfu + 911360;      // 147,456
  unsigned short* zf4l = zfu + 1058816;     // ends 1,206,272 ushorts

  const float s1  = (float)(beta_fn(27.0 / 2.0, 0.5) / beta_fn(3.0 / 2.0, 0.5));
  const float s2c = (float)(beta_fn(800.0 / 2.0, 0.5) / beta_fn(32.0 / 2.0, 0.5));
  const float s3  = (float)(beta_fn(3136.0 / 2.0, 0.5) / beta_fn(64.0 / 2.0, 0.5));
  const float s4  = (float)(beta_fn(1152.0 / 2.0, 0.5) / beta_fn(128.0 / 2.0, 0.5));

  auto g1 = [](int n) { return dim3((n + 255) / 256); };

  // prep: column norms (two-stage) + fragment-ordered z
  znorm_part_kernel<<<dim3(1, 16),  256, 0, stream>>>(z1, part, 27, 32, 0);
  znorm_part_kernel<<<dim3(1, 16),  256, 0, stream>>>(z2, part, 800, 64, 32);
  znorm_part_kernel<<<dim3(2, 16),  256, 0, stream>>>(z3, part, 3136, 128, 96);
  znorm_part_kernel<<<dim3(2, 16),  256, 0, stream>>>(z4, part, 1152, 128, 224);
  znorm_part_kernel<<<dim3(8, 16),  256, 0, stream>>>(zf1, part, 352, 512, 352);
  znorm_part_kernel<<<dim3(16, 16), 256, 0, stream>>>(zf2, part, 512, 1000, 864);
  znorm_fin_kernel<<<8, 256, 0, stream>>>(part, zn);
  zfprep_kernel<3, 3, 12, 9, 32><<<12, 256, 0, stream>>>(z1, zf1h, zf1l);
  zfprep_kernel<32, 5, 25, 25, 64><<<200, 256, 0, stream>>>(z2, zf2h, zf2l);
  zfprep_kernel<64, 6, 49, 49, 128><<<1568, 256, 0, stream>>>(z3, zf3h, zf3l);
  zfprep_kernel<128, 7, 9, 9, 128><<<576, 256, 0, stream>>>(z4, zf4h, zf4l);

  // ---- layer 1: (16,3,128,128) -> m1 (16,32,64,64)   [MT=64, MREP=1]
  logmap_s2_kernel<<<g1(262144), 256, 0, stream>>>(x, vm0, s2a, 3, 16384, 262144);
  hconv_mfma<3, 3, 12, 3, 1, 32, 128, 128, 8, 8, 4, 1, 1>
      <<<4096, 256, 0, stream>>>(vm0, s2a, zf1h, zf1l, b1, zn + 0, mA, s2b, fA, s1);
  wavgpool_kernel<<<dim3(32, 16), 256, 0, stream>>>(mA, fA, flat, 32, 4096, 352, 0);

  // ---- layer 2: m1 -> m2 (16,64,32,32)   [MT=64, MREP=4, 4 waves]
  hconv_mfma<32, 5, 25, 5, 2, 64, 64, 64, 8, 8, 1, 4, 4>
      <<<1024, 256, 0, stream>>>(mA, s2b, zf2h, zf2l, b2, zn + 32, mB, s2a, fB, s2c);
  wavgpool_kernel<<<dim3(64, 16), 256, 0, stream>>>(mB, fB, flat, 64, 1024, 352, 32);

  // ---- layer 3: m2 -> m3 (16,128,16,16)  [MT=64, MREP=4, 8 waves]
  hconv_mfma<64, 6, 49, 7, 3, 128, 32, 32, 8, 8, 1, 4, 8>
      <<<256, 512, 0, stream>>>(mB, s2a, zf3h, zf3l, b3, zn + 96, mA, s2b, fA, s3);
  wavgpool_kernel<<<dim3(128, 16), 256, 0, stream>>>(mA, fA, flat, 128, 256, 352, 96);

  // ---- layer 4: m3 -> m4 (16,128,8,8)    [MT=16, 8 waves]
  hconv_mfma<128, 7, 9, 3, 1, 128, 16, 16, 2, 8, 1, 1, 8>
      <<<256, 512, 0, stream>>>(mA, s2b, zf4h, zf4l, b4, zn + 224, mB, s2a, fB, s4);
  wavgpool_kernel<<<dim3(128, 16), 256, 0, stream>>>(mB, fB, flat, 128, 64, 352, 224);

  // ---- head: flat (16,352) -> (16,512) -> hrelu -> (16,1000)
  pfc_kernel<352, 512, 256><<<16, 256, 0, stream>>>(flat, zf1, bf1, zn + 352, h1r);
  hrelu_rows_kernel<512, 256><<<16, 256, 0, stream>>>(h1r, h1);
  pfc_kernel<512, 1000, 256><<<16, 256, 0, stream>>>(h1, zf2, bf2, zn + 864, outp);

  (void)in_sizes; (void)n_in; (void)out_size; (void)ws_size;
}

// Round 9
// 216.680 us; speedup vs baseline: 14.1987x; 1.3496x over previous
//
#include <hip/hip_runtime.h>
#include <cmath>

// ---------------------------------------------------------------------------
// Hyperbolic MS-CNN (Poincare ball, c=1) — round 9.
//  * MFMA convs (split bf16 hi/lo, 3 MFMAs) + fused epilogue + MREP.
//  * Head rewritten: parallel pfc_y (grid NOUT/64 x B) + tiny pfc_fin;
//    hrelu fused into FC1's finish kernel.
// ---------------------------------------------------------------------------

#define EPSF 1e-15f
#define ATANH_CAP 0.9999999f  // 1 - 1e-7

typedef __attribute__((ext_vector_type(8))) short short8;
typedef __attribute__((ext_vector_type(4))) float f32x4;

__device__ inline unsigned rne16(float f) {
  unsigned u = __float_as_uint(f);
  return (u + 0x7FFFu + ((u >> 16) & 1u)) >> 16;
}
__device__ inline float fexp2(float x) { return __builtin_amdgcn_exp2f(x); }
__device__ inline float flog2(float x) { return __builtin_amdgcn_logf(x); }
__device__ inline float frcp(float x) { return __builtin_amdgcn_rcpf(x); }

__device__ inline float atanh_over(float n) {
  float nc = fminf(n, ATANH_CAP);
  float f = 0.34657359f * flog2((1.f + nc) * frcp(1.f - nc)) * frcp(n);
  float s = 1.f + 0.33333333f * n * n;
  return (n < 0.004f) ? s : f;
}
__device__ inline float tanh_over(float n) {
  float p2 = fexp2(2.885390082f * n);  // e^{2n}
  float f = (1.f - 2.f * frcp(p2 + 1.f)) * frcp(n);
  float s = 1.f - 0.33333333f * n * n;
  return (n < 0.004f) ? s : f;
}
__device__ inline float sinh_zasinh(float q, float twozn) {
  float aq = fabsf(q);
  float t = aq + sqrtf(fmaf(aq, aq, 1.f));
  float p = fexp2(twozn * flog2(t));
  float y = 0.5f * (p - frcp(p));
  return copysignf(y, q);
}

// ---------------- z column norms, two-stage ---------------------------------
__global__ __launch_bounds__(256) void znorm_part_kernel(
    const float* __restrict__ z, float* __restrict__ part,
    int K, int Nout, int coff) {
  const int tid = threadIdx.x;
  const int col = blockIdx.x * 64 + (tid & 63);
  const int kg = (blockIdx.y << 2) + (tid >> 6);
  float s = 0.f;
  if (col < Nout)
    for (int k = kg; k < K; k += 64) {
      float v = z[(size_t)k * Nout + col];
      s += v * v;
    }
  __shared__ float red[256];
  red[tid] = s;
  __syncthreads();
  if (tid < 64 && col < Nout) {
    float t = red[tid] + red[tid + 64] + red[tid + 128] + red[tid + 192];
    part[(size_t)blockIdx.y * 2048 + coff + col] = t;
  }
}
__global__ __launch_bounds__(256) void znorm_fin_kernel(
    const float* __restrict__ part, float* __restrict__ zn) {
  int c = blockIdx.x * 256 + threadIdx.x;
  float s = 0.f;
#pragma unroll
  for (int rr = 0; rr < 16; ++rr) s += part[rr * 2048 + c];
  zn[c] = sqrtf(fmaxf(s, EPSF));
}

// ---------------- z -> MFMA-fragment-ordered hi/lo bf16 ---------------------
template <int CIN, int CSH, int TAPS, int KK, int COUT>
__global__ __launch_bounds__(256) void zfprep_kernel(
    const float* __restrict__ z, unsigned short* __restrict__ zh,
    unsigned short* __restrict__ zl) {
  constexpr int CPAD = 1 << CSH;
  constexpr int KP = TAPS * CPAD;
  constexpr int NT = COUT / 16;
  int t = blockIdx.x * 256 + threadIdx.x;
  if (t >= KP * COUT) return;
  int k = t / COUT, n = t - k * COUT;
  int ks = k >> 5, lg = (k >> 3) & 3, i = k & 7;
  int nt = n >> 4, lm = n & 15;
  size_t e = ((size_t)(ks * NT + nt) * 64 + lg * 16 + lm) * 8 + i;
  int tap = k >> CSH, c = k & (CPAD - 1);
  float val = (c < CIN && tap < KK) ? z[(size_t)(c * KK + tap) * COUT + n] : 0.f;
  unsigned hi = rne16(val);
  float hif = __uint_as_float(hi << 16);
  unsigned lo = rne16(val - hif);
  zh[e] = (unsigned short)hi;
  zl[e] = (unsigned short)lo;
}

// ---------------- logmap0 + per-pixel sum of squares ------------------------
__global__ __launch_bounds__(256) void logmap_s2_kernel(
    const float* __restrict__ in, float* __restrict__ out,
    float* __restrict__ s2, int C, int HW, int total) {
  int i = blockIdx.x * blockDim.x + threadIdx.x;
  if (i >= total) return;
  int b = i / HW, s = i - b * HW;
  const float* p = in + (size_t)b * C * HW + s;
  float ss = 0.f;
  for (int c = 0; c < C; ++c) { float v = p[(size_t)c * HW]; ss += v * v; }
  float n = sqrtf(fmaxf(ss, EPSF));
  float f = atanh_over(n);
  float* q = out + (size_t)b * C * HW + s;
  for (int c = 0; c < C; ++c) q[(size_t)c * HW] = f * p[(size_t)c * HW];
  s2[i] = f * f * ss;
}

// ---------------- weighted spatial mean -------------------------------------
__global__ __launch_bounds__(256) void wavgpool_kernel(
    const float* __restrict__ vm, const float* __restrict__ f,
    float* __restrict__ flat, int C, int HW, int flatC, int coff) {
  int c = blockIdx.x, b = blockIdx.y, tid = threadIdx.x;
  const float* p = vm + ((size_t)b * C + c) * HW;
  const float* q = f + (size_t)b * HW;
  float s = 0.f;
  for (int i = tid; i < HW; i += blockDim.x) s += p[i] * q[i];
  __shared__ float red[256];
  red[tid] = s; __syncthreads();
  for (int st = 128; st > 0; st >>= 1) {
    if (tid < st) red[tid] += red[tid + st];
    __syncthreads();
  }
  if (tid == 0) flat[(size_t)b * flatC + coff + c] = red[0] / (float)HW;
}

// ---------------- MFMA fused hconv + hrelu-tangent + maxpool + maps ---------
template <int CIN, int CSH, int TAPS, int K, int PAD, int COUT, int H, int W,
          int TH, int TW, int WM, int MREP, int WN>
__global__ __launch_bounds__(WM * WN * 64) void hconv_mfma(
    const float* __restrict__ vin, const float* __restrict__ s2map,
    const unsigned short* __restrict__ zfh,
    const unsigned short* __restrict__ zfl,
    const float* __restrict__ r, const float* __restrict__ zn,
    float* __restrict__ mout, float* __restrict__ s2out,
    float* __restrict__ fout, float scale) {
  constexpr int NTHR = WM * WN * 64;
  constexpr int CPAD = 1 << CSH;
  constexpr int KK = K * K;
  constexpr int MT = WM * MREP * 16;
  static_assert(MT == TH * TW, "tile rows mismatch");
  constexpr int NT = COUT / 16;
  constexpr int NTW = NT / WN;
  static_assert(NTW * WN == NT, "");
  constexpr int NK = TAPS * CPAD / 32;
  static_assert(NK * 32 == TAPS * CPAD, "K-step misalign");
  constexpr int SY = TH + K - 1, SX = TW + K - 1;
  constexpr int NPOS = SY * SX;
  constexpr int RWU = (CPAD >= 32) ? (CPAD + 8) : CPAD;
  constexpr int CGR = CPAD / 8;
  constexpr int TRS = MT + 4;
  constexpr int WINU = NPOS * RWU;
  constexpr int TRU = 2 * COUT * TRS;
  constexpr int SHU = (2 * WINU > TRU) ? 2 * WINU : TRU;
  constexpr int HO = H / 2, WO = W / 2;
  constexpr int PH = TH / 2, PW = TW / 2, NPP = PH * PW;
  constexpr int CG0 = NTHR / NPP;
  constexpr int CG = (CG0 < COUT) ? CG0 : COUT;
  constexpr int CPG = COUT / CG;
  static_assert(CPG * CG == COUT, "pool split");

  __shared__ __align__(16) unsigned short winbuf[SHU];
  __shared__ float s2w[NPOS];
  __shared__ float gA[MT], cA[MT];
  __shared__ float c1b[COUT], shb[COUT], z2b[COUT];
  __shared__ float redw[(WN > 1) ? WN * MT : 1];
  __shared__ float pacc[NTHR];
  unsigned short* winh = winbuf;
  unsigned short* winl = winbuf + WINU;

  const int tid = threadIdx.x;
  int bid = blockIdx.x;
  constexpr int TXC = W / TW, TYC = H / TH;
  const int tx = bid % TXC; bid /= TXC;
  const int ty = bid % TYC; const int b = bid / TYC;
  const int y0 = ty * TH, x0 = tx * TW;

  if (tid < COUT) {
    float rv = r[tid];
    float znv = zn[tid];
    float ch = coshf(2.f * rv), sh = sinhf(2.f * rv);
    c1b[tid] = 2.f * ch / znv;
    shb[tid] = sh;
    z2b[tid] = 2.f * znv;
  }
  const float* vb = vin + (size_t)b * CIN * H * W;
  for (int idx = tid; idx < CGR * NPOS; idx += NTHR) {
    int pos = idx / CGR;
    int cg = idx - pos * CGR;
    int sy = pos / SX, sx = pos - sy * SX;
    int gy = y0 + sy - PAD, gx = x0 + sx - PAD;
    bool inb = (gy >= 0 && gy < H && gx >= 0 && gx < W);
    const float* gp = vb + (size_t)(cg * 8) * H * W + gy * W + gx;
    short8 hv, lv;
#pragma unroll
    for (int j = 0; j < 8; ++j) {
      float val = 0.f;
      if constexpr (CIN == CPAD) {
        if (inb) val = gp[(size_t)j * H * W];
      } else {
        if (inb && (cg * 8 + j) < CIN) val = gp[(size_t)j * H * W];
      }
      unsigned hi = rne16(val);
      float hif = __uint_as_float(hi << 16);
      unsigned lo = rne16(val - hif);
      hv[j] = (short)hi;
      lv[j] = (short)lo;
    }
    *(short8*)(winh + pos * RWU + cg * 8) = hv;
    *(short8*)(winl + pos * RWU + cg * 8) = lv;
  }
  const float* s2bp = s2map + (size_t)b * H * W;
  for (int i = tid; i < NPOS; i += NTHR) {
    int sy = i / SX, sx = i - sy * SX;
    int gy = y0 + sy - PAD, gx = x0 + sx - PAD;
    s2w[i] = (gy >= 0 && gy < H && gx >= 0 && gx < W) ? s2bp[gy * W + gx] : 0.f;
  }
  __syncthreads();

  if (tid < MT) {
    int py = tid / TW, px = tid - (tid / TW) * TW;
    float s = 0.f;
    for (int iy = 0; iy < K; ++iy)
      for (int ix = 0; ix < K; ++ix)
        s += s2w[(py + iy) * SX + (px + ix)];
    float n = sqrtf(fmaxf(scale * scale * s, EPSF));
    float th = n * tanh_over(n);
    gA[tid] = th * scale * frcp(n);
    cA[tid] = th * th;
  }
  __syncthreads();

  const int w = __builtin_amdgcn_readfirstlane(tid >> 6);
  const int wm = w % WM, wn = w / WM;
  const int lane = tid & 63, lm = lane & 15, lg = lane >> 4;
  const int nt0 = wn * NTW;

  int pyr[MREP], pxr[MREP];
#pragma unroll
  for (int rep = 0; rep < MREP; ++rep) {
    int m = (wm * MREP + rep) * 16 + lm;
    pyr[rep] = m / TW;
    pxr[rep] = m - (m / TW) * TW;
  }

  f32x4 acc[MREP][NTW];
#pragma unroll
  for (int rep = 0; rep < MREP; ++rep)
#pragma unroll
    for (int j = 0; j < NTW; ++j) acc[rep][j] = (f32x4){0.f, 0.f, 0.f, 0.f};

  const unsigned short* bph = zfh + (size_t)nt0 * 512 + lane * 8;
  const unsigned short* bpl = zfl + (size_t)nt0 * 512 + lane * 8;
  constexpr size_t BSTEP = (size_t)NT * 512;

#define LOADB(BH, BL, KS)                                             \
  do {                                                                \
    const unsigned short* ph_ = bph + (size_t)(KS)*BSTEP;             \
    const unsigned short* pl_ = bpl + (size_t)(KS)*BSTEP;             \
    _Pragma("unroll") for (int j_ = 0; j_ < NTW; ++j_) {              \
      BH[j_] = *(const uint4*)(ph_ + j_ * 512);                       \
      BL[j_] = *(const uint4*)(pl_ + j_ * 512);                       \
    }                                                                 \
  } while (0)

#define STEPK(KS, BH, BL)                                             \
  do {                                                                \
    const int kbase_ = (KS)*32 + lg * 8;                              \
    const int tap_ = kbase_ >> CSH;                                   \
    const int c0_ = kbase_ & (CPAD - 1);                              \
    bool valid_ = true;                                               \
    if constexpr (TAPS != KK) valid_ = (tap_ < KK);                   \
    const int iy_ = tap_ / K, ix_ = tap_ - (tap_ / K) * K;            \
    _Pragma("unroll") for (int rep_ = 0; rep_ < MREP; ++rep_) {       \
      short8 ahi_ = {}, alo_ = {};                                    \
      if (valid_) {                                                   \
        const int lofs_ =                                             \
            ((pyr[rep_] + iy_) * SX + (pxr[rep_] + ix_)) * RWU + c0_; \
        ahi_ = *(const short8*)(winh + lofs_);                        \
        alo_ = *(const short8*)(winl + lofs_);                        \
      }                                                               \
      _Pragma("unroll") for (int j_ = 0; j_ < NTW; ++j_) {            \
        short8 bhv_ = __builtin_bit_cast(short8, BH[j_]);             \
        short8 blv_ = __builtin_bit_cast(short8, BL[j_]);             \
        acc[rep_][j_] = __builtin_amdgcn_mfma_f32_16x16x32_bf16(      \
            ahi_, bhv_, acc[rep_][j_], 0, 0, 0);                      \
        acc[rep_][j_] = __builtin_amdgcn_mfma_f32_16x16x32_bf16(      \
            ahi_, blv_, acc[rep_][j_], 0, 0, 0);                      \
        acc[rep_][j_] = __builtin_amdgcn_mfma_f32_16x16x32_bf16(      \
            alo_, bhv_, acc[rep_][j_], 0, 0, 0);                      \
      }                                                               \
    }                                                                 \
  } while (0)

  {
    uint4 BhA[NTW], BlA[NTW], BhB[NTW], BlB[NTW];
    LOADB(BhA, BlA, 0);
    int ks = 0;
    for (;;) {
      if (ks + 1 < NK) LOADB(BhB, BlB, ks + 1);
      STEPK(ks, BhA, BlA);
      if (++ks == NK) break;
      if (ks + 1 < NK) LOADB(BhA, BlA, ks + 1);
      STEPK(ks, BhB, BlB);
      if (++ks == NK) break;
    }
  }
#undef LOADB
#undef STEPK

  float lsA[MREP][4];
#pragma unroll
  for (int rep = 0; rep < MREP; ++rep) {
    const int rbase = (wm * MREP + rep) * 16 + lg * 4;
    float ls[4] = {0.f, 0.f, 0.f, 0.f};
    float gR[4], rcpom[4], onePc[4];
#pragma unroll
    for (int reg = 0; reg < 4; ++reg) {
      float cx2 = cA[rbase + reg];
      gR[reg] = gA[rbase + reg];
      rcpom[reg] = frcp(fmaxf(1.f - cx2, EPSF));
      onePc[reg] = 1.f + cx2;
    }
#pragma unroll
    for (int j = 0; j < NTW; ++j) {
      int o = (nt0 + j) * 16 + lm;
      float c1 = c1b[o], sh = shb[o], z2 = z2b[o];
#pragma unroll
      for (int reg = 0; reg < 4; ++reg) {
        float num = c1 * (gR[reg] * acc[rep][j][reg]) - onePc[reg] * sh;
        float yv = sinh_zasinh(num * rcpom[reg], z2);
        acc[rep][j][reg] = yv;
        ls[reg] += yv * yv;
      }
    }
#pragma unroll
    for (int mask = 1; mask < 16; mask <<= 1)
#pragma unroll
      for (int reg = 0; reg < 4; ++reg)
        ls[reg] += __shfl_xor(ls[reg], mask);
#pragma unroll
    for (int reg = 0; reg < 4; ++reg) lsA[rep][reg] = ls[reg];
    if constexpr (WN > 1) {
      if (lm == 0) {
#pragma unroll
        for (int reg = 0; reg < 4; ++reg)
          redw[wn * MT + rbase + reg] = ls[reg];
      }
    }
  }
  __syncthreads();

  float* tr = (float*)winbuf;
#pragma unroll
  for (int rep = 0; rep < MREP; ++rep) {
    const int rbase = (wm * MREP + rep) * 16 + lg * 4;
    float fs[4];
#pragma unroll
    for (int reg = 0; reg < 4; ++reg) {
      float s;
      if constexpr (WN > 1) {
        s = 0.f;
#pragma unroll
        for (int k2 = 0; k2 < WN; ++k2) s += redw[k2 * MT + rbase + reg];
      } else {
        s = lsA[rep][reg];
      }
      float inv = frcp(1.f + sqrtf(1.f + s));
      float ny = sqrtf(fmaxf(s * inv * inv, EPSF));
      fs[reg] = atanh_over(ny) * inv;
    }
#pragma unroll
    for (int j = 0; j < NTW; ++j) {
      int o = (nt0 + j) * 16 + lm;
#pragma unroll
      for (int reg = 0; reg < 4; ++reg)
        tr[o * TRS + rbase + reg] = fs[reg] * fmaxf(acc[rep][j][reg], 0.f);
    }
  }
  __syncthreads();

  const int y0p = y0 >> 1, x0p = x0 >> 1;
  if (tid < NPP * CG) {
    int cg = tid / NPP, p = tid - cg * NPP;
    int ppy = p / PW, ppx = p - ppy * PW;
    const float* base = tr + (ppy * 2) * TW + ppx * 2;
    float ss = 0.f;
#pragma unroll
    for (int j = 0; j < CPG; ++j) {
      int c = cg * CPG + j;
      const float* rp = base + c * TRS;
      float mv = fmaxf(fmaxf(rp[0], rp[1]), fmaxf(rp[TW], rp[TW + 1]));
      mout[((size_t)(b * COUT + c) * HO + y0p + ppy) * WO + x0p + ppx] = mv;
      ss += mv * mv;
    }
    pacc[cg * NPP + p] = ss;
  }
  __syncthreads();
  if (tid < NPP) {
    float ss = 0.f;
    for (int k2 = 0; k2 < CG; ++k2) ss += pacc[k2 * NPP + tid];
    int ppy = tid / PW, ppx = tid - (tid / PW) * PW;
    size_t pix = ((size_t)b * HO + y0p + ppy) * WO + x0p + ppx;
    s2out[pix] = ss;
    float n = sqrtf(fmaxf(ss, EPSF));
    fout[pix] = tanh_over(n);
  }
}

// ---------------- head: parallel Poincare FC --------------------------------
// grid (ceil(NOUT/64), B); computes y for 64 outputs/block + partial sums.
template <int NIN, int NOUT, bool POS>
__global__ __launch_bounds__(256) void pfc_y_kernel(
    const float* __restrict__ x, const float* __restrict__ z,
    const float* __restrict__ r, const float* __restrict__ zn,
    float* __restrict__ ybuf, float* __restrict__ part,
    float* __restrict__ partpos) {
  constexpr int KCH = NIN / 4;
  const int b = blockIdx.y, tid = threadIdx.x;
  const int nt = gridDim.x;
  const int o = blockIdx.x * 64 + (tid & 63);
  const int kg = tid >> 6;
  __shared__ float xs[NIN];
  __shared__ float red[256];
  for (int i = tid; i < NIN; i += 256) xs[i] = x[(size_t)b * NIN + i];
  __syncthreads();
  float s = 0.f;
  for (int i = tid; i < NIN; i += 256) { float v = xs[i]; s += v * v; }
  red[tid] = s;
  __syncthreads();
  for (int st = 128; st > 0; st >>= 1) {
    if (tid < st) red[tid] += red[tid + st];
    __syncthreads();
  }
  const float cx2 = red[0];
  __syncthreads();
  // K-split dot: wave kg covers k in [kg*KCH, (kg+1)*KCH)
  float d = 0.f;
  if (o < NOUT) {
    const float* zp = z + (size_t)(kg * KCH) * NOUT + o;
    const float* xp = xs + kg * KCH;
    for (int k = 0; k < KCH; ++k) d = fmaf(xp[k], zp[(size_t)k * NOUT], d);
  }
  red[tid] = d;
  __syncthreads();
  if (tid < 64) {
    float dot = red[tid] + red[tid + 64] + red[tid + 128] + red[tid + 192];
    float y = 0.f;
    if (o < NOUT) {
      float znv = zn[o], rv = r[o];
      float onemc = fmaxf(1.f - cx2, EPSF);
      float num = 2.f * (dot / znv) * coshf(2.f * rv) - (1.f + cx2) * sinhf(2.f * rv);
      y = sinh_zasinh(num * frcp(onemc), 2.f * znv);
      ybuf[(size_t)b * NOUT + o] = y;
    }
    float ls = y * y;
    float lp = POS ? (fmaxf(y, 0.f) * fmaxf(y, 0.f)) : 0.f;
#pragma unroll
    for (int mask = 1; mask < 64; mask <<= 1) {
      ls += __shfl_xor(ls, mask);
      if (POS) lp += __shfl_xor(lp, mask);
    }
    if (tid == 0) {
      part[(size_t)b * nt + blockIdx.x] = ls;
      if (POS) partpos[(size_t)b * nt + blockIdx.x] = lp;
    }
  }
}

// finish FC1 + fused hrelu: h = tanh(nw)/nw * fl * max(y,0)
template <int NOUT, int NT>
__global__ __launch_bounds__(256) void pfc_fin_hrelu_kernel(
    const float* __restrict__ ybuf, const float* __restrict__ part,
    const float* __restrict__ partpos, float* __restrict__ h) {
  const int b = blockIdx.x, tid = threadIdx.x;
  float s = 0.f, sp = 0.f;
#pragma unroll
  for (int t = 0; t < NT; ++t) {
    s += part[(size_t)b * NT + t];
    sp += partpos[(size_t)b * NT + t];
  }
  float inv = frcp(1.f + sqrtf(1.f + s));          // ball projection
  float ny = sqrtf(fmaxf(s, EPSF)) * inv;          // |proj(y)|
  float fl = atanh_over(ny) * inv;                 // logmap0 * proj factor
  float nw = fl * sqrtf(fmaxf(sp, EPSF));          // |relu tangent|
  float gg = tanh_over(nw);                        // expmap0 factor
  float cmb = gg * fl;
  for (int o = tid; o < NOUT; o += 256)
    h[(size_t)b * NOUT + o] = cmb * fmaxf(ybuf[(size_t)b * NOUT + o], 0.f);
}

// finish FC2: out = y / (1 + sqrt(1 + sum y^2))
template <int NOUT, int NT>
__global__ __launch_bounds__(256) void pfc_fin_kernel(
    const float* __restrict__ ybuf, const float* __restrict__ part,
    float* __restrict__ out) {
  const int b = blockIdx.x, tid = threadIdx.x;
  float s = 0.f;
#pragma unroll
  for (int t = 0; t < NT; ++t) s += part[(size_t)b * NT + t];
  float inv = frcp(1.f + sqrtf(1.f + s));
  for (int o = tid; o < NOUT; o += 256)
    out[(size_t)b * NOUT + o] = ybuf[(size_t)b * NOUT + o] * inv;
}

// ---------------------------------------------------------------------------
static inline double beta_fn(double a, double b) {
  return std::exp(std::lgamma(a) + std::lgamma(b) - std::lgamma(a + b));
}

extern "C" void kernel_launch(void* const* d_in, const int* in_sizes, int n_in,
                              void* d_out, int out_size, void* d_ws, size_t ws_size,
                              hipStream_t stream) {
  const float* x   = (const float*)d_in[0];
  const float* z1  = (const float*)d_in[1];
  const float* b1  = (const float*)d_in[2];
  const float* z2  = (const float*)d_in[3];
  const float* b2  = (const float*)d_in[4];
  const float* z3  = (const float*)d_in[5];
  const float* b3  = (const float*)d_in[6];
  const float* z4  = (const float*)d_in[7];
  const float* b4  = (const float*)d_in[8];
  const float* zf1 = (const float*)d_in[9];
  const float* bf1 = (const float*)d_in[10];
  const float* zf2 = (const float*)d_in[11];
  const float* bf2 = (const float*)d_in[12];
  float* outp = (float*)d_out;

  float* ws    = (float*)d_ws;
  float* zn    = ws;                        // 2048
  float* flat  = ws + 2048;                 // 5632
  float* h1r   = ws + 7680;                 // 8192 (ybuf for FC1)
  float* h1    = ws + 15872;                // 8704
  float* vm0   = ws + 24576;                // 786,432
  float* mA    = vm0 + 786432;              // 2,097,152
  float* mB    = mA + 2097152;              // 1,048,576
  float* s2a   = mB + 1048576;              // 262,144
  float* s2b   = s2a + 262144;              // 65,536
  float* fA    = s2b + 65536;               // 65,536
  float* fB    = fA + 65536;                // 16,384
  float* part  = fB + 16384;                // 32,768 (znorm partials)
  unsigned short* zfu = (unsigned short*)(part + 32768);
  unsigned short* zf1h = zfu;               //   3,072
  unsigned short* zf1l = zfu + 3072;
  unsigned short* zf2h = zfu + 6144;        //  51,200
  unsigned short* zf2l = zfu + 57344;
  unsigned short* zf3h = zfu + 108544;      // 401,408
  unsigned short* zf3l = zfu + 509952;
  unsigned short* zf4h = zfu + 911360;      // 147,456
  unsigned short* zf4l = zfu + 1058816;     // ends 1,206,272 ushorts
  float* yb2  = part + 32768 + 603136;      // 16,000 (ybuf for FC2)
  float* hp1  = yb2 + 16000;                // 128
  float* hpp1 = hp1 + 128;                  // 128
  float* hp2  = hpp1 + 128;                 // 256

  const float s1  = (float)(beta_fn(27.0 / 2.0, 0.5) / beta_fn(3.0 / 2.0, 0.5));
  const float s2c = (float)(beta_fn(800.0 / 2.0, 0.5) / beta_fn(32.0 / 2.0, 0.5));
  const float s3  = (float)(beta_fn(3136.0 / 2.0, 0.5) / beta_fn(64.0 / 2.0, 0.5));
  const float s4  = (float)(beta_fn(1152.0 / 2.0, 0.5) / beta_fn(128.0 / 2.0, 0.5));

  auto g1 = [](int n) { return dim3((n + 255) / 256); };

  // prep: column norms (two-stage) + fragment-ordered z
  znorm_part_kernel<<<dim3(1, 16),  256, 0, stream>>>(z1, part, 27, 32, 0);
  znorm_part_kernel<<<dim3(1, 16),  256, 0, stream>>>(z2, part, 800, 64, 32);
  znorm_part_kernel<<<dim3(2, 16),  256, 0, stream>>>(z3, part, 3136, 128, 96);
  znorm_part_kernel<<<dim3(2, 16),  256, 0, stream>>>(z4, part, 1152, 128, 224);
  znorm_part_kernel<<<dim3(8, 16),  256, 0, stream>>>(zf1, part, 352, 512, 352);
  znorm_part_kernel<<<dim3(16, 16), 256, 0, stream>>>(zf2, part, 512, 1000, 864);
  znorm_fin_kernel<<<8, 256, 0, stream>>>(part, zn);
  zfprep_kernel<3, 3, 12, 9, 32><<<12, 256, 0, stream>>>(z1, zf1h, zf1l);
  zfprep_kernel<32, 5, 25, 25, 64><<<200, 256, 0, stream>>>(z2, zf2h, zf2l);
  zfprep_kernel<64, 6, 49, 49, 128><<<1568, 256, 0, stream>>>(z3, zf3h, zf3l);
  zfprep_kernel<128, 7, 9, 9, 128><<<576, 256, 0, stream>>>(z4, zf4h, zf4l);

  // ---- layer 1: (16,3,128,128) -> m1 (16,32,64,64)
  logmap_s2_kernel<<<g1(262144), 256, 0, stream>>>(x, vm0, s2a, 3, 16384, 262144);
  hconv_mfma<3, 3, 12, 3, 1, 32, 128, 128, 8, 8, 4, 1, 1>
      <<<4096, 256, 0, stream>>>(vm0, s2a, zf1h, zf1l, b1, zn + 0, mA, s2b, fA, s1);
  wavgpool_kernel<<<dim3(32, 16), 256, 0, stream>>>(mA, fA, flat, 32, 4096, 352, 0);

  // ---- layer 2: m1 -> m2 (16,64,32,32)
  hconv_mfma<32, 5, 25, 5, 2, 64, 64, 64, 8, 8, 1, 4, 4>
      <<<1024, 256, 0, stream>>>(mA, s2b, zf2h, zf2l, b2, zn + 32, mB, s2a, fB, s2c);
  wavgpool_kernel<<<dim3(64, 16), 256, 0, stream>>>(mB, fB, flat, 64, 1024, 352, 32);

  // ---- layer 3: m2 -> m3 (16,128,16,16)
  hconv_mfma<64, 6, 49, 7, 3, 128, 32, 32, 8, 8, 1, 4, 8>
      <<<256, 512, 0, stream>>>(mB, s2a, zf3h, zf3l, b3, zn + 96, mA, s2b, fA, s3);
  wavgpool_kernel<<<dim3(128, 16), 256, 0, stream>>>(mA, fA, flat, 128, 256, 352, 96);

  // ---- layer 4: m3 -> m4 (16,128,8,8)
  hconv_mfma<128, 7, 9, 3, 1, 128, 16, 16, 2, 8, 1, 1, 8>
      <<<256, 512, 0, stream>>>(mA, s2b, zf4h, zf4l, b4, zn + 224, mB, s2a, fB, s4);
  wavgpool_kernel<<<dim3(128, 16), 256, 0, stream>>>(mB, fB, flat, 128, 64, 352, 224);

  // ---- head: flat (16,352) -> (16,512) -> hrelu -> (16,1000)
  pfc_y_kernel<352, 512, true><<<dim3(8, 16), 256, 0, stream>>>(
      flat, zf1, bf1, zn + 352, h1r, hp1, hpp1);
  pfc_fin_hrelu_kernel<512, 8><<<16, 256, 0, stream>>>(h1r, hp1, hpp1, h1);
  pfc_y_kernel<512, 1000, false><<<dim3(16, 16), 256, 0, stream>>>(
      h1, zf2, bf2, zn + 864, yb2, hp2, nullptr);
  pfc_fin_kernel<1000, 16><<<16, 256, 0, stream>>>(yb2, hp2, outp);

  (void)in_sizes; (void)n_in; (void)out_size; (void)ws_size;
}

// Round 10
// 190.759 us; speedup vs baseline: 16.1280x; 1.1359x over previous
//
#include <hip/hip_runtime.h>
#include <cmath>

// ---------------------------------------------------------------------------
// Hyperbolic MS-CNN (Poincare ball, c=1) — round 10.
//  * MFMA convs (split bf16 hi/lo, 3 MFMAs) + fused epilogue + MREP.
//  * L3 re-tiled MT=32 -> 2 blocks/CU (occupancy 25%->50% cap).
//  * znorm / zfprep prep merged into 2 kernels (launch overhead).
// ---------------------------------------------------------------------------

#define EPSF 1e-15f
#define ATANH_CAP 0.9999999f  // 1 - 1e-7

typedef __attribute__((ext_vector_type(8))) short short8;
typedef __attribute__((ext_vector_type(4))) float f32x4;

__device__ inline unsigned rne16(float f) {
  unsigned u = __float_as_uint(f);
  return (u + 0x7FFFu + ((u >> 16) & 1u)) >> 16;
}
__device__ inline float fexp2(float x) { return __builtin_amdgcn_exp2f(x); }
__device__ inline float flog2(float x) { return __builtin_amdgcn_logf(x); }
__device__ inline float frcp(float x) { return __builtin_amdgcn_rcpf(x); }

__device__ inline float atanh_over(float n) {
  float nc = fminf(n, ATANH_CAP);
  float f = 0.34657359f * flog2((1.f + nc) * frcp(1.f - nc)) * frcp(n);
  float s = 1.f + 0.33333333f * n * n;
  return (n < 0.004f) ? s : f;
}
__device__ inline float tanh_over(float n) {
  float p2 = fexp2(2.885390082f * n);  // e^{2n}
  float f = (1.f - 2.f * frcp(p2 + 1.f)) * frcp(n);
  float s = 1.f - 0.33333333f * n * n;
  return (n < 0.004f) ? s : f;
}
__device__ inline float sinh_zasinh(float q, float twozn) {
  float aq = fabsf(q);
  float t = aq + sqrtf(fmaf(aq, aq, 1.f));
  float p = fexp2(twozn * flog2(t));
  float y = 0.5f * (p - frcp(p));
  return copysignf(y, q);
}

// ---------------- merged z column norms, stage 1 ----------------------------
// grid (30, 16): [0]z1 [1]z2 [2,3]z3 [4,5]z4 [6..13]zf1 [14..29]zf2
__global__ __launch_bounds__(256) void znorm_all_kernel(
    const float* __restrict__ z1, const float* __restrict__ z2,
    const float* __restrict__ z3, const float* __restrict__ z4,
    const float* __restrict__ zf1, const float* __restrict__ zf2,
    float* __restrict__ part) {
  const int bx = blockIdx.x;
  const float* z; int K, Nout, coff, lb;
  if (bx < 1)       { z = z1;  K = 27;   Nout = 32;   coff = 0;   lb = bx; }
  else if (bx < 2)  { z = z2;  K = 800;  Nout = 64;   coff = 32;  lb = bx - 1; }
  else if (bx < 4)  { z = z3;  K = 3136; Nout = 128;  coff = 96;  lb = bx - 2; }
  else if (bx < 6)  { z = z4;  K = 1152; Nout = 128;  coff = 224; lb = bx - 4; }
  else if (bx < 14) { z = zf1; K = 352;  Nout = 512;  coff = 352; lb = bx - 6; }
  else              { z = zf2; K = 512;  Nout = 1000; coff = 864; lb = bx - 14; }
  const int tid = threadIdx.x;
  const int col = lb * 64 + (tid & 63);
  const int kg = (blockIdx.y << 2) + (tid >> 6);
  float s = 0.f;
  if (col < Nout)
    for (int k = kg; k < K; k += 64) {
      float v = z[(size_t)k * Nout + col];
      s += v * v;
    }
  __shared__ float red[256];
  red[tid] = s;
  __syncthreads();
  if (tid < 64 && col < Nout) {
    float t = red[tid] + red[tid + 64] + red[tid + 128] + red[tid + 192];
    part[(size_t)blockIdx.y * 2048 + coff + col] = t;
  }
}
__global__ __launch_bounds__(256) void znorm_fin_kernel(
    const float* __restrict__ part, float* __restrict__ zn) {
  int c = blockIdx.x * 256 + threadIdx.x;
  float s = 0.f;
#pragma unroll
  for (int rr = 0; rr < 16; ++rr) s += part[rr * 2048 + c];
  zn[c] = sqrtf(fmaxf(s, EPSF));
}

// ---------------- z -> MFMA-fragment-ordered hi/lo bf16 (merged) ------------
template <int CIN, int CSH, int TAPS, int KK, int COUT>
__device__ inline void zfprep_body(int blk, const float* __restrict__ z,
                                   unsigned short* __restrict__ zh,
                                   unsigned short* __restrict__ zl) {
  constexpr int CPAD = 1 << CSH;
  constexpr int KP = TAPS * CPAD;
  constexpr int NT = COUT / 16;
  int t = blk * 256 + threadIdx.x;
  if (t >= KP * COUT) return;
  int k = t / COUT, n = t - k * COUT;
  int ks = k >> 5, lg = (k >> 3) & 3, i = k & 7;
  int nt = n >> 4, lm = n & 15;
  size_t e = ((size_t)(ks * NT + nt) * 64 + lg * 16 + lm) * 8 + i;
  int tap = k >> CSH, c = k & (CPAD - 1);
  float val = (c < CIN && tap < KK) ? z[(size_t)(c * KK + tap) * COUT + n] : 0.f;
  unsigned hi = rne16(val);
  float hif = __uint_as_float(hi << 16);
  unsigned lo = rne16(val - hif);
  zh[e] = (unsigned short)hi;
  zl[e] = (unsigned short)lo;
}
// grid 2356: [0,12) z1 | [12,212) z2 | [212,1780) z3 | [1780,2356) z4
__global__ __launch_bounds__(256) void zfprep_all_kernel(
    const float* __restrict__ z1, const float* __restrict__ z2,
    const float* __restrict__ z3, const float* __restrict__ z4,
    unsigned short* __restrict__ zf1h, unsigned short* __restrict__ zf1l,
    unsigned short* __restrict__ zf2h, unsigned short* __restrict__ zf2l,
    unsigned short* __restrict__ zf3h, unsigned short* __restrict__ zf3l,
    unsigned short* __restrict__ zf4h, unsigned short* __restrict__ zf4l) {
  const int bx = blockIdx.x;
  if (bx < 12)        zfprep_body<3, 3, 12, 9, 32>(bx, z1, zf1h, zf1l);
  else if (bx < 212)  zfprep_body<32, 5, 25, 25, 64>(bx - 12, z2, zf2h, zf2l);
  else if (bx < 1780) zfprep_body<64, 6, 49, 49, 128>(bx - 212, z3, zf3h, zf3l);
  else                zfprep_body<128, 7, 9, 9, 128>(bx - 1780, z4, zf4h, zf4l);
}

// ---------------- logmap0 + per-pixel sum of squares ------------------------
__global__ __launch_bounds__(256) void logmap_s2_kernel(
    const float* __restrict__ in, float* __restrict__ out,
    float* __restrict__ s2, int C, int HW, int total) {
  int i = blockIdx.x * blockDim.x + threadIdx.x;
  if (i >= total) return;
  int b = i / HW, s = i - b * HW;
  const float* p = in + (size_t)b * C * HW + s;
  float ss = 0.f;
  for (int c = 0; c < C; ++c) { float v = p[(size_t)c * HW]; ss += v * v; }
  float n = sqrtf(fmaxf(ss, EPSF));
  float f = atanh_over(n);
  float* q = out + (size_t)b * C * HW + s;
  for (int c = 0; c < C; ++c) q[(size_t)c * HW] = f * p[(size_t)c * HW];
  s2[i] = f * f * ss;
}

// ---------------- weighted spatial mean -------------------------------------
__global__ __launch_bounds__(256) void wavgpool_kernel(
    const float* __restrict__ vm, const float* __restrict__ f,
    float* __restrict__ flat, int C, int HW, int flatC, int coff) {
  int c = blockIdx.x, b = blockIdx.y, tid = threadIdx.x;
  const float* p = vm + ((size_t)b * C + c) * HW;
  const float* q = f + (size_t)b * HW;
  float s = 0.f;
  for (int i = tid; i < HW; i += blockDim.x) s += p[i] * q[i];
  __shared__ float red[256];
  red[tid] = s; __syncthreads();
  for (int st = 128; st > 0; st >>= 1) {
    if (tid < st) red[tid] += red[tid + st];
    __syncthreads();
  }
  if (tid == 0) flat[(size_t)b * flatC + coff + c] = red[0] / (float)HW;
}

// ---------------- MFMA fused hconv + hrelu-tangent + maxpool + maps ---------
template <int CIN, int CSH, int TAPS, int K, int PAD, int COUT, int H, int W,
          int TH, int TW, int WM, int MREP, int WN>
__global__ __launch_bounds__(WM * WN * 64) void hconv_mfma(
    const float* __restrict__ vin, const float* __restrict__ s2map,
    const unsigned short* __restrict__ zfh,
    const unsigned short* __restrict__ zfl,
    const float* __restrict__ r, const float* __restrict__ zn,
    float* __restrict__ mout, float* __restrict__ s2out,
    float* __restrict__ fout, float scale) {
  constexpr int NTHR = WM * WN * 64;
  constexpr int CPAD = 1 << CSH;
  constexpr int KK = K * K;
  constexpr int MT = WM * MREP * 16;
  static_assert(MT == TH * TW, "tile rows mismatch");
  constexpr int NT = COUT / 16;
  constexpr int NTW = NT / WN;
  static_assert(NTW * WN == NT, "");
  constexpr int NK = TAPS * CPAD / 32;
  static_assert(NK * 32 == TAPS * CPAD, "K-step misalign");
  constexpr int SY = TH + K - 1, SX = TW + K - 1;
  constexpr int NPOS = SY * SX;
  constexpr int RWU = (CPAD >= 32) ? (CPAD + 8) : CPAD;
  constexpr int CGR = CPAD / 8;
  constexpr int TRS = MT + 4;
  constexpr int WINU = NPOS * RWU;
  constexpr int TRU = 2 * COUT * TRS;
  constexpr int SHU = (2 * WINU > TRU) ? 2 * WINU : TRU;
  constexpr int HO = H / 2, WO = W / 2;
  constexpr int PH = TH / 2, PW = TW / 2, NPP = PH * PW;
  constexpr int CG0 = NTHR / NPP;
  constexpr int CG = (CG0 < COUT) ? CG0 : COUT;
  constexpr int CPG = COUT / CG;
  static_assert(CPG * CG == COUT, "pool split");

  __shared__ __align__(16) unsigned short winbuf[SHU];
  __shared__ float s2w[NPOS];
  __shared__ float gA[MT], cA[MT];
  __shared__ float c1b[COUT], shb[COUT], z2b[COUT];
  __shared__ float redw[(WN > 1) ? WN * MT : 1];
  __shared__ float pacc[NTHR];
  unsigned short* winh = winbuf;
  unsigned short* winl = winbuf + WINU;

  const int tid = threadIdx.x;
  int bid = blockIdx.x;
  constexpr int TXC = W / TW, TYC = H / TH;
  const int tx = bid % TXC; bid /= TXC;
  const int ty = bid % TYC; const int b = bid / TYC;
  const int y0 = ty * TH, x0 = tx * TW;

  if (tid < COUT) {
    float rv = r[tid];
    float znv = zn[tid];
    float ch = coshf(2.f * rv), sh = sinhf(2.f * rv);
    c1b[tid] = 2.f * ch / znv;
    shb[tid] = sh;
    z2b[tid] = 2.f * znv;
  }
  const float* vb = vin + (size_t)b * CIN * H * W;
  for (int idx = tid; idx < CGR * NPOS; idx += NTHR) {
    int pos = idx / CGR;
    int cg = idx - pos * CGR;
    int sy = pos / SX, sx = pos - sy * SX;
    int gy = y0 + sy - PAD, gx = x0 + sx - PAD;
    bool inb = (gy >= 0 && gy < H && gx >= 0 && gx < W);
    const float* gp = vb + (size_t)(cg * 8) * H * W + gy * W + gx;
    short8 hv, lv;
#pragma unroll
    for (int j = 0; j < 8; ++j) {
      float val = 0.f;
      if constexpr (CIN == CPAD) {
        if (inb) val = gp[(size_t)j * H * W];
      } else {
        if (inb && (cg * 8 + j) < CIN) val = gp[(size_t)j * H * W];
      }
      unsigned hi = rne16(val);
      float hif = __uint_as_float(hi << 16);
      unsigned lo = rne16(val - hif);
      hv[j] = (short)hi;
      lv[j] = (short)lo;
    }
    *(short8*)(winh + pos * RWU + cg * 8) = hv;
    *(short8*)(winl + pos * RWU + cg * 8) = lv;
  }
  const float* s2bp = s2map + (size_t)b * H * W;
  for (int i = tid; i < NPOS; i += NTHR) {
    int sy = i / SX, sx = i - sy * SX;
    int gy = y0 + sy - PAD, gx = x0 + sx - PAD;
    s2w[i] = (gy >= 0 && gy < H && gx >= 0 && gx < W) ? s2bp[gy * W + gx] : 0.f;
  }
  __syncthreads();

  if (tid < MT) {
    int py = tid / TW, px = tid - (tid / TW) * TW;
    float s = 0.f;
    for (int iy = 0; iy < K; ++iy)
      for (int ix = 0; ix < K; ++ix)
        s += s2w[(py + iy) * SX + (px + ix)];
    float n = sqrtf(fmaxf(scale * scale * s, EPSF));
    float th = n * tanh_over(n);
    gA[tid] = th * scale * frcp(n);
    cA[tid] = th * th;
  }
  __syncthreads();

  const int w = __builtin_amdgcn_readfirstlane(tid >> 6);
  const int wm = w % WM, wn = w / WM;
  const int lane = tid & 63, lm = lane & 15, lg = lane >> 4;
  const int nt0 = wn * NTW;

  int pyr[MREP], pxr[MREP];
#pragma unroll
  for (int rep = 0; rep < MREP; ++rep) {
    int m = (wm * MREP + rep) * 16 + lm;
    pyr[rep] = m / TW;
    pxr[rep] = m - (m / TW) * TW;
  }

  f32x4 acc[MREP][NTW];
#pragma unroll
  for (int rep = 0; rep < MREP; ++rep)
#pragma unroll
    for (int j = 0; j < NTW; ++j) acc[rep][j] = (f32x4){0.f, 0.f, 0.f, 0.f};

  const unsigned short* bph = zfh + (size_t)nt0 * 512 + lane * 8;
  const unsigned short* bpl = zfl + (size_t)nt0 * 512 + lane * 8;
  constexpr size_t BSTEP = (size_t)NT * 512;

#define LOADB(BH, BL, KS)                                             \
  do {                                                                \
    const unsigned short* ph_ = bph + (size_t)(KS)*BSTEP;             \
    const unsigned short* pl_ = bpl + (size_t)(KS)*BSTEP;             \
    _Pragma("unroll") for (int j_ = 0; j_ < NTW; ++j_) {              \
      BH[j_] = *(const uint4*)(ph_ + j_ * 512);                       \
      BL[j_] = *(const uint4*)(pl_ + j_ * 512);                       \
    }                                                                 \
  } while (0)

#define STEPK(KS, BH, BL)                                             \
  do {                                                                \
    const int kbase_ = (KS)*32 + lg * 8;                              \
    const int tap_ = kbase_ >> CSH;                                   \
    const int c0_ = kbase_ & (CPAD - 1);                              \
    bool valid_ = true;                                               \
    if constexpr (TAPS != KK) valid_ = (tap_ < KK);                   \
    const int iy_ = tap_ / K, ix_ = tap_ - (tap_ / K) * K;            \
    _Pragma("unroll") for (int rep_ = 0; rep_ < MREP; ++rep_) {       \
      short8 ahi_ = {}, alo_ = {};                                    \
      if (valid_) {                                                   \
        const int lofs_ =                                             \
            ((pyr[rep_] + iy_) * SX + (pxr[rep_] + ix_)) * RWU + c0_; \
        ahi_ = *(const short8*)(winh + lofs_);                        \
        alo_ = *(const short8*)(winl + lofs_);                        \
      }                                                               \
      _Pragma("unroll") for (int j_ = 0; j_ < NTW; ++j_) {            \
        short8 bhv_ = __builtin_bit_cast(short8, BH[j_]);             \
        short8 blv_ = __builtin_bit_cast(short8, BL[j_]);             \
        acc[rep_][j_] = __builtin_amdgcn_mfma_f32_16x16x32_bf16(      \
            ahi_, bhv_, acc[rep_][j_], 0, 0, 0);                      \
        acc[rep_][j_] = __builtin_amdgcn_mfma_f32_16x16x32_bf16(      \
            ahi_, blv_, acc[rep_][j_], 0, 0, 0);                      \
        acc[rep_][j_] = __builtin_amdgcn_mfma_f32_16x16x32_bf16(      \
            alo_, bhv_, acc[rep_][j_], 0, 0, 0);                      \
      }                                                               \
    }                                                                 \
  } while (0)

  {
    uint4 BhA[NTW], BlA[NTW], BhB[NTW], BlB[NTW];
    LOADB(BhA, BlA, 0);
    int ks = 0;
    for (;;) {
      if (ks + 1 < NK) LOADB(BhB, BlB, ks + 1);
      STEPK(ks, BhA, BlA);
      if (++ks == NK) break;
      if (ks + 1 < NK) LOADB(BhA, BlA, ks + 1);
      STEPK(ks, BhB, BlB);
      if (++ks == NK) break;
    }
  }
#undef LOADB
#undef STEPK

  float lsA[MREP][4];
#pragma unroll
  for (int rep = 0; rep < MREP; ++rep) {
    const int rbase = (wm * MREP + rep) * 16 + lg * 4;
    float ls[4] = {0.f, 0.f, 0.f, 0.f};
    float gR[4], rcpom[4], onePc[4];
#pragma unroll
    for (int reg = 0; reg < 4; ++reg) {
      float cx2 = cA[rbase + reg];
      gR[reg] = gA[rbase + reg];
      rcpom[reg] = frcp(fmaxf(1.f - cx2, EPSF));
      onePc[reg] = 1.f + cx2;
    }
#pragma unroll
    for (int j = 0; j < NTW; ++j) {
      int o = (nt0 + j) * 16 + lm;
      float c1 = c1b[o], sh = shb[o], z2 = z2b[o];
#pragma unroll
      for (int reg = 0; reg < 4; ++reg) {
        float num = c1 * (gR[reg] * acc[rep][j][reg]) - onePc[reg] * sh;
        float yv = sinh_zasinh(num * rcpom[reg], z2);
        acc[rep][j][reg] = yv;
        ls[reg] += yv * yv;
      }
    }
#pragma unroll
    for (int mask = 1; mask < 16; mask <<= 1)
#pragma unroll
      for (int reg = 0; reg < 4; ++reg)
        ls[reg] += __shfl_xor(ls[reg], mask);
#pragma unroll
    for (int reg = 0; reg < 4; ++reg) lsA[rep][reg] = ls[reg];
    if constexpr (WN > 1) {
      if (lm == 0) {
#pragma unroll
        for (int reg = 0; reg < 4; ++reg)
          redw[wn * MT + rbase + reg] = ls[reg];
      }
    }
  }
  __syncthreads();

  float* tr = (float*)winbuf;
#pragma unroll
  for (int rep = 0; rep < MREP; ++rep) {
    const int rbase = (wm * MREP + rep) * 16 + lg * 4;
    float fs[4];
#pragma unroll
    for (int reg = 0; reg < 4; ++reg) {
      float s;
      if constexpr (WN > 1) {
        s = 0.f;
#pragma unroll
        for (int k2 = 0; k2 < WN; ++k2) s += redw[k2 * MT + rbase + reg];
      } else {
        s = lsA[rep][reg];
      }
      float inv = frcp(1.f + sqrtf(1.f + s));
      float ny = sqrtf(fmaxf(s * inv * inv, EPSF));
      fs[reg] = atanh_over(ny) * inv;
    }
#pragma unroll
    for (int j = 0; j < NTW; ++j) {
      int o = (nt0 + j) * 16 + lm;
#pragma unroll
      for (int reg = 0; reg < 4; ++reg)
        tr[o * TRS + rbase + reg] = fs[reg] * fmaxf(acc[rep][j][reg], 0.f);
    }
  }
  __syncthreads();

  const int y0p = y0 >> 1, x0p = x0 >> 1;
  if (tid < NPP * CG) {
    int cg = tid / NPP, p = tid - cg * NPP;
    int ppy = p / PW, ppx = p - ppy * PW;
    const float* base = tr + (ppy * 2) * TW + ppx * 2;
    float ss = 0.f;
#pragma unroll
    for (int j = 0; j < CPG; ++j) {
      int c = cg * CPG + j;
      const float* rp = base + c * TRS;
      float mv = fmaxf(fmaxf(rp[0], rp[1]), fmaxf(rp[TW], rp[TW + 1]));
      mout[((size_t)(b * COUT + c) * HO + y0p + ppy) * WO + x0p + ppx] = mv;
      ss += mv * mv;
    }
    pacc[cg * NPP + p] = ss;
  }
  __syncthreads();
  if (tid < NPP) {
    float ss = 0.f;
    for (int k2 = 0; k2 < CG; ++k2) ss += pacc[k2 * NPP + tid];
    int ppy = tid / PW, ppx = tid - (tid / PW) * PW;
    size_t pix = ((size_t)b * HO + y0p + ppy) * WO + x0p + ppx;
    s2out[pix] = ss;
    float n = sqrtf(fmaxf(ss, EPSF));
    fout[pix] = tanh_over(n);
  }
}

// ---------------- head: parallel Poincare FC --------------------------------
template <int NIN, int NOUT, bool POS>
__global__ __launch_bounds__(256) void pfc_y_kernel(
    const float* __restrict__ x, const float* __restrict__ z,
    const float* __restrict__ r, const float* __restrict__ zn,
    float* __restrict__ ybuf, float* __restrict__ part,
    float* __restrict__ partpos) {
  constexpr int KCH = NIN / 4;
  const int b = blockIdx.y, tid = threadIdx.x;
  const int nt = gridDim.x;
  const int o = blockIdx.x * 64 + (tid & 63);
  const int kg = tid >> 6;
  __shared__ float xs[NIN];
  __shared__ float red[256];
  for (int i = tid; i < NIN; i += 256) xs[i] = x[(size_t)b * NIN + i];
  __syncthreads();
  float s = 0.f;
  for (int i = tid; i < NIN; i += 256) { float v = xs[i]; s += v * v; }
  red[tid] = s;
  __syncthreads();
  for (int st = 128; st > 0; st >>= 1) {
    if (tid < st) red[tid] += red[tid + st];
    __syncthreads();
  }
  const float cx2 = red[0];
  __syncthreads();
  float d = 0.f;
  if (o < NOUT) {
    const float* zp = z + (size_t)(kg * KCH) * NOUT + o;
    const float* xp = xs + kg * KCH;
    for (int k = 0; k < KCH; ++k) d = fmaf(xp[k], zp[(size_t)k * NOUT], d);
  }
  red[tid] = d;
  __syncthreads();
  if (tid < 64) {
    float dot = red[tid] + red[tid + 64] + red[tid + 128] + red[tid + 192];
    float y = 0.f;
    if (o < NOUT) {
      float znv = zn[o], rv = r[o];
      float onemc = fmaxf(1.f - cx2, EPSF);
      float num = 2.f * (dot / znv) * coshf(2.f * rv) - (1.f + cx2) * sinhf(2.f * rv);
      y = sinh_zasinh(num * frcp(onemc), 2.f * znv);
      ybuf[(size_t)b * NOUT + o] = y;
    }
    float ls = y * y;
    float lp = POS ? (fmaxf(y, 0.f) * fmaxf(y, 0.f)) : 0.f;
#pragma unroll
    for (int mask = 1; mask < 64; mask <<= 1) {
      ls += __shfl_xor(ls, mask);
      if (POS) lp += __shfl_xor(lp, mask);
    }
    if (tid == 0) {
      part[(size_t)b * nt + blockIdx.x] = ls;
      if (POS) partpos[(size_t)b * nt + blockIdx.x] = lp;
    }
  }
}

template <int NOUT, int NT>
__global__ __launch_bounds__(256) void pfc_fin_hrelu_kernel(
    const float* __restrict__ ybuf, const float* __restrict__ part,
    const float* __restrict__ partpos, float* __restrict__ h) {
  const int b = blockIdx.x, tid = threadIdx.x;
  float s = 0.f, sp = 0.f;
#pragma unroll
  for (int t = 0; t < NT; ++t) {
    s += part[(size_t)b * NT + t];
    sp += partpos[(size_t)b * NT + t];
  }
  float inv = frcp(1.f + sqrtf(1.f + s));
  float ny = sqrtf(fmaxf(s, EPSF)) * inv;
  float fl = atanh_over(ny) * inv;
  float nw = fl * sqrtf(fmaxf(sp, EPSF));
  float gg = tanh_over(nw);
  float cmb = gg * fl;
  for (int o = tid; o < NOUT; o += 256)
    h[(size_t)b * NOUT + o] = cmb * fmaxf(ybuf[(size_t)b * NOUT + o], 0.f);
}

template <int NOUT, int NT>
__global__ __launch_bounds__(256) void pfc_fin_kernel(
    const float* __restrict__ ybuf, const float* __restrict__ part,
    float* __restrict__ out) {
  const int b = blockIdx.x, tid = threadIdx.x;
  float s = 0.f;
#pragma unroll
  for (int t = 0; t < NT; ++t) s += part[(size_t)b * NT + t];
  float inv = frcp(1.f + sqrtf(1.f + s));
  for (int o = tid; o < NOUT; o += 256)
    out[(size_t)b * NOUT + o] = ybuf[(size_t)b * NOUT + o] * inv;
}

// ---------------------------------------------------------------------------
static inline double beta_fn(double a, double b) {
  return std::exp(std::lgamma(a) + std::lgamma(b) - std::lgamma(a + b));
}

extern "C" void kernel_launch(void* const* d_in, const int* in_sizes, int n_in,
                              void* d_out, int out_size, void* d_ws, size_t ws_size,
                              hipStream_t stream) {
  const float* x   = (const float*)d_in[0];
  const float* z1  = (const float*)d_in[1];
  const float* b1  = (const float*)d_in[2];
  const float* z2  = (const float*)d_in[3];
  const float* b2  = (const float*)d_in[4];
  const float* z3  = (const float*)d_in[5];
  const float* b3  = (const float*)d_in[6];
  const float* z4  = (const float*)d_in[7];
  const float* b4  = (const float*)d_in[8];
  const float* zf1 = (const float*)d_in[9];
  const float* bf1 = (const float*)d_in[10];
  const float* zf2 = (const float*)d_in[11];
  const float* bf2 = (const float*)d_in[12];
  float* outp = (float*)d_out;

  float* ws    = (float*)d_ws;
  float* zn    = ws;                        // 2048
  float* flat  = ws + 2048;                 // 5632
  float* h1r   = ws + 7680;                 // 8192 (ybuf for FC1)
  float* h1    = ws + 15872;                // 8704
  float* vm0   = ws + 24576;                // 786,432
  float* mA    = vm0 + 786432;              // 2,097,152
  float* mB    = mA + 2097152;              // 1,048,576
  float* s2a   = mB + 1048576;              // 262,144
  float* s2b   = s2a + 262144;              // 65,536
  float* fA    = s2b + 65536;               // 65,536
  float* fB    = fA + 65536;                // 16,384
  float* part  = fB + 16384;                // 32,768 (znorm partials)
  unsigned short* zfu = (unsigned short*)(part + 32768);
  unsigned short* zf1h = zfu;               //   3,072
  unsigned short* zf1l = zfu + 3072;
  unsigned short* zf2h = zfu + 6144;        //  51,200
  unsigned short* zf2l = zfu + 57344;
  unsigned short* zf3h = zfu + 108544;      // 401,408
  unsigned short* zf3l = zfu + 509952;
  unsigned short* zf4h = zfu + 911360;      // 147,456
  unsigned short* zf4l = zfu + 1058816;     // ends 1,206,272 ushorts
  float* yb2  = part + 32768 + 603136;      // 16,000 (ybuf for FC2)
  float* hp1  = yb2 + 16000;                // 128
  float* hpp1 = hp1 + 128;                  // 128
  float* hp2  = hpp1 + 128;                 // 256

  const float s1  = (float)(beta_fn(27.0 / 2.0, 0.5) / beta_fn(3.0 / 2.0, 0.5));
  const float s2c = (float)(beta_fn(800.0 / 2.0, 0.5) / beta_fn(32.0 / 2.0, 0.5));
  const float s3  = (float)(beta_fn(3136.0 / 2.0, 0.5) / beta_fn(64.0 / 2.0, 0.5));
  const float s4  = (float)(beta_fn(1152.0 / 2.0, 0.5) / beta_fn(128.0 / 2.0, 0.5));

  auto g1 = [](int n) { return dim3((n + 255) / 256); };

  // prep: merged column norms + merged fragment-ordered z
  znorm_all_kernel<<<dim3(30, 16), 256, 0, stream>>>(z1, z2, z3, z4, zf1, zf2, part);
  znorm_fin_kernel<<<8, 256, 0, stream>>>(part, zn);
  zfprep_all_kernel<<<2356, 256, 0, stream>>>(z1, z2, z3, z4, zf1h, zf1l,
                                              zf2h, zf2l, zf3h, zf3l, zf4h, zf4l);

  // ---- layer 1: (16,3,128,128) -> m1 (16,32,64,64)
  logmap_s2_kernel<<<g1(262144), 256, 0, stream>>>(x, vm0, s2a, 3, 16384, 262144);
  hconv_mfma<3, 3, 12, 3, 1, 32, 128, 128, 8, 8, 4, 1, 1>
      <<<4096, 256, 0, stream>>>(vm0, s2a, zf1h, zf1l, b1, zn + 0, mA, s2b, fA, s1);
  wavgpool_kernel<<<dim3(32, 16), 256, 0, stream>>>(mA, fA, flat, 32, 4096, 352, 0);

  // ---- layer 2: m1 -> m2 (16,64,32,32)
  hconv_mfma<32, 5, 25, 5, 2, 64, 64, 64, 8, 8, 1, 4, 4>
      <<<1024, 256, 0, stream>>>(mA, s2b, zf2h, zf2l, b2, zn + 32, mB, s2a, fB, s2c);
  wavgpool_kernel<<<dim3(64, 16), 256, 0, stream>>>(mB, fB, flat, 64, 1024, 352, 32);

  // ---- layer 3: m2 -> m3 (16,128,16,16)  [MT=32 -> 2 blocks/CU]
  hconv_mfma<64, 6, 49, 7, 3, 128, 32, 32, 4, 8, 1, 2, 8>
      <<<512, 512, 0, stream>>>(mB, s2a, zf3h, zf3l, b3, zn + 96, mA, s2b, fA, s3);
  wavgpool_kernel<<<dim3(128, 16), 256, 0, stream>>>(mA, fA, flat, 128, 256, 352, 96);

  // ---- layer 4: m3 -> m4 (16,128,8,8)
  hconv_mfma<128, 7, 9, 3, 1, 128, 16, 16, 2, 8, 1, 1, 8>
      <<<256, 512, 0, stream>>>(mA, s2b, zf4h, zf4l, b4, zn + 224, mB, s2a, fB, s4);
  wavgpool_kernel<<<dim3(128, 16), 256, 0, stream>>>(mB, fB, flat, 128, 64, 352, 224);

  // ---- head: flat (16,352) -> (16,512) -> hrelu -> (16,1000)
  pfc_y_kernel<352, 512, true><<<dim3(8, 16), 256, 0, stream>>>(
      flat, zf1, bf1, zn + 352, h1r, hp1, hpp1);
  pfc_fin_hrelu_kernel<512, 8><<<16, 256, 0, stream>>>(h1r, hp1, hpp1, h1);
  pfc_y_kernel<512, 1000, false><<<dim3(16, 16), 256, 0, stream>>>(
      h1, zf2, bf2, zn + 864, yb2, hp2, nullptr);
  pfc_fin_kernel<1000, 16><<<16, 256, 0, stream>>>(yb2, hp2, outp);

  (void)in_sizes; (void)n_in; (void)out_size; (void)ws_size;
}